// Round 7
// baseline (697.932 us; speedup 1.0000x reference)
//
#include <hip/hip_runtime.h>
#include <cstddef>
#include <cstdint>

#define N_NODES 20000
#define N_EDGES 320000

typedef __attribute__((ext_vector_type(8))) short bf8_t;   // 8 x bf16
typedef __attribute__((ext_vector_type(4))) float f4_t;    // MFMA acc / float4

__device__ __forceinline__ short f2bf(float f) {
  unsigned u = __float_as_uint(f);
  u += 0x7fff + ((u >> 16) & 1);   // round-to-nearest-even
  return (short)(u >> 16);
}

// ======================= CSR build =======================
__global__ void count_deg_kernel(const int* __restrict__ dst, int* __restrict__ deg, int e_cnt) {
  int e = blockIdx.x * blockDim.x + threadIdx.x;
  if (e < e_cnt) atomicAdd(&deg[dst[e]], 1);
}

__global__ void scan_kernel(const int* __restrict__ deg, int* __restrict__ rowptr,
                            int* __restrict__ cursor, int n) {
  __shared__ int sdata[1024];
  __shared__ int s_carry;
  int tid = threadIdx.x;
  if (tid == 0) s_carry = 0;
  __syncthreads();
  for (int base = 0; base < n; base += 1024) {
    int idx = base + tid;
    int v = (idx < n) ? deg[idx] : 0;
    sdata[tid] = v;
    __syncthreads();
    for (int off = 1; off < 1024; off <<= 1) {
      int t = (tid >= off) ? sdata[tid - off] : 0;
      __syncthreads();
      sdata[tid] += t;
      __syncthreads();
    }
    int excl = sdata[tid] - v;
    if (idx < n) { int val = s_carry + excl; rowptr[idx] = val; cursor[idx] = val; }
    __syncthreads();
    if (tid == 0) s_carry += sdata[1023];
    __syncthreads();
  }
  if (tid == 0) rowptr[n] = s_carry;
}

__global__ void fill_csr_kernel(const int* __restrict__ src, const int* __restrict__ dst,
                                int* __restrict__ cursor, int* __restrict__ csr_src,
                                int* __restrict__ csr_eid, int e_cnt) {
  int e = blockIdx.x * blockDim.x + threadIdx.x;
  if (e < e_cnt) {
    int pos = atomicAdd(&cursor[dst[e]], 1);
    csr_src[pos] = src[e];
    csr_eid[pos] = e;
  }
}

// ======================= weight prep =======================
// W1t[n][k] = e1_wl[k][n] in bf16 (n<256,k<64)
// WcT[j][k] = (e2_wl @ wp)[k][j] fp32  (j<2,k<256)
// pc[j]     = (e2_b @ wp)[j]
__global__ void prep_weights_kernel(const float* __restrict__ w1, const float* __restrict__ w2,
                                    const float* __restrict__ b2, const float* __restrict__ wp,
                                    short* __restrict__ w1t, float* __restrict__ wct,
                                    float* __restrict__ pc) {
  int i = blockIdx.x * blockDim.x + threadIdx.x;
  if (i < 16384) {
    int n = i >> 6, k = i & 63;
    w1t[n * 64 + k] = f2bf(w1[k * 256 + n]);
  } else if (i < 16896) {
    int j = i - 16384;        // 0..511
    int jj = j & 1;
    int k  = j >> 1;          // 0..255
    float s = 0.f;
    for (int c = 0; c < 64; ++c) s = fmaf(w2[k * 64 + c], wp[c * 2 + jj], s);
    wct[jj * 256 + k] = s;
  } else if (i < 16898) {
    int jj = i - 16896;
    float s = 0.f;
    for (int c = 0; c < 64; ++c) s = fmaf(b2[c], wp[c * 2 + jj], s);
    pc[jj] = s;
  }
}

// ======================= fp32 GEMM bodies =======================
template<int KIN>
__device__ __forceinline__ void gemm_body(
    const float* __restrict__ A, const float* __restrict__ W, int wld, int cb,
    int block_m, int M, float (&acc)[8][4],
    float (*As)[128 + 4], float (*Ws)[64 + 4])
{
  int tid = threadIdx.x;
  int tx = tid & 15;
  int ty = tid >> 4;
  #pragma unroll
  for (int i = 0; i < 8; ++i)
    #pragma unroll
    for (int j = 0; j < 4; ++j) acc[i][j] = 0.f;

  for (int k0 = 0; k0 < KIN; k0 += 16) {
    #pragma unroll
    for (int rep = 0; rep < 2; ++rep) {
      int ar = (tid >> 2) + rep * 64;
      int ak = (tid & 3) * 4;
      int gr = block_m + ar;
      float4 v = make_float4(0.f, 0.f, 0.f, 0.f);
      if (gr < M) v = *(const float4*)&A[(size_t)gr * KIN + k0 + ak];
      As[ak + 0][ar] = v.x; As[ak + 1][ar] = v.y;
      As[ak + 2][ar] = v.z; As[ak + 3][ar] = v.w;
    }
    {
      int wr = tid >> 4;
      int wc = (tid & 15) * 4;
      float4 v = *(const float4*)&W[(size_t)(k0 + wr) * wld + cb + wc];
      Ws[wr][wc + 0] = v.x; Ws[wr][wc + 1] = v.y;
      Ws[wr][wc + 2] = v.z; Ws[wr][wc + 3] = v.w;
    }
    __syncthreads();
    #pragma unroll
    for (int k = 0; k < 16; ++k) {
      float a[8], w[4];
      #pragma unroll
      for (int i = 0; i < 8; ++i) a[i] = As[k][ty * 8 + i];
      #pragma unroll
      for (int j = 0; j < 4; ++j) w[j] = Ws[k][tx * 4 + j];
      #pragma unroll
      for (int i = 0; i < 8; ++i)
        #pragma unroll
        for (int j = 0; j < 4; ++j) acc[i][j] = fmaf(a[i], w[j], acc[i][j]);
    }
    __syncthreads();
  }
}

// MODE 0: raw.  MODE 3: relu(v + bias).
template<int KIN, int MODE>
__global__ __launch_bounds__(256) void gemm64_kernel(
    const float* __restrict__ A, const float* __restrict__ W, int wld,
    const float* __restrict__ bias, float* __restrict__ out, int old, int M)
{
  __shared__ float As[16][128 + 4];
  __shared__ float Ws[16][64 + 4];
  float acc[8][4];
  int block_m = (int)blockIdx.x * 128;
  int cb = (int)blockIdx.y * 64;
  gemm_body<KIN>(A, W, wld, cb, block_m, M, acc, As, Ws);

  int tid = threadIdx.x;
  int tx = tid & 15, ty = tid >> 4;
  int gc = cb + tx * 4;
  #pragma unroll
  for (int i = 0; i < 8; ++i) {
    int gr = block_m + ty * 8 + i;
    if (gr >= M) continue;
    size_t idx = (size_t)gr * old + gc;
    float t0 = acc[i][0], t1 = acc[i][1], t2 = acc[i][2], t3 = acc[i][3];
    if (MODE == 3) {
      t0 = fmaxf(t0 + bias[gc + 0], 0.f);
      t1 = fmaxf(t1 + bias[gc + 1], 0.f);
      t2 = fmaxf(t2 + bias[gc + 2], 0.f);
      t3 = fmaxf(t3 + bias[gc + 3], 0.f);
    }
    *(float4*)&out[idx] = make_float4(t0, t1, t2, t3);
  }
}

// Pair GEMM for 256-wide projections: y<4 -> A@Wl colblock y -> xl; y>=4 -> A@Wr -> xr.
template<int KIN>
__global__ __launch_bounds__(256) void gemm_pair256_kernel(
    const float* __restrict__ A,
    const float* __restrict__ Wl, const float* __restrict__ Wr,
    float* __restrict__ xl, float* __restrict__ xr, int M)
{
  __shared__ float As[16][128 + 4];
  __shared__ float Ws[16][64 + 4];
  float acc[8][4];
  int block_m = (int)blockIdx.x * 128;
  int y = (int)blockIdx.y;
  const float* W = (y < 4) ? Wl : Wr;
  float* out = (y < 4) ? xl : xr;
  int cb = (y & 3) * 64;
  gemm_body<KIN>(A, W, 256, cb, block_m, M, acc, As, Ws);

  int tid = threadIdx.x;
  int tx = tid & 15, ty = tid >> 4;
  int gc = cb + tx * 4;
  #pragma unroll
  for (int i = 0; i < 8; ++i) {
    int gr = block_m + ty * 8 + i;
    if (gr >= M) continue;
    *(float4*)&out[(size_t)gr * 256 + gc] =
        make_float4(acc[i][0], acc[i][1], acc[i][2], acc[i][3]);
  }
}

// Dual 64-col GEMM: y==0 -> A@W0 -> out0 ; ==1 -> A@W1 -> out1.
template<int KIN>
__global__ __launch_bounds__(256) void gemm64_dual_kernel(
    const float* __restrict__ A,
    const float* __restrict__ W0, const float* __restrict__ W1, int wld,
    float* __restrict__ out0, float* __restrict__ out1, int M)
{
  __shared__ float As[16][128 + 4];
  __shared__ float Ws[16][64 + 4];
  float acc[8][4];
  int block_m = (int)blockIdx.x * 128;
  const float* W = (blockIdx.y == 0) ? W0 : W1;
  float* out = (blockIdx.y == 0) ? out0 : out1;
  gemm_body<KIN>(A, W, wld, 0, block_m, M, acc, As, Ws);

  int tid = threadIdx.x;
  int tx = tid & 15, ty = tid >> 4;
  int gc = tx * 4;
  #pragma unroll
  for (int i = 0; i < 8; ++i) {
    int gr = block_m + ty * 8 + i;
    if (gr >= M) continue;
    *(float4*)&out[(size_t)gr * 64 + gc] =
        make_float4(acc[i][0], acc[i][1], acc[i][2], acc[i][3]);
  }
}

// ======================= GATv2 aggregation =======================
#define AGG_UPD(P, X)                                     \
  {                                                       \
    float mn = fmaxf(m, (P));                             \
    float sc = __expf(m - mn);                            \
    float w  = __expf((P) - mn);                          \
    z = z * sc + w;                                       \
    acc = acc * sc + w * (X);                             \
    m = mn;                                               \
  }

#define AGG_BODY(STR)                                                         \
  float m, z, acc;                                                            \
  {                                                                           \
    float xs = xl[(size_t)d * STR + tid];                                     \
    float t = xs + xr_v;                                                      \
    t = t > 0.f ? t : 0.2f * t;                                               \
    float p = t * att_v;                                                      \
    _Pragma("unroll")                                                         \
    for (int off = 32; off > 0; off >>= 1) p += __shfl_xor(p, off, 64);       \
    m = p; z = 1.f; acc = xs;                                                 \
  }                                                                           \
  int j = 0;                                                                  \
  for (; j + 8 <= deg; j += 8) {                                              \
    int s[8]; float xv[8], p[8];                                              \
    _Pragma("unroll")                                                         \
    for (int u = 0; u < 8; ++u) s[u] = csr_src[row0 + j + u];                 \
    _Pragma("unroll")                                                         \
    for (int u = 0; u < 8; ++u) xv[u] = xl[(size_t)s[u] * STR + tid];         \
    _Pragma("unroll")                                                         \
    for (int u = 0; u < 8; ++u) {                                             \
      float t = xv[u] + xr_v;                                                 \
      t = t > 0.f ? t : 0.2f * t;                                             \
      p[u] = t * att_v;                                                       \
    }                                                                         \
    _Pragma("unroll")                                                         \
    for (int off = 32; off > 0; off >>= 1) {                                  \
      _Pragma("unroll")                                                       \
      for (int u = 0; u < 8; ++u) p[u] += __shfl_xor(p[u], off, 64);          \
    }                                                                         \
    _Pragma("unroll")                                                         \
    for (int u = 0; u < 8; ++u) AGG_UPD(p[u], xv[u]);                         \
  }                                                                           \
  for (; j + 4 <= deg; j += 4) {                                              \
    int s[4]; float xv[4], p[4];                                              \
    _Pragma("unroll")                                                         \
    for (int u = 0; u < 4; ++u) s[u] = csr_src[row0 + j + u];                 \
    _Pragma("unroll")                                                         \
    for (int u = 0; u < 4; ++u) xv[u] = xl[(size_t)s[u] * STR + tid];         \
    _Pragma("unroll")                                                         \
    for (int u = 0; u < 4; ++u) {                                             \
      float t = xv[u] + xr_v;                                                 \
      t = t > 0.f ? t : 0.2f * t;                                             \
      p[u] = t * att_v;                                                       \
    }                                                                         \
    _Pragma("unroll")                                                         \
    for (int off = 32; off > 0; off >>= 1) {                                  \
      _Pragma("unroll")                                                       \
      for (int u = 0; u < 4; ++u) p[u] += __shfl_xor(p[u], off, 64);          \
    }                                                                         \
    _Pragma("unroll")                                                         \
    for (int u = 0; u < 4; ++u) AGG_UPD(p[u], xv[u]);                         \
  }                                                                           \
  for (; j < deg; ++j) {                                                      \
    int s = csr_src[row0 + j];                                                \
    float x = xl[(size_t)s * STR + tid];                                      \
    float t = x + xr_v;                                                       \
    t = t > 0.f ? t : 0.2f * t;                                               \
    float p = t * att_v;                                                      \
    _Pragma("unroll")                                                         \
    for (int off = 32; off > 0; off >>= 1) p += __shfl_xor(p, off, 64);       \
    AGG_UPD(p, x);                                                            \
  }

// single-head, one wave per destination, stride 64
template<bool ELU>
__global__ __launch_bounds__(64) void gat_agg64(
    const float* __restrict__ xl, const float* __restrict__ xr,
    const float* __restrict__ att, const float* __restrict__ bias,
    const int* __restrict__ rowptr, const int* __restrict__ csr_src,
    float* __restrict__ out, int old)
{
  int d = blockIdx.x;
  int tid = threadIdx.x;
  int row0 = rowptr[d];
  int deg = rowptr[d + 1] - row0;
  float xr_v = xr[(size_t)d * 64 + tid];
  float att_v = att[tid];
  AGG_BODY(64)
  float val = acc / z + bias[tid];
  if (ELU) val = val > 0.f ? val : __expf(val) - 1.f;
  out[(size_t)d * old + tid] = val;
}

// 4-head fused: block=256 (wave h = head h), xl/xr/out stride 256, concat layout.
template<bool ELU>
__global__ __launch_bounds__(256) void gat_agg256(
    const float* __restrict__ xl, const float* __restrict__ xr,
    const float* __restrict__ att, const float* __restrict__ bias,
    const int* __restrict__ rowptr, const int* __restrict__ csr_src,
    float* __restrict__ out)
{
  int d = blockIdx.x;
  int tid = threadIdx.x;
  int row0 = rowptr[d];
  int deg = rowptr[d + 1] - row0;
  float xr_v = xr[(size_t)d * 256 + tid];
  float att_v = att[tid];
  AGG_BODY(256)
  float val = acc / z + bias[tid];
  if (ELU) val = val > 0.f ? val : __expf(val) - 1.f;
  out[(size_t)d * 256 + tid] = val;
}

// ======================= folded chunk kernel (edge rows >= N) =======================
// p[row] = elu(A[row]@W1 + b1) @ Wc + pc, where Wc = W2@wp (precomputed fp32).
// GEMM2 algebraically folded away: no LDS, no W2 loads, no G repack.
// Per 128-row block, 4 waves x 32 rows, GEMM1 transposed-MFMA as before.
__global__ __launch_bounds__(256) void chunk_fold_kernel(
    const float* __restrict__ A,      // edge_type + N*64
    const short* __restrict__ W1t,    // [256][64] bf16 (n,k) == W1^T
    const float* __restrict__ b1,     // [256]
    const float* __restrict__ WcT,    // [2][256] fp32
    const float* __restrict__ pc,     // [2]
    float* __restrict__ pbufN,        // pbuf + 2*N_NODES
    int Mtot)
{
  int tid = threadIdx.x;
  int w = tid >> 6;
  int lane = tid & 63;
  int quad = lane >> 4;
  int l15 = lane & 15;
  int row_base = (int)blockIdx.x * 128 + w * 32;

  // row frags: lane l15 = row, k = ks*32 + quad*8 + j  (B-op for transposed GEMM1)
  bf8_t a1[2][2];
  #pragma unroll
  for (int rt = 0; rt < 2; ++rt) {
    int r = row_base + rt * 16 + l15;
    int rc = r < Mtot ? r : Mtot - 1;
    const float* ap = A + (size_t)rc * 64 + quad * 8;
    #pragma unroll
    for (int ks = 0; ks < 2; ++ks) {
      float4 v0 = *(const float4*)(ap + ks * 32);
      float4 v1 = *(const float4*)(ap + ks * 32 + 4);
      bf8_t f;
      f[0] = f2bf(v0.x); f[1] = f2bf(v0.y); f[2] = f2bf(v0.z); f[3] = f2bf(v0.w);
      f[4] = f2bf(v1.x); f[5] = f2bf(v1.y); f[6] = f2bf(v1.z); f[7] = f2bf(v1.w);
      a1[rt][ks] = f;
    }
  }

  // p accumulators: [rt][wp-col]
  float p0[2] = {0.f, 0.f};   // wp col 0, rt 0/1
  float p1[2] = {0.f, 0.f};   // wp col 1, rt 0/1

  for (int cc = 0; cc < 4; ++cc) {
    #pragma unroll
    for (int nt = 0; nt < 4; ++nt) {
      const short* wb = W1t + (cc * 64 + nt * 16 + l15) * 64 + quad * 8;
      bf8_t w0 = *(const bf8_t*)(wb);
      bf8_t w1 = *(const bf8_t*)(wb + 32);
      f4_t g0 = {0.f, 0.f, 0.f, 0.f};
      f4_t g1 = {0.f, 0.f, 0.f, 0.f};
      g0 = __builtin_amdgcn_mfma_f32_16x16x32_bf16(w0, a1[0][0], g0, 0, 0, 0);
      g0 = __builtin_amdgcn_mfma_f32_16x16x32_bf16(w1, a1[0][1], g0, 0, 0, 0);
      g1 = __builtin_amdgcn_mfma_f32_16x16x32_bf16(w0, a1[1][0], g1, 0, 0, 0);
      g1 = __builtin_amdgcn_mfma_f32_16x16x32_bf16(w1, a1[1][1], g1, 0, 0, 0);
      // lane reg r = G[row = l15 (+16*rt)][col = cc*64 + nt*16 + quad*4 + r]
      int cbase = cc * 64 + nt * 16 + quad * 4;
      f4_t b4  = *(const f4_t*)&b1[cbase];
      f4_t wc0 = *(const f4_t*)&WcT[cbase];
      f4_t wc1 = *(const f4_t*)&WcT[256 + cbase];
      #pragma unroll
      for (int r = 0; r < 4; ++r) {
        float v0 = g0[r] + b4[r];
        v0 = v0 > 0.f ? v0 : __expf(v0) - 1.f;
        p0[0] = fmaf(v0, wc0[r], p0[0]);
        p1[0] = fmaf(v0, wc1[r], p1[0]);
        float v1 = g1[r] + b4[r];
        v1 = v1 > 0.f ? v1 : __expf(v1) - 1.f;
        p0[1] = fmaf(v1, wc0[r], p0[1]);
        p1[1] = fmaf(v1, wc1[r], p1[1]);
      }
    }
  }

  // reduce over quad (lane bits 4,5): full col-sum lands on every lane
  #pragma unroll
  for (int off = 16; off < 64; off <<= 1) {
    p0[0] += __shfl_xor(p0[0], off, 64);
    p0[1] += __shfl_xor(p0[1], off, 64);
    p1[0] += __shfl_xor(p1[0], off, 64);
    p1[1] += __shfl_xor(p1[1], off, 64);
  }
  if (quad == 0) {
    float c0 = pc[0], c1 = pc[1];
    int row0 = row_base + l15;
    int row1 = row_base + 16 + l15;
    if (row0 < Mtot) *(float2*)&pbufN[2 * row0] = make_float2(p0[0] + c0, p1[0] + c1);
    if (row1 < Mtot) *(float2*)&pbufN[2 * row1] = make_float2(p0[1] + c0, p1[1] + c1);
  }
}

// ======================= per-edge p for edge ids < N (no atomics) =======================
__global__ void edge_dot_kernel(const float* __restrict__ edge_repr, const float* __restrict__ wp,
                                float* __restrict__ pbuf, int e_cnt) {
  __shared__ float swp[128];
  if (threadIdx.x < 128) swp[threadIdx.x] = wp[threadIdx.x];
  __syncthreads();
  int e = blockIdx.x * blockDim.x + threadIdx.x;
  if (e >= e_cnt) return;
  const float* er = edge_repr + (size_t)e * 64;
  float a0 = 0.f, a1 = 0.f;
  #pragma unroll
  for (int k = 0; k < 64; ++k) {
    float v = er[k];
    a0 = fmaf(v, swp[2 * k + 0], a0);
    a1 = fmaf(v, swp[2 * k + 1], a1);
  }
  *(float2*)&pbuf[2 * e] = make_float2(a0, a1);
}

// ======================= Heads: CSR-gather msg + log_softmax + proxy =======================
__global__ void head_kernel(const float* __restrict__ node_repr, const float* __restrict__ ph,
                            const int* __restrict__ rowptr, const int* __restrict__ csr_eid,
                            const float* __restrict__ pbuf, const float* __restrict__ wu,
                            const float* __restrict__ bu, const float* __restrict__ w2,
                            const float* __restrict__ b2, float* __restrict__ out, int n) {
  __shared__ float swu[128];
  __shared__ float sw2[256];
  int tid = threadIdx.x;
  if (tid < 128) swu[tid] = wu[tid];
  sw2[tid] = w2[tid];
  __syncthreads();
  int i = blockIdx.x * blockDim.x + tid;
  if (i >= n) return;
  // msg gather over in-edges
  float m0 = 0.f, m1 = 0.f;
  int r0 = rowptr[i], r1 = rowptr[i + 1];
  int jj = r0;
  for (; jj + 4 <= r1; jj += 4) {
    int e0 = csr_eid[jj + 0], e1 = csr_eid[jj + 1];
    int e2 = csr_eid[jj + 2], e3 = csr_eid[jj + 3];
    float2 q0 = *(const float2*)&pbuf[2 * e0];
    float2 q1 = *(const float2*)&pbuf[2 * e1];
    float2 q2 = *(const float2*)&pbuf[2 * e2];
    float2 q3 = *(const float2*)&pbuf[2 * e3];
    m0 += (q0.x + q1.x) + (q2.x + q3.x);
    m1 += (q0.y + q1.y) + (q2.y + q3.y);
  }
  for (; jj < r1; ++jj) {
    int e = csr_eid[jj];
    float2 q = *(const float2*)&pbuf[2 * e];
    m0 += q.x; m1 += q.y;
  }
  const float* nr = node_repr + (size_t)i * 64;
  float u0 = bu[0], u1 = bu[1];
  #pragma unroll
  for (int k = 0; k < 64; ++k) {
    float v = nr[k];
    u0 = fmaf(v, swu[2 * k + 0], u0);
    u1 = fmaf(v, swu[2 * k + 1], u1);
  }
  float v0 = u0 + m0;
  float v1 = u1 + m1;
  float mx = fmaxf(v0, v1);
  float lse = mx + logf(__expf(v0 - mx) + __expf(v1 - mx));
  out[2 * i + 0] = v0 - lse;
  out[2 * i + 1] = v1 - lse;
  const float* p = ph + (size_t)i * 128;
  float p0 = b2[0], p1 = b2[1];
  #pragma unroll
  for (int k = 0; k < 128; ++k) {
    float v = p[k];
    p0 = fmaf(v, sw2[2 * k + 0], p0);
    p1 = fmaf(v, sw2[2 * k + 1], p1);
  }
  out[2 * n + 2 * i + 0] = p0;
  out[2 * n + 2 * i + 1] = p1;
}

// ======================= launch =======================
extern "C" void kernel_launch(void* const* d_in, const int* in_sizes, int n_in,
                              void* d_out, int out_size, void* d_ws, size_t ws_size,
                              hipStream_t stream) {
  const int N = N_NODES, E = N_EDGES;
  const float* x         = (const float*)d_in[0];
  const float* edge_type = (const float*)d_in[1];
  const int*   ei        = (const int*)d_in[2];
  const float* n1_wl  = (const float*)d_in[3];
  const float* n1_wr  = (const float*)d_in[4];
  const float* n1_att = (const float*)d_in[5];
  const float* n1_b   = (const float*)d_in[6];
  const float* n2_wl  = (const float*)d_in[7];
  const float* n2_wr  = (const float*)d_in[8];
  const float* n2_att = (const float*)d_in[9];
  const float* n2_b   = (const float*)d_in[10];
  const float* e1_wl  = (const float*)d_in[11];
  const float* e1_wr  = (const float*)d_in[12];
  const float* e1_att = (const float*)d_in[13];
  const float* e1_b   = (const float*)d_in[14];
  const float* e2_wl  = (const float*)d_in[15];
  const float* e2_wr  = (const float*)d_in[16];
  const float* e2_att = (const float*)d_in[17];
  const float* e2_b   = (const float*)d_in[18];
  const float* crf_wu = (const float*)d_in[19];
  const float* crf_bu = (const float*)d_in[20];
  const float* crf_wp = (const float*)d_in[21];
  const float* px_w1  = (const float*)d_in[22];
  const float* px_b1  = (const float*)d_in[23];
  const float* px_w2  = (const float*)d_in[24];
  const float* px_b2  = (const float*)d_in[25];
  float* out = (float*)d_out;
  const int* src = ei;
  const int* dst = ei + E;
  (void)in_sizes; (void)n_in; (void)out_size; (void)ws_size;

  // ---- workspace layout (~80 MB of ~327 MB) ----
  char* ws = (char*)d_ws;
  size_t off = 0;
  auto alloc = [&](size_t bytes) -> void* {
    void* p = ws + off;
    off += (bytes + 255) & ~(size_t)255;
    return p;
  };
  float* arena0 = (float*)alloc((size_t)N * 256 * 4);  // xl / [N,64] views / ph
  float* arena1 = (float*)alloc((size_t)N * 256 * 4);  // xr
  float* arena2 = (float*)alloc((size_t)N * 256 * 4);  // h / g_low
  float* ph     = arena0;
  float* B3    = (float*)alloc((size_t)N * 64 * 4);    // node_repr
  float* erlow = (float*)alloc((size_t)N * 64 * 4);    // edge_repr rows < N
  float* pbuf  = (float*)alloc((size_t)E * 2 * 4);     // per-edge CRF p-pairs
  int* deg     = (int*)alloc((size_t)N * 4);
  int* rowptr  = (int*)alloc((size_t)(N + 1) * 4);
  int* cursor  = (int*)alloc((size_t)N * 4);
  int* csr_src = (int*)alloc((size_t)E * 4);
  int* csr_eid = (int*)alloc((size_t)E * 4);
  short* W1t   = (short*)alloc((size_t)256 * 64 * 2);
  float* WcT   = (float*)alloc((size_t)2 * 256 * 4);
  float* pcv   = (float*)alloc((size_t)2 * 4);

  const int EB = (E + 255) / 256;
  const int NB = (N + 127) / 128;        // 157
  const int Mhigh = E - N;               // 300000
  const int CFB = (Mhigh + 127) / 128;   // 2344

  hipMemsetAsync(deg, 0, (size_t)N * 4, stream);
  count_deg_kernel<<<EB, 256, 0, stream>>>(dst, deg, E);
  scan_kernel<<<1, 1024, 0, stream>>>(deg, rowptr, cursor, N);
  fill_csr_kernel<<<EB, 256, 0, stream>>>(src, dst, cursor, csr_src, csr_eid, E);
  prep_weights_kernel<<<68, 256, 0, stream>>>(e1_wl, e2_wl, e2_b, crf_wp, W1t, WcT, pcv);

  // ---- node layer 1: GATv2(64 -> 4x64, concat) + elu ----
  gemm_pair256_kernel<64><<<dim3(NB, 8), 256, 0, stream>>>(x, n1_wl, n1_wr, arena0, arena1, N);
  gat_agg256<true><<<N, 256, 0, stream>>>(arena0, arena1, n1_att, n1_b, rowptr, csr_src, arena2);

  // ---- node layer 2: GATv2(256 -> 64) -> B3 ----
  gemm64_dual_kernel<256><<<dim3(NB, 2), 256, 0, stream>>>(arena2, n2_wl, n2_wr, 64, arena0, arena1, N);
  gat_agg64<false><<<N, 64, 0, stream>>>(arena0, arena1, n2_att, n2_b, rowptr, csr_src, B3, 64);

  // ---- edge layer 1, rows < N ----
  gemm_pair256_kernel<64><<<dim3(NB, 8), 256, 0, stream>>>(edge_type, e1_wl, e1_wr, arena0, arena1, N);
  gat_agg256<true><<<N, 256, 0, stream>>>(arena0, arena1, e1_att, e1_b, rowptr, csr_src, arena2);

  // ---- edge layer 2, rows < N -> erlow ----
  gemm64_dual_kernel<256><<<dim3(NB, 2), 256, 0, stream>>>(arena2, e2_wl, e2_wr, 64, arena0, arena1, N);
  gat_agg64<false><<<N, 64, 0, stream>>>(arena0, arena1, e2_att, e2_b, rowptr, csr_src, erlow, 64);

  // ---- CRF per-edge p pairs (no atomics) ----
  edge_dot_kernel<<<(N + 255) / 256, 256, 0, stream>>>(erlow, crf_wp, pbuf, N);
  chunk_fold_kernel<<<CFB, 256, 0, stream>>>(edge_type + (size_t)N * 64, W1t,
                                             e1_b, WcT, pcv, pbuf + 2 * (size_t)N, Mhigh);

  // ---- heads ----
  gemm64_kernel<64, 3><<<dim3(NB, 2), 256, 0, stream>>>(B3, px_w1, 128, px_b1, ph, 128, N);
  head_kernel<<<(N + 255) / 256, 256, 0, stream>>>(B3, ph, rowptr, csr_eid, pbuf,
                                                   crf_wu, crf_bu, px_w2, px_b2, out, N);
}

// Round 8
// 668.666 us; speedup vs baseline: 1.0438x; 1.0438x over previous
//
#include <hip/hip_runtime.h>
#include <cstddef>
#include <cstdint>

#define N_NODES 20000
#define N_EDGES 320000

typedef __attribute__((ext_vector_type(8))) short bf8_t;   // 8 x bf16
typedef __attribute__((ext_vector_type(4))) float f4_t;    // MFMA acc / float4
typedef unsigned short bfu;                                 // bf16 storage
typedef __attribute__((ext_vector_type(4))) unsigned short us4_t;

__device__ __forceinline__ short f2bf(float f) {
  unsigned u = __float_as_uint(f);
  u += 0x7fff + ((u >> 16) & 1);   // round-to-nearest-even
  return (short)(u >> 16);
}
__device__ __forceinline__ float bf2f(bfu u) {
  return __uint_as_float(((unsigned)u) << 16);
}

// ======================= CSR build =======================
__global__ void count_deg_kernel(const int* __restrict__ dst, int* __restrict__ deg, int e_cnt) {
  int e = blockIdx.x * blockDim.x + threadIdx.x;
  if (e < e_cnt) atomicAdd(&deg[dst[e]], 1);
}

__global__ void scan_kernel(const int* __restrict__ deg, int* __restrict__ rowptr,
                            int* __restrict__ cursor, int n) {
  __shared__ int sdata[1024];
  __shared__ int s_carry;
  int tid = threadIdx.x;
  if (tid == 0) s_carry = 0;
  __syncthreads();
  for (int base = 0; base < n; base += 1024) {
    int idx = base + tid;
    int v = (idx < n) ? deg[idx] : 0;
    sdata[tid] = v;
    __syncthreads();
    for (int off = 1; off < 1024; off <<= 1) {
      int t = (tid >= off) ? sdata[tid - off] : 0;
      __syncthreads();
      sdata[tid] += t;
      __syncthreads();
    }
    int excl = sdata[tid] - v;
    if (idx < n) { int val = s_carry + excl; rowptr[idx] = val; cursor[idx] = val; }
    __syncthreads();
    if (tid == 0) s_carry += sdata[1023];
    __syncthreads();
  }
  if (tid == 0) rowptr[n] = s_carry;
}

__global__ void fill_csr_kernel(const int* __restrict__ src, const int* __restrict__ dst,
                                int* __restrict__ cursor, int* __restrict__ csr_src,
                                int* __restrict__ csr_eid, int e_cnt) {
  int e = blockIdx.x * blockDim.x + threadIdx.x;
  if (e < e_cnt) {
    int pos = atomicAdd(&cursor[dst[e]], 1);
    csr_src[pos] = src[e];
    csr_eid[pos] = e;
  }
}

// ======================= weight prep =======================
__global__ void prep_weights_kernel(const float* __restrict__ w1, const float* __restrict__ w2,
                                    const float* __restrict__ b2, const float* __restrict__ wp,
                                    short* __restrict__ w1t, float* __restrict__ wct,
                                    float* __restrict__ pc) {
  int i = blockIdx.x * blockDim.x + threadIdx.x;
  if (i < 16384) {
    int n = i >> 6, k = i & 63;
    w1t[n * 64 + k] = f2bf(w1[k * 256 + n]);
  } else if (i < 16896) {
    int j = i - 16384;
    int jj = j & 1;
    int k  = j >> 1;
    float s = 0.f;
    for (int c = 0; c < 64; ++c) s = fmaf(w2[k * 64 + c], wp[c * 2 + jj], s);
    wct[jj * 256 + k] = s;
  } else if (i < 16898) {
    int jj = i - 16896;
    float s = 0.f;
    for (int c = 0; c < 64; ++c) s = fmaf(b2[c], wp[c * 2 + jj], s);
    pc[jj] = s;
  }
}

// ======================= fp32 GEMM bodies =======================
template<int KIN>
__device__ __forceinline__ void gemm_body(
    const float* __restrict__ A, const float* __restrict__ W, int wld, int cb,
    int block_m, int M, float (&acc)[8][4],
    float (*As)[128 + 4], float (*Ws)[64 + 4])
{
  int tid = threadIdx.x;
  int tx = tid & 15;
  int ty = tid >> 4;
  #pragma unroll
  for (int i = 0; i < 8; ++i)
    #pragma unroll
    for (int j = 0; j < 4; ++j) acc[i][j] = 0.f;

  for (int k0 = 0; k0 < KIN; k0 += 16) {
    #pragma unroll
    for (int rep = 0; rep < 2; ++rep) {
      int ar = (tid >> 2) + rep * 64;
      int ak = (tid & 3) * 4;
      int gr = block_m + ar;
      float4 v = make_float4(0.f, 0.f, 0.f, 0.f);
      if (gr < M) v = *(const float4*)&A[(size_t)gr * KIN + k0 + ak];
      As[ak + 0][ar] = v.x; As[ak + 1][ar] = v.y;
      As[ak + 2][ar] = v.z; As[ak + 3][ar] = v.w;
    }
    {
      int wr = tid >> 4;
      int wc = (tid & 15) * 4;
      float4 v = *(const float4*)&W[(size_t)(k0 + wr) * wld + cb + wc];
      Ws[wr][wc + 0] = v.x; Ws[wr][wc + 1] = v.y;
      Ws[wr][wc + 2] = v.z; Ws[wr][wc + 3] = v.w;
    }
    __syncthreads();
    #pragma unroll
    for (int k = 0; k < 16; ++k) {
      float a[8], w[4];
      #pragma unroll
      for (int i = 0; i < 8; ++i) a[i] = As[k][ty * 8 + i];
      #pragma unroll
      for (int j = 0; j < 4; ++j) w[j] = Ws[k][tx * 4 + j];
      #pragma unroll
      for (int i = 0; i < 8; ++i)
        #pragma unroll
        for (int j = 0; j < 4; ++j) acc[i][j] = fmaf(a[i], w[j], acc[i][j]);
    }
    __syncthreads();
  }
}

// MODE 0: raw.  MODE 3: relu(v + bias).
template<int KIN, int MODE>
__global__ __launch_bounds__(256) void gemm64_kernel(
    const float* __restrict__ A, const float* __restrict__ W, int wld,
    const float* __restrict__ bias, float* __restrict__ out, int old, int M)
{
  __shared__ float As[16][128 + 4];
  __shared__ float Ws[16][64 + 4];
  float acc[8][4];
  int block_m = (int)blockIdx.x * 128;
  int cb = (int)blockIdx.y * 64;
  gemm_body<KIN>(A, W, wld, cb, block_m, M, acc, As, Ws);

  int tid = threadIdx.x;
  int tx = tid & 15, ty = tid >> 4;
  int gc = cb + tx * 4;
  #pragma unroll
  for (int i = 0; i < 8; ++i) {
    int gr = block_m + ty * 8 + i;
    if (gr >= M) continue;
    size_t idx = (size_t)gr * old + gc;
    float t0 = acc[i][0], t1 = acc[i][1], t2 = acc[i][2], t3 = acc[i][3];
    if (MODE == 3) {
      t0 = fmaxf(t0 + bias[gc + 0], 0.f);
      t1 = fmaxf(t1 + bias[gc + 1], 0.f);
      t2 = fmaxf(t2 + bias[gc + 2], 0.f);
      t3 = fmaxf(t3 + bias[gc + 3], 0.f);
    }
    *(float4*)&out[idx] = make_float4(t0, t1, t2, t3);
  }
}

// Pair GEMM for 256-wide projections: y<4 -> A@Wl colblock y -> xl (BF16);
// y>=4 -> A@Wr -> xr (fp32).
template<int KIN>
__global__ __launch_bounds__(256) void gemm_pair256_kernel(
    const float* __restrict__ A,
    const float* __restrict__ Wl, const float* __restrict__ Wr,
    bfu* __restrict__ xl, float* __restrict__ xr, int M)
{
  __shared__ float As[16][128 + 4];
  __shared__ float Ws[16][64 + 4];
  float acc[8][4];
  int block_m = (int)blockIdx.x * 128;
  int y = (int)blockIdx.y;
  const float* W = (y < 4) ? Wl : Wr;
  int cb = (y & 3) * 64;
  gemm_body<KIN>(A, W, 256, cb, block_m, M, acc, As, Ws);

  int tid = threadIdx.x;
  int tx = tid & 15, ty = tid >> 4;
  int gc = cb + tx * 4;
  #pragma unroll
  for (int i = 0; i < 8; ++i) {
    int gr = block_m + ty * 8 + i;
    if (gr >= M) continue;
    if (y < 4) {
      us4_t pk;
      pk[0] = (bfu)f2bf(acc[i][0]); pk[1] = (bfu)f2bf(acc[i][1]);
      pk[2] = (bfu)f2bf(acc[i][2]); pk[3] = (bfu)f2bf(acc[i][3]);
      *(us4_t*)&xl[(size_t)gr * 256 + gc] = pk;
    } else {
      *(float4*)&xr[(size_t)gr * 256 + gc] =
          make_float4(acc[i][0], acc[i][1], acc[i][2], acc[i][3]);
    }
  }
}

// Dual 64-col GEMM: y==0 -> A@W0 -> xl (BF16) ; y==1 -> A@W1 -> xr (fp32).
template<int KIN>
__global__ __launch_bounds__(256) void gemm64_dual_kernel(
    const float* __restrict__ A,
    const float* __restrict__ W0, const float* __restrict__ W1, int wld,
    bfu* __restrict__ xl, float* __restrict__ xr, int M)
{
  __shared__ float As[16][128 + 4];
  __shared__ float Ws[16][64 + 4];
  float acc[8][4];
  int block_m = (int)blockIdx.x * 128;
  int y = (int)blockIdx.y;
  const float* W = (y == 0) ? W0 : W1;
  gemm_body<KIN>(A, W, wld, 0, block_m, M, acc, As, Ws);

  int tid = threadIdx.x;
  int tx = tid & 15, ty = tid >> 4;
  int gc = tx * 4;
  #pragma unroll
  for (int i = 0; i < 8; ++i) {
    int gr = block_m + ty * 8 + i;
    if (gr >= M) continue;
    if (y == 0) {
      us4_t pk;
      pk[0] = (bfu)f2bf(acc[i][0]); pk[1] = (bfu)f2bf(acc[i][1]);
      pk[2] = (bfu)f2bf(acc[i][2]); pk[3] = (bfu)f2bf(acc[i][3]);
      *(us4_t*)&xl[(size_t)gr * 64 + gc] = pk;
    } else {
      *(float4*)&xr[(size_t)gr * 64 + gc] =
          make_float4(acc[i][0], acc[i][1], acc[i][2], acc[i][3]);
    }
  }
}

// ======================= GATv2 aggregation (bf16 xl gathers) =======================
#define AGG_UPD(P, X)                                     \
  {                                                       \
    float mn = fmaxf(m, (P));                             \
    float sc = __expf(m - mn);                            \
    float w  = __expf((P) - mn);                          \
    z = z * sc + w;                                       \
    acc = acc * sc + w * (X);                             \
    m = mn;                                               \
  }

#define AGG_BODY(STR)                                                         \
  float m, z, acc;                                                            \
  {                                                                           \
    float xs = bf2f(xl[(size_t)d * STR + tid]);                               \
    float t = xs + xr_v;                                                      \
    t = t > 0.f ? t : 0.2f * t;                                               \
    float p = t * att_v;                                                      \
    _Pragma("unroll")                                                         \
    for (int off = 32; off > 0; off >>= 1) p += __shfl_xor(p, off, 64);       \
    m = p; z = 1.f; acc = xs;                                                 \
  }                                                                           \
  int j = 0;                                                                  \
  for (; j + 8 <= deg; j += 8) {                                              \
    int s[8]; float xv[8], p[8];                                              \
    _Pragma("unroll")                                                         \
    for (int u = 0; u < 8; ++u) s[u] = csr_src[row0 + j + u];                 \
    _Pragma("unroll")                                                         \
    for (int u = 0; u < 8; ++u) xv[u] = bf2f(xl[(size_t)s[u] * STR + tid]);   \
    _Pragma("unroll")                                                         \
    for (int u = 0; u < 8; ++u) {                                             \
      float t = xv[u] + xr_v;                                                 \
      t = t > 0.f ? t : 0.2f * t;                                             \
      p[u] = t * att_v;                                                       \
    }                                                                         \
    _Pragma("unroll")                                                         \
    for (int off = 32; off > 0; off >>= 1) {                                  \
      _Pragma("unroll")                                                       \
      for (int u = 0; u < 8; ++u) p[u] += __shfl_xor(p[u], off, 64);          \
    }                                                                         \
    _Pragma("unroll")                                                         \
    for (int u = 0; u < 8; ++u) AGG_UPD(p[u], xv[u]);                         \
  }                                                                           \
  for (; j + 4 <= deg; j += 4) {                                              \
    int s[4]; float xv[4], p[4];                                              \
    _Pragma("unroll")                                                         \
    for (int u = 0; u < 4; ++u) s[u] = csr_src[row0 + j + u];                 \
    _Pragma("unroll")                                                         \
    for (int u = 0; u < 4; ++u) xv[u] = bf2f(xl[(size_t)s[u] * STR + tid]);   \
    _Pragma("unroll")                                                         \
    for (int u = 0; u < 4; ++u) {                                             \
      float t = xv[u] + xr_v;                                                 \
      t = t > 0.f ? t : 0.2f * t;                                             \
      p[u] = t * att_v;                                                       \
    }                                                                         \
    _Pragma("unroll")                                                         \
    for (int off = 32; off > 0; off >>= 1) {                                  \
      _Pragma("unroll")                                                       \
      for (int u = 0; u < 4; ++u) p[u] += __shfl_xor(p[u], off, 64);          \
    }                                                                         \
    _Pragma("unroll")                                                         \
    for (int u = 0; u < 4; ++u) AGG_UPD(p[u], xv[u]);                         \
  }                                                                           \
  for (; j < deg; ++j) {                                                      \
    int s = csr_src[row0 + j];                                                \
    float x = bf2f(xl[(size_t)s * STR + tid]);                                \
    float t = x + xr_v;                                                       \
    t = t > 0.f ? t : 0.2f * t;                                               \
    float p = t * att_v;                                                      \
    _Pragma("unroll")                                                         \
    for (int off = 32; off > 0; off >>= 1) p += __shfl_xor(p, off, 64);       \
    AGG_UPD(p, x);                                                            \
  }

// single-head, one wave per destination, stride 64
template<bool ELU>
__global__ __launch_bounds__(64) void gat_agg64(
    const bfu* __restrict__ xl, const float* __restrict__ xr,
    const float* __restrict__ att, const float* __restrict__ bias,
    const int* __restrict__ rowptr, const int* __restrict__ csr_src,
    float* __restrict__ out, int old)
{
  int d = blockIdx.x;
  int tid = threadIdx.x;
  int row0 = rowptr[d];
  int deg = rowptr[d + 1] - row0;
  float xr_v = xr[(size_t)d * 64 + tid];
  float att_v = att[tid];
  AGG_BODY(64)
  float val = acc / z + bias[tid];
  if (ELU) val = val > 0.f ? val : __expf(val) - 1.f;
  out[(size_t)d * old + tid] = val;
}

// 4-head fused: block=256 (wave h = head h), stride 256, concat layout.
template<bool ELU>
__global__ __launch_bounds__(256) void gat_agg256(
    const bfu* __restrict__ xl, const float* __restrict__ xr,
    const float* __restrict__ att, const float* __restrict__ bias,
    const int* __restrict__ rowptr, const int* __restrict__ csr_src,
    float* __restrict__ out)
{
  int d = blockIdx.x;
  int tid = threadIdx.x;
  int row0 = rowptr[d];
  int deg = rowptr[d + 1] - row0;
  float xr_v = xr[(size_t)d * 256 + tid];
  float att_v = att[tid];
  AGG_BODY(256)
  float val = acc / z + bias[tid];
  if (ELU) val = val > 0.f ? val : __expf(val) - 1.f;
  out[(size_t)d * 256 + tid] = val;
}

// ======================= folded chunk kernel (edge rows >= N) =======================
__global__ __launch_bounds__(256) void chunk_fold_kernel(
    const float* __restrict__ A,      // edge_type + N*64
    const short* __restrict__ W1t,    // [256][64] bf16 (n,k) == W1^T
    const float* __restrict__ b1,     // [256]
    const float* __restrict__ WcT,    // [2][256] fp32
    const float* __restrict__ pc,     // [2]
    float* __restrict__ pbufN,        // pbuf + 2*N_NODES
    int Mtot)
{
  int tid = threadIdx.x;
  int w = tid >> 6;
  int lane = tid & 63;
  int quad = lane >> 4;
  int l15 = lane & 15;
  int row_base = (int)blockIdx.x * 128 + w * 32;

  bf8_t a1[2][2];
  #pragma unroll
  for (int rt = 0; rt < 2; ++rt) {
    int r = row_base + rt * 16 + l15;
    int rc = r < Mtot ? r : Mtot - 1;
    const float* ap = A + (size_t)rc * 64 + quad * 8;
    #pragma unroll
    for (int ks = 0; ks < 2; ++ks) {
      float4 v0 = *(const float4*)(ap + ks * 32);
      float4 v1 = *(const float4*)(ap + ks * 32 + 4);
      bf8_t f;
      f[0] = f2bf(v0.x); f[1] = f2bf(v0.y); f[2] = f2bf(v0.z); f[3] = f2bf(v0.w);
      f[4] = f2bf(v1.x); f[5] = f2bf(v1.y); f[6] = f2bf(v1.z); f[7] = f2bf(v1.w);
      a1[rt][ks] = f;
    }
  }

  float p0[2] = {0.f, 0.f};
  float p1[2] = {0.f, 0.f};

  for (int cc = 0; cc < 4; ++cc) {
    #pragma unroll
    for (int nt = 0; nt < 4; ++nt) {
      const short* wb = W1t + (cc * 64 + nt * 16 + l15) * 64 + quad * 8;
      bf8_t w0 = *(const bf8_t*)(wb);
      bf8_t w1 = *(const bf8_t*)(wb + 32);
      f4_t g0 = {0.f, 0.f, 0.f, 0.f};
      f4_t g1 = {0.f, 0.f, 0.f, 0.f};
      g0 = __builtin_amdgcn_mfma_f32_16x16x32_bf16(w0, a1[0][0], g0, 0, 0, 0);
      g0 = __builtin_amdgcn_mfma_f32_16x16x32_bf16(w1, a1[0][1], g0, 0, 0, 0);
      g1 = __builtin_amdgcn_mfma_f32_16x16x32_bf16(w0, a1[1][0], g1, 0, 0, 0);
      g1 = __builtin_amdgcn_mfma_f32_16x16x32_bf16(w1, a1[1][1], g1, 0, 0, 0);
      int cbase = cc * 64 + nt * 16 + quad * 4;
      f4_t b4  = *(const f4_t*)&b1[cbase];
      f4_t wc0 = *(const f4_t*)&WcT[cbase];
      f4_t wc1 = *(const f4_t*)&WcT[256 + cbase];
      #pragma unroll
      for (int r = 0; r < 4; ++r) {
        float v0 = g0[r] + b4[r];
        v0 = v0 > 0.f ? v0 : __expf(v0) - 1.f;
        p0[0] = fmaf(v0, wc0[r], p0[0]);
        p1[0] = fmaf(v0, wc1[r], p1[0]);
        float v1 = g1[r] + b4[r];
        v1 = v1 > 0.f ? v1 : __expf(v1) - 1.f;
        p0[1] = fmaf(v1, wc0[r], p0[1]);
        p1[1] = fmaf(v1, wc1[r], p1[1]);
      }
    }
  }

  #pragma unroll
  for (int off = 16; off < 64; off <<= 1) {
    p0[0] += __shfl_xor(p0[0], off, 64);
    p0[1] += __shfl_xor(p0[1], off, 64);
    p1[0] += __shfl_xor(p1[0], off, 64);
    p1[1] += __shfl_xor(p1[1], off, 64);
  }
  if (quad == 0) {
    float c0 = pc[0], c1 = pc[1];
    int row0 = row_base + l15;
    int row1 = row_base + 16 + l15;
    if (row0 < Mtot) *(float2*)&pbufN[2 * row0] = make_float2(p0[0] + c0, p1[0] + c1);
    if (row1 < Mtot) *(float2*)&pbufN[2 * row1] = make_float2(p0[1] + c0, p1[1] + c1);
  }
}

// ======================= per-edge p for edge ids < N =======================
__global__ void edge_dot_kernel(const float* __restrict__ edge_repr, const float* __restrict__ wp,
                                float* __restrict__ pbuf, int e_cnt) {
  __shared__ float swp[128];
  if (threadIdx.x < 128) swp[threadIdx.x] = wp[threadIdx.x];
  __syncthreads();
  int e = blockIdx.x * blockDim.x + threadIdx.x;
  if (e >= e_cnt) return;
  const float* er = edge_repr + (size_t)e * 64;
  float a0 = 0.f, a1 = 0.f;
  #pragma unroll
  for (int k = 0; k < 64; ++k) {
    float v = er[k];
    a0 = fmaf(v, swp[2 * k + 0], a0);
    a1 = fmaf(v, swp[2 * k + 1], a1);
  }
  *(float2*)&pbuf[2 * e] = make_float2(a0, a1);
}

// ======================= Heads =======================
__global__ void head_kernel(const float* __restrict__ node_repr, const float* __restrict__ ph,
                            const int* __restrict__ rowptr, const int* __restrict__ csr_eid,
                            const float* __restrict__ pbuf, const float* __restrict__ wu,
                            const float* __restrict__ bu, const float* __restrict__ w2,
                            const float* __restrict__ b2, float* __restrict__ out, int n) {
  __shared__ float swu[128];
  __shared__ float sw2[256];
  int tid = threadIdx.x;
  if (tid < 128) swu[tid] = wu[tid];
  sw2[tid] = w2[tid];
  __syncthreads();
  int i = blockIdx.x * blockDim.x + tid;
  if (i >= n) return;
  float m0 = 0.f, m1 = 0.f;
  int r0 = rowptr[i], r1 = rowptr[i + 1];
  int jj = r0;
  for (; jj + 4 <= r1; jj += 4) {
    int e0 = csr_eid[jj + 0], e1 = csr_eid[jj + 1];
    int e2 = csr_eid[jj + 2], e3 = csr_eid[jj + 3];
    float2 q0 = *(const float2*)&pbuf[2 * e0];
    float2 q1 = *(const float2*)&pbuf[2 * e1];
    float2 q2 = *(const float2*)&pbuf[2 * e2];
    float2 q3 = *(const float2*)&pbuf[2 * e3];
    m0 += (q0.x + q1.x) + (q2.x + q3.x);
    m1 += (q0.y + q1.y) + (q2.y + q3.y);
  }
  for (; jj < r1; ++jj) {
    int e = csr_eid[jj];
    float2 q = *(const float2*)&pbuf[2 * e];
    m0 += q.x; m1 += q.y;
  }
  const float* nr = node_repr + (size_t)i * 64;
  float u0 = bu[0], u1 = bu[1];
  #pragma unroll
  for (int k = 0; k < 64; ++k) {
    float v = nr[k];
    u0 = fmaf(v, swu[2 * k + 0], u0);
    u1 = fmaf(v, swu[2 * k + 1], u1);
  }
  float v0 = u0 + m0;
  float v1 = u1 + m1;
  float mx = fmaxf(v0, v1);
  float lse = mx + logf(__expf(v0 - mx) + __expf(v1 - mx));
  out[2 * i + 0] = v0 - lse;
  out[2 * i + 1] = v1 - lse;
  const float* p = ph + (size_t)i * 128;
  float p0 = b2[0], p1 = b2[1];
  #pragma unroll
  for (int k = 0; k < 128; ++k) {
    float v = p[k];
    p0 = fmaf(v, sw2[2 * k + 0], p0);
    p1 = fmaf(v, sw2[2 * k + 1], p1);
  }
  out[2 * n + 2 * i + 0] = p0;
  out[2 * n + 2 * i + 1] = p1;
}

// ======================= launch =======================
extern "C" void kernel_launch(void* const* d_in, const int* in_sizes, int n_in,
                              void* d_out, int out_size, void* d_ws, size_t ws_size,
                              hipStream_t stream) {
  const int N = N_NODES, E = N_EDGES;
  const float* x         = (const float*)d_in[0];
  const float* edge_type = (const float*)d_in[1];
  const int*   ei        = (const int*)d_in[2];
  const float* n1_wl  = (const float*)d_in[3];
  const float* n1_wr  = (const float*)d_in[4];
  const float* n1_att = (const float*)d_in[5];
  const float* n1_b   = (const float*)d_in[6];
  const float* n2_wl  = (const float*)d_in[7];
  const float* n2_wr  = (const float*)d_in[8];
  const float* n2_att = (const float*)d_in[9];
  const float* n2_b   = (const float*)d_in[10];
  const float* e1_wl  = (const float*)d_in[11];
  const float* e1_wr  = (const float*)d_in[12];
  const float* e1_att = (const float*)d_in[13];
  const float* e1_b   = (const float*)d_in[14];
  const float* e2_wl  = (const float*)d_in[15];
  const float* e2_wr  = (const float*)d_in[16];
  const float* e2_att = (const float*)d_in[17];
  const float* e2_b   = (const float*)d_in[18];
  const float* crf_wu = (const float*)d_in[19];
  const float* crf_bu = (const float*)d_in[20];
  const float* crf_wp = (const float*)d_in[21];
  const float* px_w1  = (const float*)d_in[22];
  const float* px_b1  = (const float*)d_in[23];
  const float* px_w2  = (const float*)d_in[24];
  const float* px_b2  = (const float*)d_in[25];
  float* out = (float*)d_out;
  const int* src = ei;
  const int* dst = ei + E;
  (void)in_sizes; (void)n_in; (void)out_size; (void)ws_size;

  // ---- workspace layout ----
  char* ws = (char*)d_ws;
  size_t off = 0;
  auto alloc = [&](size_t bytes) -> void* {
    void* p = ws + off;
    off += (bytes + 255) & ~(size_t)255;
    return p;
  };
  char* arena0 = (char*)alloc((size_t)N * 256 * 4);  // xl bf16 [N,256] / ph fp32 [N,128]
  float* arena1 = (float*)alloc((size_t)N * 256 * 4); // xr fp32
  float* arena2 = (float*)alloc((size_t)N * 256 * 4); // h / g_low fp32
  bfu* xl_bf   = (bfu*)arena0;
  float* ph    = (float*)arena0;
  float* B3    = (float*)alloc((size_t)N * 64 * 4);    // node_repr
  float* erlow = (float*)alloc((size_t)N * 64 * 4);    // edge_repr rows < N
  float* pbuf  = (float*)alloc((size_t)E * 2 * 4);     // per-edge CRF p-pairs
  int* deg     = (int*)alloc((size_t)N * 4);
  int* rowptr  = (int*)alloc((size_t)(N + 1) * 4);
  int* cursor  = (int*)alloc((size_t)N * 4);
  int* csr_src = (int*)alloc((size_t)E * 4);
  int* csr_eid = (int*)alloc((size_t)E * 4);
  short* W1t   = (short*)alloc((size_t)256 * 64 * 2);
  float* WcT   = (float*)alloc((size_t)2 * 256 * 4);
  float* pcv   = (float*)alloc((size_t)2 * 4);

  const int EB = (E + 255) / 256;
  const int NB = (N + 127) / 128;        // 157
  const int Mhigh = E - N;               // 300000
  const int CFB = (Mhigh + 127) / 128;   // 2344

  hipMemsetAsync(deg, 0, (size_t)N * 4, stream);
  count_deg_kernel<<<EB, 256, 0, stream>>>(dst, deg, E);
  scan_kernel<<<1, 1024, 0, stream>>>(deg, rowptr, cursor, N);
  fill_csr_kernel<<<EB, 256, 0, stream>>>(src, dst, cursor, csr_src, csr_eid, E);
  prep_weights_kernel<<<68, 256, 0, stream>>>(e1_wl, e2_wl, e2_b, crf_wp, W1t, WcT, pcv);

  // ---- node layer 1: GATv2(64 -> 4x64, concat) + elu ----
  gemm_pair256_kernel<64><<<dim3(NB, 8), 256, 0, stream>>>(x, n1_wl, n1_wr, xl_bf, arena1, N);
  gat_agg256<true><<<N, 256, 0, stream>>>(xl_bf, arena1, n1_att, n1_b, rowptr, csr_src, arena2);

  // ---- node layer 2: GATv2(256 -> 64) -> B3 ----
  gemm64_dual_kernel<256><<<dim3(NB, 2), 256, 0, stream>>>(arena2, n2_wl, n2_wr, 64, xl_bf, arena1, N);
  gat_agg64<false><<<N, 64, 0, stream>>>(xl_bf, arena1, n2_att, n2_b, rowptr, csr_src, B3, 64);

  // ---- edge layer 1, rows < N ----
  gemm_pair256_kernel<64><<<dim3(NB, 8), 256, 0, stream>>>(edge_type, e1_wl, e1_wr, xl_bf, arena1, N);
  gat_agg256<true><<<N, 256, 0, stream>>>(xl_bf, arena1, e1_att, e1_b, rowptr, csr_src, arena2);

  // ---- edge layer 2, rows < N -> erlow ----
  gemm64_dual_kernel<256><<<dim3(NB, 2), 256, 0, stream>>>(arena2, e2_wl, e2_wr, 64, xl_bf, arena1, N);
  gat_agg64<false><<<N, 64, 0, stream>>>(xl_bf, arena1, e2_att, e2_b, rowptr, csr_src, erlow, 64);

  // ---- CRF per-edge p pairs ----
  edge_dot_kernel<<<(N + 255) / 256, 256, 0, stream>>>(erlow, crf_wp, pbuf, N);
  chunk_fold_kernel<<<CFB, 256, 0, stream>>>(edge_type + (size_t)N * 64, W1t,
                                             e1_b, WcT, pcv, pbuf + 2 * (size_t)N, Mhigh);

  // ---- heads ----
  gemm64_kernel<64, 3><<<dim3(NB, 2), 256, 0, stream>>>(B3, px_w1, 128, px_b1, ph, 128, N);
  head_kernel<<<(N + 255) / 256, 256, 0, stream>>>(B3, ph, rowptr, csr_eid, pbuf,
                                                   crf_wu, crf_bu, px_w2, px_b2, out, N);
}

// Round 9
// 588.032 us; speedup vs baseline: 1.1869x; 1.1371x over previous
//
#include <hip/hip_runtime.h>
#include <cstddef>
#include <cstdint>

#define N_NODES 20000
#define N_EDGES 320000

typedef __attribute__((ext_vector_type(8))) short bf8_t;   // 8 x bf16 (MFMA frag)
typedef __attribute__((ext_vector_type(4))) float f4_t;    // MFMA acc / float4
typedef unsigned short bfu;                                 // bf16 storage
typedef __attribute__((ext_vector_type(4))) unsigned short us4_t;
typedef __attribute__((ext_vector_type(8))) unsigned short us8_t;

__device__ __forceinline__ short f2bf(float f) {
  unsigned u = __float_as_uint(f);
  u += 0x7fff + ((u >> 16) & 1);   // round-to-nearest-even
  return (short)(u >> 16);
}
__device__ __forceinline__ float bf2f(bfu u) {
  return __uint_as_float(((unsigned)u) << 16);
}

// ======================= CSR build =======================
__global__ void count_deg_kernel(const int* __restrict__ dst, int* __restrict__ deg, int e_cnt) {
  int e = blockIdx.x * blockDim.x + threadIdx.x;
  if (e < e_cnt) atomicAdd(&deg[dst[e]], 1);
}

__global__ void scan_kernel(const int* __restrict__ deg, int* __restrict__ rowptr,
                            int* __restrict__ cursor, int n) {
  __shared__ int sdata[1024];
  __shared__ int s_carry;
  int tid = threadIdx.x;
  if (tid == 0) s_carry = 0;
  __syncthreads();
  for (int base = 0; base < n; base += 1024) {
    int idx = base + tid;
    int v = (idx < n) ? deg[idx] : 0;
    sdata[tid] = v;
    __syncthreads();
    for (int off = 1; off < 1024; off <<= 1) {
      int t = (tid >= off) ? sdata[tid - off] : 0;
      __syncthreads();
      sdata[tid] += t;
      __syncthreads();
    }
    int excl = sdata[tid] - v;
    if (idx < n) { int val = s_carry + excl; rowptr[idx] = val; cursor[idx] = val; }
    __syncthreads();
    if (tid == 0) s_carry += sdata[1023];
    __syncthreads();
  }
  if (tid == 0) rowptr[n] = s_carry;
}

__global__ void fill_csr_kernel(const int* __restrict__ src, const int* __restrict__ dst,
                                int* __restrict__ cursor, int* __restrict__ csr_src,
                                int* __restrict__ csr_eid, int e_cnt) {
  int e = blockIdx.x * blockDim.x + threadIdx.x;
  if (e < e_cnt) {
    int pos = atomicAdd(&cursor[dst[e]], 1);
    csr_src[pos] = src[e];
    csr_eid[pos] = e;
  }
}

// ======================= weight prep =======================
__global__ void prep_weights_kernel(const float* __restrict__ w1, const float* __restrict__ w2,
                                    const float* __restrict__ b2, const float* __restrict__ wp,
                                    short* __restrict__ w1t, float* __restrict__ wct,
                                    float* __restrict__ pc) {
  int i = blockIdx.x * blockDim.x + threadIdx.x;
  if (i < 16384) {
    int n = i >> 6, k = i & 63;
    w1t[n * 64 + k] = f2bf(w1[k * 256 + n]);
  } else if (i < 16896) {
    int j = i - 16384;
    int jj = j & 1;
    int k  = j >> 1;
    float s = 0.f;
    for (int c = 0; c < 64; ++c) s = fmaf(w2[k * 64 + c], wp[c * 2 + jj], s);
    wct[jj * 256 + k] = s;
  } else if (i < 16898) {
    int jj = i - 16896;
    float s = 0.f;
    for (int c = 0; c < 64; ++c) s = fmaf(b2[c], wp[c * 2 + jj], s);
    pc[jj] = s;
  }
}

// ======================= fp32 GEMM bodies =======================
template<int KIN>
__device__ __forceinline__ void gemm_body(
    const float* __restrict__ A, const float* __restrict__ W, int wld, int cb,
    int block_m, int M, float (&acc)[8][4],
    float (*As)[128 + 4], float (*Ws)[64 + 4])
{
  int tid = threadIdx.x;
  int tx = tid & 15;
  int ty = tid >> 4;
  #pragma unroll
  for (int i = 0; i < 8; ++i)
    #pragma unroll
    for (int j = 0; j < 4; ++j) acc[i][j] = 0.f;

  for (int k0 = 0; k0 < KIN; k0 += 16) {
    #pragma unroll
    for (int rep = 0; rep < 2; ++rep) {
      int ar = (tid >> 2) + rep * 64;
      int ak = (tid & 3) * 4;
      int gr = block_m + ar;
      float4 v = make_float4(0.f, 0.f, 0.f, 0.f);
      if (gr < M) v = *(const float4*)&A[(size_t)gr * KIN + k0 + ak];
      As[ak + 0][ar] = v.x; As[ak + 1][ar] = v.y;
      As[ak + 2][ar] = v.z; As[ak + 3][ar] = v.w;
    }
    {
      int wr = tid >> 4;
      int wc = (tid & 15) * 4;
      float4 v = *(const float4*)&W[(size_t)(k0 + wr) * wld + cb + wc];
      Ws[wr][wc + 0] = v.x; Ws[wr][wc + 1] = v.y;
      Ws[wr][wc + 2] = v.z; Ws[wr][wc + 3] = v.w;
    }
    __syncthreads();
    #pragma unroll
    for (int k = 0; k < 16; ++k) {
      float a[8], w[4];
      #pragma unroll
      for (int i = 0; i < 8; ++i) a[i] = As[k][ty * 8 + i];
      #pragma unroll
      for (int j = 0; j < 4; ++j) w[j] = Ws[k][tx * 4 + j];
      #pragma unroll
      for (int i = 0; i < 8; ++i)
        #pragma unroll
        for (int j = 0; j < 4; ++j) acc[i][j] = fmaf(a[i], w[j], acc[i][j]);
    }
    __syncthreads();
  }
}

// MODE 0: raw.  MODE 3: relu(v + bias).
template<int KIN, int MODE>
__global__ __launch_bounds__(256) void gemm64_kernel(
    const float* __restrict__ A, const float* __restrict__ W, int wld,
    const float* __restrict__ bias, float* __restrict__ out, int old, int M)
{
  __shared__ float As[16][128 + 4];
  __shared__ float Ws[16][64 + 4];
  float acc[8][4];
  int block_m = (int)blockIdx.x * 128;
  int cb = (int)blockIdx.y * 64;
  gemm_body<KIN>(A, W, wld, cb, block_m, M, acc, As, Ws);

  int tid = threadIdx.x;
  int tx = tid & 15, ty = tid >> 4;
  int gc = cb + tx * 4;
  #pragma unroll
  for (int i = 0; i < 8; ++i) {
    int gr = block_m + ty * 8 + i;
    if (gr >= M) continue;
    size_t idx = (size_t)gr * old + gc;
    float t0 = acc[i][0], t1 = acc[i][1], t2 = acc[i][2], t3 = acc[i][3];
    if (MODE == 3) {
      t0 = fmaxf(t0 + bias[gc + 0], 0.f);
      t1 = fmaxf(t1 + bias[gc + 1], 0.f);
      t2 = fmaxf(t2 + bias[gc + 2], 0.f);
      t3 = fmaxf(t3 + bias[gc + 3], 0.f);
    }
    *(float4*)&out[idx] = make_float4(t0, t1, t2, t3);
  }
}

// Pair GEMM for 256-wide projections: y<4 -> A@Wl colblock y -> xl (BF16);
// y>=4 -> A@Wr -> xr (fp32).
template<int KIN>
__global__ __launch_bounds__(256) void gemm_pair256_kernel(
    const float* __restrict__ A,
    const float* __restrict__ Wl, const float* __restrict__ Wr,
    bfu* __restrict__ xl, float* __restrict__ xr, int M)
{
  __shared__ float As[16][128 + 4];
  __shared__ float Ws[16][64 + 4];
  float acc[8][4];
  int block_m = (int)blockIdx.x * 128;
  int y = (int)blockIdx.y;
  const float* W = (y < 4) ? Wl : Wr;
  int cb = (y & 3) * 64;
  gemm_body<KIN>(A, W, 256, cb, block_m, M, acc, As, Ws);

  int tid = threadIdx.x;
  int tx = tid & 15, ty = tid >> 4;
  int gc = cb + tx * 4;
  #pragma unroll
  for (int i = 0; i < 8; ++i) {
    int gr = block_m + ty * 8 + i;
    if (gr >= M) continue;
    if (y < 4) {
      us4_t pk;
      pk[0] = (bfu)f2bf(acc[i][0]); pk[1] = (bfu)f2bf(acc[i][1]);
      pk[2] = (bfu)f2bf(acc[i][2]); pk[3] = (bfu)f2bf(acc[i][3]);
      *(us4_t*)&xl[(size_t)gr * 256 + gc] = pk;
    } else {
      *(float4*)&xr[(size_t)gr * 256 + gc] =
          make_float4(acc[i][0], acc[i][1], acc[i][2], acc[i][3]);
    }
  }
}

// Dual 64-col GEMM: y==0 -> A@W0 -> xl (BF16) ; y==1 -> A@W1 -> xr (fp32).
template<int KIN>
__global__ __launch_bounds__(256) void gemm64_dual_kernel(
    const float* __restrict__ A,
    const float* __restrict__ W0, const float* __restrict__ W1, int wld,
    bfu* __restrict__ xl, float* __restrict__ xr, int M)
{
  __shared__ float As[16][128 + 4];
  __shared__ float Ws[16][64 + 4];
  float acc[8][4];
  int block_m = (int)blockIdx.x * 128;
  int y = (int)blockIdx.y;
  const float* W = (y == 0) ? W0 : W1;
  gemm_body<KIN>(A, W, wld, 0, block_m, M, acc, As, Ws);

  int tid = threadIdx.x;
  int tx = tid & 15, ty = tid >> 4;
  int gc = tx * 4;
  #pragma unroll
  for (int i = 0; i < 8; ++i) {
    int gr = block_m + ty * 8 + i;
    if (gr >= M) continue;
    if (y == 0) {
      us4_t pk;
      pk[0] = (bfu)f2bf(acc[i][0]); pk[1] = (bfu)f2bf(acc[i][1]);
      pk[2] = (bfu)f2bf(acc[i][2]); pk[3] = (bfu)f2bf(acc[i][3]);
      *(us4_t*)&xl[(size_t)gr * 64 + gc] = pk;
    } else {
      *(float4*)&xr[(size_t)gr * 64 + gc] =
          make_float4(acc[i][0], acc[i][1], acc[i][2], acc[i][3]);
    }
  }
}

// ======================= GATv2 aggregation v2 =======================
// Edge x channel-chunk tiling: wave h = head h; lane = egrp*8 + cch.
// Each lane owns 8 channels (one 16B bf16x8 load) of one of 8 edge slots.
// logit reduce = 3 shfl over cch; online-max = 3 shfl over egrp; value acc
// is lane-local (acc8 rescaled by uniform sc); one 27-shfl reduce at end.
template<bool ELU, int STR>
__global__ __launch_bounds__(STR == 256 ? 256 : 64) void gat_agg_v2(
    const bfu* __restrict__ xl, const float* __restrict__ xr,
    const float* __restrict__ att, const float* __restrict__ bias,
    const int* __restrict__ rowptr, const int* __restrict__ csr_src,
    float* __restrict__ out, int old)
{
  int d = blockIdx.x;
  int tid = threadIdx.x;
  int h = tid >> 6;           // wave = head
  int lane = tid & 63;
  int egrp = lane >> 3;       // edge slot 0..7
  int cch  = lane & 7;        // channel chunk 0..7
  int row0 = rowptr[d];
  int deg = rowptr[d + 1] - row0;
  int cbase = h * 64 + cch * 8;

  float xrv[8], attv[8];
  {
    const float* xrp = xr + (size_t)d * STR + cbase;
    const float* atp = att + cbase;
    float4 a0 = *(const float4*)(xrp);
    float4 a1 = *(const float4*)(xrp + 4);
    xrv[0] = a0.x; xrv[1] = a0.y; xrv[2] = a0.z; xrv[3] = a0.w;
    xrv[4] = a1.x; xrv[5] = a1.y; xrv[6] = a1.z; xrv[7] = a1.w;
    float4 b0 = *(const float4*)(atp);
    float4 b1 = *(const float4*)(atp + 4);
    attv[0] = b0.x; attv[1] = b0.y; attv[2] = b0.z; attv[3] = b0.w;
    attv[4] = b1.x; attv[5] = b1.y; attv[6] = b1.z; attv[7] = b1.w;
  }

  // ---- self loop: init m; value/z live only on egrp 0 ----
  float m, zloc;
  float acc8[8];
  {
    us8_t xu = *(const us8_t*)&xl[(size_t)d * STR + cbase];
    float part = 0.f;
    #pragma unroll
    for (int i = 0; i < 8; ++i) {
      float xs = bf2f(xu[i]);
      float t = xs + xrv[i];
      t = t > 0.f ? t : 0.2f * t;
      part = fmaf(t, attv[i], part);
      acc8[i] = (egrp == 0) ? xs : 0.f;
    }
    part += __shfl_xor(part, 1, 64);
    part += __shfl_xor(part, 2, 64);
    part += __shfl_xor(part, 4, 64);
    m = part;
    zloc = (egrp == 0) ? 1.f : 0.f;
  }

  // ---- edge loop: 8 edges per iteration ----
  for (int j = 0; j < deg; j += 8) {
    int idx = j + egrp;
    bool valid = idx < deg;
    int s = valid ? csr_src[row0 + idx] : d;
    us8_t xu = *(const us8_t*)&xl[(size_t)s * STR + cbase];
    float xf[8];
    float part = 0.f;
    #pragma unroll
    for (int i = 0; i < 8; ++i) {
      xf[i] = bf2f(xu[i]);
      float t = xf[i] + xrv[i];
      t = t > 0.f ? t : 0.2f * t;
      part = fmaf(t, attv[i], part);
    }
    part += __shfl_xor(part, 1, 64);
    part += __shfl_xor(part, 2, 64);
    part += __shfl_xor(part, 4, 64);
    float logit = valid ? part : -1e30f;
    float gmax = logit;
    gmax = fmaxf(gmax, __shfl_xor(gmax, 8, 64));
    gmax = fmaxf(gmax, __shfl_xor(gmax, 16, 64));
    gmax = fmaxf(gmax, __shfl_xor(gmax, 32, 64));
    float mn = fmaxf(m, gmax);
    float sc = __expf(m - mn);
    float w  = __expf(logit - mn);     // invalid -> exp(~-1e30) = 0
    zloc = zloc * sc + w;
    #pragma unroll
    for (int i = 0; i < 8; ++i) acc8[i] = fmaf(w, xf[i], acc8[i] * sc);
    m = mn;
  }

  // ---- final reduce over edge groups (offsets 8,16,32) ----
  #pragma unroll
  for (int off = 8; off < 64; off <<= 1) {
    zloc += __shfl_xor(zloc, off, 64);
    #pragma unroll
    for (int i = 0; i < 8; ++i) acc8[i] += __shfl_xor(acc8[i], off, 64);
  }

  if (egrp == 0) {
    float invz = 1.f / zloc;
    float o[8];
    #pragma unroll
    for (int i = 0; i < 8; ++i) {
      float val = acc8[i] * invz + bias[cbase + i];
      if (ELU) val = val > 0.f ? val : __expf(val) - 1.f;
      o[i] = val;
    }
    float* op = out + (size_t)d * old + cbase;
    *(float4*)(op)     = make_float4(o[0], o[1], o[2], o[3]);
    *(float4*)(op + 4) = make_float4(o[4], o[5], o[6], o[7]);
  }
}

// ======================= folded chunk kernel (edge rows >= N) =======================
__global__ __launch_bounds__(256) void chunk_fold_kernel(
    const float* __restrict__ A,      // edge_type + N*64
    const short* __restrict__ W1t,    // [256][64] bf16 (n,k) == W1^T
    const float* __restrict__ b1,     // [256]
    const float* __restrict__ WcT,    // [2][256] fp32
    const float* __restrict__ pc,     // [2]
    float* __restrict__ pbufN,        // pbuf + 2*N_NODES
    int Mtot)
{
  int tid = threadIdx.x;
  int w = tid >> 6;
  int lane = tid & 63;
  int quad = lane >> 4;
  int l15 = lane & 15;
  int row_base = (int)blockIdx.x * 128 + w * 32;

  bf8_t a1[2][2];
  #pragma unroll
  for (int rt = 0; rt < 2; ++rt) {
    int r = row_base + rt * 16 + l15;
    int rc = r < Mtot ? r : Mtot - 1;
    const float* ap = A + (size_t)rc * 64 + quad * 8;
    #pragma unroll
    for (int ks = 0; ks < 2; ++ks) {
      float4 v0 = *(const float4*)(ap + ks * 32);
      float4 v1 = *(const float4*)(ap + ks * 32 + 4);
      bf8_t f;
      f[0] = f2bf(v0.x); f[1] = f2bf(v0.y); f[2] = f2bf(v0.z); f[3] = f2bf(v0.w);
      f[4] = f2bf(v1.x); f[5] = f2bf(v1.y); f[6] = f2bf(v1.z); f[7] = f2bf(v1.w);
      a1[rt][ks] = f;
    }
  }

  float p0[2] = {0.f, 0.f};
  float p1[2] = {0.f, 0.f};

  for (int cc = 0; cc < 4; ++cc) {
    #pragma unroll
    for (int nt = 0; nt < 4; ++nt) {
      const short* wb = W1t + (cc * 64 + nt * 16 + l15) * 64 + quad * 8;
      bf8_t w0 = *(const bf8_t*)(wb);
      bf8_t w1 = *(const bf8_t*)(wb + 32);
      f4_t g0 = {0.f, 0.f, 0.f, 0.f};
      f4_t g1 = {0.f, 0.f, 0.f, 0.f};
      g0 = __builtin_amdgcn_mfma_f32_16x16x32_bf16(w0, a1[0][0], g0, 0, 0, 0);
      g0 = __builtin_amdgcn_mfma_f32_16x16x32_bf16(w1, a1[0][1], g0, 0, 0, 0);
      g1 = __builtin_amdgcn_mfma_f32_16x16x32_bf16(w0, a1[1][0], g1, 0, 0, 0);
      g1 = __builtin_amdgcn_mfma_f32_16x16x32_bf16(w1, a1[1][1], g1, 0, 0, 0);
      int cbase = cc * 64 + nt * 16 + quad * 4;
      f4_t b4  = *(const f4_t*)&b1[cbase];
      f4_t wc0 = *(const f4_t*)&WcT[cbase];
      f4_t wc1 = *(const f4_t*)&WcT[256 + cbase];
      #pragma unroll
      for (int r = 0; r < 4; ++r) {
        float v0 = g0[r] + b4[r];
        v0 = v0 > 0.f ? v0 : __expf(v0) - 1.f;
        p0[0] = fmaf(v0, wc0[r], p0[0]);
        p1[0] = fmaf(v0, wc1[r], p1[0]);
        float v1 = g1[r] + b4[r];
        v1 = v1 > 0.f ? v1 : __expf(v1) - 1.f;
        p0[1] = fmaf(v1, wc0[r], p0[1]);
        p1[1] = fmaf(v1, wc1[r], p1[1]);
      }
    }
  }

  #pragma unroll
  for (int off = 16; off < 64; off <<= 1) {
    p0[0] += __shfl_xor(p0[0], off, 64);
    p0[1] += __shfl_xor(p0[1], off, 64);
    p1[0] += __shfl_xor(p1[0], off, 64);
    p1[1] += __shfl_xor(p1[1], off, 64);
  }
  if (quad == 0) {
    float c0 = pc[0], c1 = pc[1];
    int row0 = row_base + l15;
    int row1 = row_base + 16 + l15;
    if (row0 < Mtot) *(float2*)&pbufN[2 * row0] = make_float2(p0[0] + c0, p1[0] + c1);
    if (row1 < Mtot) *(float2*)&pbufN[2 * row1] = make_float2(p0[1] + c0, p1[1] + c1);
  }
}

// ======================= per-edge p for edge ids < N =======================
__global__ void edge_dot_kernel(const float* __restrict__ edge_repr, const float* __restrict__ wp,
                                float* __restrict__ pbuf, int e_cnt) {
  __shared__ float swp[128];
  if (threadIdx.x < 128) swp[threadIdx.x] = wp[threadIdx.x];
  __syncthreads();
  int e = blockIdx.x * blockDim.x + threadIdx.x;
  if (e >= e_cnt) return;
  const float* er = edge_repr + (size_t)e * 64;
  float a0 = 0.f, a1 = 0.f;
  #pragma unroll
  for (int k = 0; k < 64; ++k) {
    float v = er[k];
    a0 = fmaf(v, swp[2 * k + 0], a0);
    a1 = fmaf(v, swp[2 * k + 1], a1);
  }
  *(float2*)&pbuf[2 * e] = make_float2(a0, a1);
}

// ======================= Heads =======================
__global__ void head_kernel(const float* __restrict__ node_repr, const float* __restrict__ ph,
                            const int* __restrict__ rowptr, const int* __restrict__ csr_eid,
                            const float* __restrict__ pbuf, const float* __restrict__ wu,
                            const float* __restrict__ bu, const float* __restrict__ w2,
                            const float* __restrict__ b2, float* __restrict__ out, int n) {
  __shared__ float swu[128];
  __shared__ float sw2[256];
  int tid = threadIdx.x;
  if (tid < 128) swu[tid] = wu[tid];
  sw2[tid] = w2[tid];
  __syncthreads();
  int i = blockIdx.x * blockDim.x + tid;
  if (i >= n) return;
  float m0 = 0.f, m1 = 0.f;
  int r0 = rowptr[i], r1 = rowptr[i + 1];
  int jj = r0;
  for (; jj + 4 <= r1; jj += 4) {
    int e0 = csr_eid[jj + 0], e1 = csr_eid[jj + 1];
    int e2 = csr_eid[jj + 2], e3 = csr_eid[jj + 3];
    float2 q0 = *(const float2*)&pbuf[2 * e0];
    float2 q1 = *(const float2*)&pbuf[2 * e1];
    float2 q2 = *(const float2*)&pbuf[2 * e2];
    float2 q3 = *(const float2*)&pbuf[2 * e3];
    m0 += (q0.x + q1.x) + (q2.x + q3.x);
    m1 += (q0.y + q1.y) + (q2.y + q3.y);
  }
  for (; jj < r1; ++jj) {
    int e = csr_eid[jj];
    float2 q = *(const float2*)&pbuf[2 * e];
    m0 += q.x; m1 += q.y;
  }
  const float* nr = node_repr + (size_t)i * 64;
  float u0 = bu[0], u1 = bu[1];
  #pragma unroll
  for (int k = 0; k < 64; ++k) {
    float v = nr[k];
    u0 = fmaf(v, swu[2 * k + 0], u0);
    u1 = fmaf(v, swu[2 * k + 1], u1);
  }
  float v0 = u0 + m0;
  float v1 = u1 + m1;
  float mx = fmaxf(v0, v1);
  float lse = mx + logf(__expf(v0 - mx) + __expf(v1 - mx));
  out[2 * i + 0] = v0 - lse;
  out[2 * i + 1] = v1 - lse;
  const float* p = ph + (size_t)i * 128;
  float p0 = b2[0], p1 = b2[1];
  #pragma unroll
  for (int k = 0; k < 128; ++k) {
    float v = p[k];
    p0 = fmaf(v, sw2[2 * k + 0], p0);
    p1 = fmaf(v, sw2[2 * k + 1], p1);
  }
  out[2 * n + 2 * i + 0] = p0;
  out[2 * n + 2 * i + 1] = p1;
}

// ======================= launch =======================
extern "C" void kernel_launch(void* const* d_in, const int* in_sizes, int n_in,
                              void* d_out, int out_size, void* d_ws, size_t ws_size,
                              hipStream_t stream) {
  const int N = N_NODES, E = N_EDGES;
  const float* x         = (const float*)d_in[0];
  const float* edge_type = (const float*)d_in[1];
  const int*   ei        = (const int*)d_in[2];
  const float* n1_wl  = (const float*)d_in[3];
  const float* n1_wr  = (const float*)d_in[4];
  const float* n1_att = (const float*)d_in[5];
  const float* n1_b   = (const float*)d_in[6];
  const float* n2_wl  = (const float*)d_in[7];
  const float* n2_wr  = (const float*)d_in[8];
  const float* n2_att = (const float*)d_in[9];
  const float* n2_b   = (const float*)d_in[10];
  const float* e1_wl  = (const float*)d_in[11];
  const float* e1_wr  = (const float*)d_in[12];
  const float* e1_att = (const float*)d_in[13];
  const float* e1_b   = (const float*)d_in[14];
  const float* e2_wl  = (const float*)d_in[15];
  const float* e2_wr  = (const float*)d_in[16];
  const float* e2_att = (const float*)d_in[17];
  const float* e2_b   = (const float*)d_in[18];
  const float* crf_wu = (const float*)d_in[19];
  const float* crf_bu = (const float*)d_in[20];
  const float* crf_wp = (const float*)d_in[21];
  const float* px_w1  = (const float*)d_in[22];
  const float* px_b1  = (const float*)d_in[23];
  const float* px_w2  = (const float*)d_in[24];
  const float* px_b2  = (const float*)d_in[25];
  float* out = (float*)d_out;
  const int* src = ei;
  const int* dst = ei + E;
  (void)in_sizes; (void)n_in; (void)out_size; (void)ws_size;

  // ---- workspace layout ----
  char* ws = (char*)d_ws;
  size_t off = 0;
  auto alloc = [&](size_t bytes) -> void* {
    void* p = ws + off;
    off += (bytes + 255) & ~(size_t)255;
    return p;
  };
  char* arena0 = (char*)alloc((size_t)N * 256 * 4);  // xl bf16 [N,256] / ph fp32 [N,128]
  float* arena1 = (float*)alloc((size_t)N * 256 * 4); // xr fp32
  float* arena2 = (float*)alloc((size_t)N * 256 * 4); // h / g_low fp32
  bfu* xl_bf   = (bfu*)arena0;
  float* ph    = (float*)arena0;
  float* B3    = (float*)alloc((size_t)N * 64 * 4);    // node_repr
  float* erlow = (float*)alloc((size_t)N * 64 * 4);    // edge_repr rows < N
  float* pbuf  = (float*)alloc((size_t)E * 2 * 4);     // per-edge CRF p-pairs
  int* deg     = (int*)alloc((size_t)N * 4);
  int* rowptr  = (int*)alloc((size_t)(N + 1) * 4);
  int* cursor  = (int*)alloc((size_t)N * 4);
  int* csr_src = (int*)alloc((size_t)E * 4);
  int* csr_eid = (int*)alloc((size_t)E * 4);
  short* W1t   = (short*)alloc((size_t)256 * 64 * 2);
  float* WcT   = (float*)alloc((size_t)2 * 256 * 4);
  float* pcv   = (float*)alloc((size_t)2 * 4);

  const int EB = (E + 255) / 256;
  const int NB = (N + 127) / 128;        // 157
  const int Mhigh = E - N;               // 300000
  const int CFB = (Mhigh + 127) / 128;   // 2344

  hipMemsetAsync(deg, 0, (size_t)N * 4, stream);
  count_deg_kernel<<<EB, 256, 0, stream>>>(dst, deg, E);
  scan_kernel<<<1, 1024, 0, stream>>>(deg, rowptr, cursor, N);
  fill_csr_kernel<<<EB, 256, 0, stream>>>(src, dst, cursor, csr_src, csr_eid, E);
  prep_weights_kernel<<<68, 256, 0, stream>>>(e1_wl, e2_wl, e2_b, crf_wp, W1t, WcT, pcv);

  // ---- node layer 1: GATv2(64 -> 4x64, concat) + elu ----
  gemm_pair256_kernel<64><<<dim3(NB, 8), 256, 0, stream>>>(x, n1_wl, n1_wr, xl_bf, arena1, N);
  gat_agg_v2<true, 256><<<N, 256, 0, stream>>>(xl_bf, arena1, n1_att, n1_b, rowptr, csr_src, arena2, 256);

  // ---- node layer 2: GATv2(256 -> 64) -> B3 ----
  gemm64_dual_kernel<256><<<dim3(NB, 2), 256, 0, stream>>>(arena2, n2_wl, n2_wr, 64, xl_bf, arena1, N);
  gat_agg_v2<false, 64><<<N, 64, 0, stream>>>(xl_bf, arena1, n2_att, n2_b, rowptr, csr_src, B3, 64);

  // ---- edge layer 1, rows < N ----
  gemm_pair256_kernel<64><<<dim3(NB, 8), 256, 0, stream>>>(edge_type, e1_wl, e1_wr, xl_bf, arena1, N);
  gat_agg_v2<true, 256><<<N, 256, 0, stream>>>(xl_bf, arena1, e1_att, e1_b, rowptr, csr_src, arena2, 256);

  // ---- edge layer 2, rows < N -> erlow ----
  gemm64_dual_kernel<256><<<dim3(NB, 2), 256, 0, stream>>>(arena2, e2_wl, e2_wr, 64, xl_bf, arena1, N);
  gat_agg_v2<false, 64><<<N, 64, 0, stream>>>(xl_bf, arena1, e2_att, e2_b, rowptr, csr_src, erlow, 64);

  // ---- CRF per-edge p pairs ----
  edge_dot_kernel<<<(N + 255) / 256, 256, 0, stream>>>(erlow, crf_wp, pbuf, N);
  chunk_fold_kernel<<<CFB, 256, 0, stream>>>(edge_type + (size_t)N * 64, W1t,
                                             e1_b, WcT, pcv, pbuf + 2 * (size_t)N, Mhigh);

  // ---- heads ----
  gemm64_kernel<64, 3><<<dim3(NB, 2), 256, 0, stream>>>(B3, px_w1, 128, px_b1, ph, 128, N);
  head_kernel<<<(N + 255) / 256, 256, 0, stream>>>(B3, ph, rowptr, csr_eid, pbuf,
                                                   crf_wu, crf_bu, px_w2, px_b2, out, N);
}

// Round 10
// 545.628 us; speedup vs baseline: 1.2791x; 1.0777x over previous
//
#include <hip/hip_runtime.h>
#include <cstddef>
#include <cstdint>

#define N_NODES 20000
#define N_EDGES 320000

typedef __attribute__((ext_vector_type(8))) short bf8_t;   // 8 x bf16 (MFMA frag)
typedef __attribute__((ext_vector_type(4))) float f4_t;    // MFMA acc / float4
typedef unsigned short bfu;                                 // bf16 storage
typedef __attribute__((ext_vector_type(4))) unsigned short us4_t;
typedef __attribute__((ext_vector_type(8))) unsigned short us8_t;

__device__ __forceinline__ short f2bf(float f) {
  unsigned u = __float_as_uint(f);
  u += 0x7fff + ((u >> 16) & 1);   // round-to-nearest-even
  return (short)(u >> 16);
}
__device__ __forceinline__ float bf2f(bfu u) {
  return __uint_as_float(((unsigned)u) << 16);
}

// ======================= CSR build =======================
__global__ void count_deg_kernel(const int* __restrict__ dst, int* __restrict__ deg, int e_cnt) {
  int e = blockIdx.x * blockDim.x + threadIdx.x;
  if (e < e_cnt) atomicAdd(&deg[dst[e]], 1);
}

__global__ void scan_kernel(const int* __restrict__ deg, int* __restrict__ rowptr,
                            int* __restrict__ cursor, int n) {
  __shared__ int sdata[1024];
  __shared__ int s_carry;
  int tid = threadIdx.x;
  if (tid == 0) s_carry = 0;
  __syncthreads();
  for (int base = 0; base < n; base += 1024) {
    int idx = base + tid;
    int v = (idx < n) ? deg[idx] : 0;
    sdata[tid] = v;
    __syncthreads();
    for (int off = 1; off < 1024; off <<= 1) {
      int t = (tid >= off) ? sdata[tid - off] : 0;
      __syncthreads();
      sdata[tid] += t;
      __syncthreads();
    }
    int excl = sdata[tid] - v;
    if (idx < n) { int val = s_carry + excl; rowptr[idx] = val; cursor[idx] = val; }
    __syncthreads();
    if (tid == 0) s_carry += sdata[1023];
    __syncthreads();
  }
  if (tid == 0) rowptr[n] = s_carry;
}

__global__ void fill_csr_kernel(const int* __restrict__ src, const int* __restrict__ dst,
                                int* __restrict__ cursor, int* __restrict__ csr_src,
                                int* __restrict__ csr_eid, int e_cnt) {
  int e = blockIdx.x * blockDim.x + threadIdx.x;
  if (e < e_cnt) {
    int pos = atomicAdd(&cursor[dst[e]], 1);
    csr_src[pos] = src[e];
    csr_eid[pos] = e;
  }
}

// ======================= weight prep: all projections -> bf16 transposed =======================
// segs 0..3: [64,256] weights -> Wt[256][64]   (n1_wl, n1_wr, e1_wl, e1_wr)
// segs 4..7: [256,64] weights -> Wt[64][256]   (n2_wl, n2_wr, e2_wl, e2_wr)
// seg 8: WcT = (e2_wl @ wp)^T fp32 [2][256] and pc = b2@wp [2]
__global__ void prep_all_kernel(
    const float* __restrict__ n1l, const float* __restrict__ n1r,
    const float* __restrict__ e1l, const float* __restrict__ e1r,
    const float* __restrict__ n2l, const float* __restrict__ n2r,
    const float* __restrict__ e2l, const float* __restrict__ e2r,
    const float* __restrict__ b2, const float* __restrict__ wp,
    short* __restrict__ t_n1l, short* __restrict__ t_n1r,
    short* __restrict__ t_e1l, short* __restrict__ t_e1r,
    short* __restrict__ t_n2l, short* __restrict__ t_n2r,
    short* __restrict__ t_e2l, short* __restrict__ t_e2r,
    float* __restrict__ wct, float* __restrict__ pc)
{
  int i = blockIdx.x * blockDim.x + threadIdx.x;
  int seg = i >> 14;
  int j = i & 16383;
  if (seg < 4) {
    const float* srcs[4] = {n1l, n1r, e1l, e1r};
    short* dsts[4] = {t_n1l, t_n1r, t_e1l, t_e1r};
    int n = j >> 6, k = j & 63;
    dsts[seg][n * 64 + k] = f2bf(srcs[seg][k * 256 + n]);
  } else if (seg < 8) {
    const float* srcs[4] = {n2l, n2r, e2l, e2r};
    short* dsts[4] = {t_n2l, t_n2r, t_e2l, t_e2r};
    int n = j >> 8, k = j & 255;
    dsts[seg - 4][n * 256 + k] = f2bf(srcs[seg - 4][k * 64 + n]);
  } else if (seg == 8) {
    if (j < 512) {
      int jj = j & 1;
      int k  = j >> 1;
      float s = 0.f;
      for (int c = 0; c < 64; ++c) s = fmaf(e2l[k * 64 + c], wp[c * 2 + jj], s);
      wct[jj * 256 + k] = s;
    } else if (j < 514) {
      int jj = j - 512;
      float s = 0.f;
      for (int c = 0; c < 64; ++c) s = fmaf(b2[c], wp[c * 2 + jj], s);
      pc[jj] = s;
    }
  }
}

// ======================= MFMA projection kernel =======================
// out[M, cb..cb+63] = A[M,K] @ W (Wt = W^T bf16 [Nout][K]).
// blockIdx.y < nslices -> xl slice (bf16 out); else -> xr slice (fp32 out).
// 2 waves x 32 rows per block; B-op = row frags, A-op = Wt frags (chunk_fold pattern):
// lane(quad,l15) reg r = C[row = rt*16 + l15][col = nt*16 + quad*4 + r].
template<int K>
__global__ __launch_bounds__(128) void mfma_proj_kernel(
    const float* __restrict__ A,
    const short* __restrict__ Wtl, const short* __restrict__ Wtr,
    bfu* __restrict__ xl, float* __restrict__ xr,
    int M, int nslices)
{
  constexpr int KC = K / 32;
  int tid = threadIdx.x;
  int w = tid >> 6, lane = tid & 63, quad = lane >> 4, l15 = lane & 15;
  int row_base = (int)blockIdx.x * 64 + w * 32;
  int y = (int)blockIdx.y;
  bool is_l = y < nslices;
  const short* Wt = is_l ? Wtl : Wtr;
  int cb = (is_l ? y : y - nslices) * 64;
  int STR = nslices * 64;

  // row frags (B-op): lane l15 = row, k = kc*32 + quad*8 + j
  bf8_t a[2][KC];
  #pragma unroll
  for (int rt = 0; rt < 2; ++rt) {
    int r = row_base + rt * 16 + l15;
    int rc = r < M ? r : M - 1;
    const float* ap = A + (size_t)rc * K + quad * 8;
    #pragma unroll
    for (int kc = 0; kc < KC; ++kc) {
      float4 v0 = *(const float4*)(ap + kc * 32);
      float4 v1 = *(const float4*)(ap + kc * 32 + 4);
      bf8_t f;
      f[0] = f2bf(v0.x); f[1] = f2bf(v0.y); f[2] = f2bf(v0.z); f[3] = f2bf(v0.w);
      f[4] = f2bf(v1.x); f[5] = f2bf(v1.y); f[6] = f2bf(v1.z); f[7] = f2bf(v1.w);
      a[rt][kc] = f;
    }
  }

  #pragma unroll
  for (int nt = 0; nt < 4; ++nt) {
    f4_t acc0 = {0.f, 0.f, 0.f, 0.f};
    f4_t acc1 = {0.f, 0.f, 0.f, 0.f};
    const short* wb = Wt + (size_t)(cb + nt * 16 + l15) * K + quad * 8;
    #pragma unroll
    for (int kc = 0; kc < KC; ++kc) {
      bf8_t wf = *(const bf8_t*)(wb + kc * 32);
      acc0 = __builtin_amdgcn_mfma_f32_16x16x32_bf16(wf, a[0][kc], acc0, 0, 0, 0);
      acc1 = __builtin_amdgcn_mfma_f32_16x16x32_bf16(wf, a[1][kc], acc1, 0, 0, 0);
    }
    #pragma unroll
    for (int rt = 0; rt < 2; ++rt) {
      f4_t acc = rt == 0 ? acc0 : acc1;
      int row = row_base + rt * 16 + l15;
      if (row >= M) continue;
      int col = cb + nt * 16 + quad * 4;
      if (is_l) {
        us4_t pk;
        pk[0] = (bfu)f2bf(acc[0]); pk[1] = (bfu)f2bf(acc[1]);
        pk[2] = (bfu)f2bf(acc[2]); pk[3] = (bfu)f2bf(acc[3]);
        *(us4_t*)&xl[(size_t)row * STR + col] = pk;
      } else {
        *(float4*)&xr[(size_t)row * STR + col] = make_float4(acc[0], acc[1], acc[2], acc[3]);
      }
    }
  }
}

// ======================= fp32 GEMM (proxy head only) =======================
template<int KIN>
__device__ __forceinline__ void gemm_body(
    const float* __restrict__ A, const float* __restrict__ W, int wld, int cb,
    int block_m, int M, float (&acc)[8][4],
    float (*As)[128 + 4], float (*Ws)[64 + 4])
{
  int tid = threadIdx.x;
  int tx = tid & 15;
  int ty = tid >> 4;
  #pragma unroll
  for (int i = 0; i < 8; ++i)
    #pragma unroll
    for (int j = 0; j < 4; ++j) acc[i][j] = 0.f;

  for (int k0 = 0; k0 < KIN; k0 += 16) {
    #pragma unroll
    for (int rep = 0; rep < 2; ++rep) {
      int ar = (tid >> 2) + rep * 64;
      int ak = (tid & 3) * 4;
      int gr = block_m + ar;
      float4 v = make_float4(0.f, 0.f, 0.f, 0.f);
      if (gr < M) v = *(const float4*)&A[(size_t)gr * KIN + k0 + ak];
      As[ak + 0][ar] = v.x; As[ak + 1][ar] = v.y;
      As[ak + 2][ar] = v.z; As[ak + 3][ar] = v.w;
    }
    {
      int wr = tid >> 4;
      int wc = (tid & 15) * 4;
      float4 v = *(const float4*)&W[(size_t)(k0 + wr) * wld + cb + wc];
      Ws[wr][wc + 0] = v.x; Ws[wr][wc + 1] = v.y;
      Ws[wr][wc + 2] = v.z; Ws[wr][wc + 3] = v.w;
    }
    __syncthreads();
    #pragma unroll
    for (int k = 0; k < 16; ++k) {
      float a[8], w[4];
      #pragma unroll
      for (int i = 0; i < 8; ++i) a[i] = As[k][ty * 8 + i];
      #pragma unroll
      for (int j = 0; j < 4; ++j) w[j] = Ws[k][tx * 4 + j];
      #pragma unroll
      for (int i = 0; i < 8; ++i)
        #pragma unroll
        for (int j = 0; j < 4; ++j) acc[i][j] = fmaf(a[i], w[j], acc[i][j]);
    }
    __syncthreads();
  }
}

template<int KIN, int MODE>
__global__ __launch_bounds__(256) void gemm64_kernel(
    const float* __restrict__ A, const float* __restrict__ W, int wld,
    const float* __restrict__ bias, float* __restrict__ out, int old, int M)
{
  __shared__ float As[16][128 + 4];
  __shared__ float Ws[16][64 + 4];
  float acc[8][4];
  int block_m = (int)blockIdx.x * 128;
  int cb = (int)blockIdx.y * 64;
  gemm_body<KIN>(A, W, wld, cb, block_m, M, acc, As, Ws);

  int tid = threadIdx.x;
  int tx = tid & 15, ty = tid >> 4;
  int gc = cb + tx * 4;
  #pragma unroll
  for (int i = 0; i < 8; ++i) {
    int gr = block_m + ty * 8 + i;
    if (gr >= M) continue;
    size_t idx = (size_t)gr * old + gc;
    float t0 = acc[i][0], t1 = acc[i][1], t2 = acc[i][2], t3 = acc[i][3];
    if (MODE == 3) {
      t0 = fmaxf(t0 + bias[gc + 0], 0.f);
      t1 = fmaxf(t1 + bias[gc + 1], 0.f);
      t2 = fmaxf(t2 + bias[gc + 2], 0.f);
      t3 = fmaxf(t3 + bias[gc + 3], 0.f);
    }
    *(float4*)&out[idx] = make_float4(t0, t1, t2, t3);
  }
}

// ======================= GATv2 aggregation v2 =======================
template<bool ELU, int STR>
__global__ __launch_bounds__(STR == 256 ? 256 : 64) void gat_agg_v2(
    const bfu* __restrict__ xl, const float* __restrict__ xr,
    const float* __restrict__ att, const float* __restrict__ bias,
    const int* __restrict__ rowptr, const int* __restrict__ csr_src,
    float* __restrict__ out, int old)
{
  int d = blockIdx.x;
  int tid = threadIdx.x;
  int h = tid >> 6;
  int lane = tid & 63;
  int egrp = lane >> 3;
  int cch  = lane & 7;
  int row0 = rowptr[d];
  int deg = rowptr[d + 1] - row0;
  int cbase = h * 64 + cch * 8;

  float xrv[8], attv[8];
  {
    const float* xrp = xr + (size_t)d * STR + cbase;
    const float* atp = att + cbase;
    float4 a0 = *(const float4*)(xrp);
    float4 a1 = *(const float4*)(xrp + 4);
    xrv[0] = a0.x; xrv[1] = a0.y; xrv[2] = a0.z; xrv[3] = a0.w;
    xrv[4] = a1.x; xrv[5] = a1.y; xrv[6] = a1.z; xrv[7] = a1.w;
    float4 b0 = *(const float4*)(atp);
    float4 b1 = *(const float4*)(atp + 4);
    attv[0] = b0.x; attv[1] = b0.y; attv[2] = b0.z; attv[3] = b0.w;
    attv[4] = b1.x; attv[5] = b1.y; attv[6] = b1.z; attv[7] = b1.w;
  }

  float m, zloc;
  float acc8[8];
  {
    us8_t xu = *(const us8_t*)&xl[(size_t)d * STR + cbase];
    float part = 0.f;
    #pragma unroll
    for (int i = 0; i < 8; ++i) {
      float xs = bf2f(xu[i]);
      float t = xs + xrv[i];
      t = t > 0.f ? t : 0.2f * t;
      part = fmaf(t, attv[i], part);
      acc8[i] = (egrp == 0) ? xs : 0.f;
    }
    part += __shfl_xor(part, 1, 64);
    part += __shfl_xor(part, 2, 64);
    part += __shfl_xor(part, 4, 64);
    m = part;
    zloc = (egrp == 0) ? 1.f : 0.f;
  }

  for (int j = 0; j < deg; j += 8) {
    int idx = j + egrp;
    bool valid = idx < deg;
    int s = valid ? csr_src[row0 + idx] : d;
    us8_t xu = *(const us8_t*)&xl[(size_t)s * STR + cbase];
    float xf[8];
    float part = 0.f;
    #pragma unroll
    for (int i = 0; i < 8; ++i) {
      xf[i] = bf2f(xu[i]);
      float t = xf[i] + xrv[i];
      t = t > 0.f ? t : 0.2f * t;
      part = fmaf(t, attv[i], part);
    }
    part += __shfl_xor(part, 1, 64);
    part += __shfl_xor(part, 2, 64);
    part += __shfl_xor(part, 4, 64);
    float logit = valid ? part : -1e30f;
    float gmax = logit;
    gmax = fmaxf(gmax, __shfl_xor(gmax, 8, 64));
    gmax = fmaxf(gmax, __shfl_xor(gmax, 16, 64));
    gmax = fmaxf(gmax, __shfl_xor(gmax, 32, 64));
    float mn = fmaxf(m, gmax);
    float sc = __expf(m - mn);
    float w  = __expf(logit - mn);
    zloc = zloc * sc + w;
    #pragma unroll
    for (int i = 0; i < 8; ++i) acc8[i] = fmaf(w, xf[i], acc8[i] * sc);
    m = mn;
  }

  #pragma unroll
  for (int off = 8; off < 64; off <<= 1) {
    zloc += __shfl_xor(zloc, off, 64);
    #pragma unroll
    for (int i = 0; i < 8; ++i) acc8[i] += __shfl_xor(acc8[i], off, 64);
  }

  if (egrp == 0) {
    float invz = 1.f / zloc;
    float o[8];
    #pragma unroll
    for (int i = 0; i < 8; ++i) {
      float val = acc8[i] * invz + bias[cbase + i];
      if (ELU) val = val > 0.f ? val : __expf(val) - 1.f;
      o[i] = val;
    }
    float* op = out + (size_t)d * old + cbase;
    *(float4*)(op)     = make_float4(o[0], o[1], o[2], o[3]);
    *(float4*)(op + 4) = make_float4(o[4], o[5], o[6], o[7]);
  }
}

// ======================= folded chunk kernel (edge rows >= N) =======================
__global__ __launch_bounds__(256) void chunk_fold_kernel(
    const float* __restrict__ A,      // edge_type + N*64
    const short* __restrict__ W1t,    // [256][64] bf16 (n,k) == W1^T
    const float* __restrict__ b1,     // [256]
    const float* __restrict__ WcT,    // [2][256] fp32
    const float* __restrict__ pc,     // [2]
    float* __restrict__ pbufN,        // pbuf + 2*N_NODES
    int Mtot)
{
  int tid = threadIdx.x;
  int w = tid >> 6;
  int lane = tid & 63;
  int quad = lane >> 4;
  int l15 = lane & 15;
  int row_base = (int)blockIdx.x * 128 + w * 32;

  bf8_t a1[2][2];
  #pragma unroll
  for (int rt = 0; rt < 2; ++rt) {
    int r = row_base + rt * 16 + l15;
    int rc = r < Mtot ? r : Mtot - 1;
    const float* ap = A + (size_t)rc * 64 + quad * 8;
    #pragma unroll
    for (int ks = 0; ks < 2; ++ks) {
      float4 v0 = *(const float4*)(ap + ks * 32);
      float4 v1 = *(const float4*)(ap + ks * 32 + 4);
      bf8_t f;
      f[0] = f2bf(v0.x); f[1] = f2bf(v0.y); f[2] = f2bf(v0.z); f[3] = f2bf(v0.w);
      f[4] = f2bf(v1.x); f[5] = f2bf(v1.y); f[6] = f2bf(v1.z); f[7] = f2bf(v1.w);
      a1[rt][ks] = f;
    }
  }

  float p0[2] = {0.f, 0.f};
  float p1[2] = {0.f, 0.f};

  for (int cc = 0; cc < 4; ++cc) {
    #pragma unroll
    for (int nt = 0; nt < 4; ++nt) {
      const short* wb = W1t + (cc * 64 + nt * 16 + l15) * 64 + quad * 8;
      bf8_t w0 = *(const bf8_t*)(wb);
      bf8_t w1 = *(const bf8_t*)(wb + 32);
      f4_t g0 = {0.f, 0.f, 0.f, 0.f};
      f4_t g1 = {0.f, 0.f, 0.f, 0.f};
      g0 = __builtin_amdgcn_mfma_f32_16x16x32_bf16(w0, a1[0][0], g0, 0, 0, 0);
      g0 = __builtin_amdgcn_mfma_f32_16x16x32_bf16(w1, a1[0][1], g0, 0, 0, 0);
      g1 = __builtin_amdgcn_mfma_f32_16x16x32_bf16(w0, a1[1][0], g1, 0, 0, 0);
      g1 = __builtin_amdgcn_mfma_f32_16x16x32_bf16(w1, a1[1][1], g1, 0, 0, 0);
      int cbase = cc * 64 + nt * 16 + quad * 4;
      f4_t b4  = *(const f4_t*)&b1[cbase];
      f4_t wc0 = *(const f4_t*)&WcT[cbase];
      f4_t wc1 = *(const f4_t*)&WcT[256 + cbase];
      #pragma unroll
      for (int r = 0; r < 4; ++r) {
        float v0 = g0[r] + b4[r];
        v0 = v0 > 0.f ? v0 : __expf(v0) - 1.f;
        p0[0] = fmaf(v0, wc0[r], p0[0]);
        p1[0] = fmaf(v0, wc1[r], p1[0]);
        float v1 = g1[r] + b4[r];
        v1 = v1 > 0.f ? v1 : __expf(v1) - 1.f;
        p0[1] = fmaf(v1, wc0[r], p0[1]);
        p1[1] = fmaf(v1, wc1[r], p1[1]);
      }
    }
  }

  #pragma unroll
  for (int off = 16; off < 64; off <<= 1) {
    p0[0] += __shfl_xor(p0[0], off, 64);
    p0[1] += __shfl_xor(p0[1], off, 64);
    p1[0] += __shfl_xor(p1[0], off, 64);
    p1[1] += __shfl_xor(p1[1], off, 64);
  }
  if (quad == 0) {
    float c0 = pc[0], c1 = pc[1];
    int row0 = row_base + l15;
    int row1 = row_base + 16 + l15;
    if (row0 < Mtot) *(float2*)&pbufN[2 * row0] = make_float2(p0[0] + c0, p1[0] + c1);
    if (row1 < Mtot) *(float2*)&pbufN[2 * row1] = make_float2(p0[1] + c0, p1[1] + c1);
  }
}

// ======================= per-edge p for edge ids < N =======================
__global__ void edge_dot_kernel(const float* __restrict__ edge_repr, const float* __restrict__ wp,
                                float* __restrict__ pbuf, int e_cnt) {
  __shared__ float swp[128];
  if (threadIdx.x < 128) swp[threadIdx.x] = wp[threadIdx.x];
  __syncthreads();
  int e = blockIdx.x * blockDim.x + threadIdx.x;
  if (e >= e_cnt) return;
  const float* er = edge_repr + (size_t)e * 64;
  float a0 = 0.f, a1 = 0.f;
  #pragma unroll
  for (int k = 0; k < 64; ++k) {
    float v = er[k];
    a0 = fmaf(v, swp[2 * k + 0], a0);
    a1 = fmaf(v, swp[2 * k + 1], a1);
  }
  *(float2*)&pbuf[2 * e] = make_float2(a0, a1);
}

// ======================= Heads =======================
__global__ void head_kernel(const float* __restrict__ node_repr, const float* __restrict__ ph,
                            const int* __restrict__ rowptr, const int* __restrict__ csr_eid,
                            const float* __restrict__ pbuf, const float* __restrict__ wu,
                            const float* __restrict__ bu, const float* __restrict__ w2,
                            const float* __restrict__ b2, float* __restrict__ out, int n) {
  __shared__ float swu[128];
  __shared__ float sw2[256];
  int tid = threadIdx.x;
  if (tid < 128) swu[tid] = wu[tid];
  sw2[tid] = w2[tid];
  __syncthreads();
  int i = blockIdx.x * blockDim.x + tid;
  if (i >= n) return;
  float m0 = 0.f, m1 = 0.f;
  int r0 = rowptr[i], r1 = rowptr[i + 1];
  int jj = r0;
  for (; jj + 4 <= r1; jj += 4) {
    int e0 = csr_eid[jj + 0], e1 = csr_eid[jj + 1];
    int e2 = csr_eid[jj + 2], e3 = csr_eid[jj + 3];
    float2 q0 = *(const float2*)&pbuf[2 * e0];
    float2 q1 = *(const float2*)&pbuf[2 * e1];
    float2 q2 = *(const float2*)&pbuf[2 * e2];
    float2 q3 = *(const float2*)&pbuf[2 * e3];
    m0 += (q0.x + q1.x) + (q2.x + q3.x);
    m1 += (q0.y + q1.y) + (q2.y + q3.y);
  }
  for (; jj < r1; ++jj) {
    int e = csr_eid[jj];
    float2 q = *(const float2*)&pbuf[2 * e];
    m0 += q.x; m1 += q.y;
  }
  const float* nr = node_repr + (size_t)i * 64;
  float u0 = bu[0], u1 = bu[1];
  #pragma unroll
  for (int k = 0; k < 64; ++k) {
    float v = nr[k];
    u0 = fmaf(v, swu[2 * k + 0], u0);
    u1 = fmaf(v, swu[2 * k + 1], u1);
  }
  float v0 = u0 + m0;
  float v1 = u1 + m1;
  float mx = fmaxf(v0, v1);
  float lse = mx + logf(__expf(v0 - mx) + __expf(v1 - mx));
  out[2 * i + 0] = v0 - lse;
  out[2 * i + 1] = v1 - lse;
  const float* p = ph + (size_t)i * 128;
  float p0 = b2[0], p1 = b2[1];
  #pragma unroll
  for (int k = 0; k < 128; ++k) {
    float v = p[k];
    p0 = fmaf(v, sw2[2 * k + 0], p0);
    p1 = fmaf(v, sw2[2 * k + 1], p1);
  }
  out[2 * n + 2 * i + 0] = p0;
  out[2 * n + 2 * i + 1] = p1;
}

// ======================= launch =======================
extern "C" void kernel_launch(void* const* d_in, const int* in_sizes, int n_in,
                              void* d_out, int out_size, void* d_ws, size_t ws_size,
                              hipStream_t stream) {
  const int N = N_NODES, E = N_EDGES;
  const float* x         = (const float*)d_in[0];
  const float* edge_type = (const float*)d_in[1];
  const int*   ei        = (const int*)d_in[2];
  const float* n1_wl  = (const float*)d_in[3];
  const float* n1_wr  = (const float*)d_in[4];
  const float* n1_att = (const float*)d_in[5];
  const float* n1_b   = (const float*)d_in[6];
  const float* n2_wl  = (const float*)d_in[7];
  const float* n2_wr  = (const float*)d_in[8];
  const float* n2_att = (const float*)d_in[9];
  const float* n2_b   = (const float*)d_in[10];
  const float* e1_wl  = (const float*)d_in[11];
  const float* e1_wr  = (const float*)d_in[12];
  const float* e1_att = (const float*)d_in[13];
  const float* e1_b   = (const float*)d_in[14];
  const float* e2_wl  = (const float*)d_in[15];
  const float* e2_wr  = (const float*)d_in[16];
  const float* e2_att = (const float*)d_in[17];
  const float* e2_b   = (const float*)d_in[18];
  const float* crf_wu = (const float*)d_in[19];
  const float* crf_bu = (const float*)d_in[20];
  const float* crf_wp = (const float*)d_in[21];
  const float* px_w1  = (const float*)d_in[22];
  const float* px_b1  = (const float*)d_in[23];
  const float* px_w2  = (const float*)d_in[24];
  const float* px_b2  = (const float*)d_in[25];
  float* out = (float*)d_out;
  const int* src = ei;
  const int* dst = ei + E;
  (void)in_sizes; (void)n_in; (void)out_size; (void)ws_size;

  // ---- workspace layout ----
  char* ws = (char*)d_ws;
  size_t off = 0;
  auto alloc = [&](size_t bytes) -> void* {
    void* p = ws + off;
    off += (bytes + 255) & ~(size_t)255;
    return p;
  };
  char* arena0 = (char*)alloc((size_t)N * 256 * 4);  // xl bf16 [N,256] / ph fp32 [N,128]
  float* arena1 = (float*)alloc((size_t)N * 256 * 4); // xr fp32
  float* arena2 = (float*)alloc((size_t)N * 256 * 4); // h / g_low fp32
  bfu* xl_bf   = (bfu*)arena0;
  float* ph    = (float*)arena0;
  float* B3    = (float*)alloc((size_t)N * 64 * 4);    // node_repr
  float* erlow = (float*)alloc((size_t)N * 64 * 4);    // edge_repr rows < N
  float* pbuf  = (float*)alloc((size_t)E * 2 * 4);     // per-edge CRF p-pairs
  int* deg     = (int*)alloc((size_t)N * 4);
  int* rowptr  = (int*)alloc((size_t)(N + 1) * 4);
  int* cursor  = (int*)alloc((size_t)N * 4);
  int* csr_src = (int*)alloc((size_t)E * 4);
  int* csr_eid = (int*)alloc((size_t)E * 4);
  short* t_n1l = (short*)alloc((size_t)16384 * 2);
  short* t_n1r = (short*)alloc((size_t)16384 * 2);
  short* t_e1l = (short*)alloc((size_t)16384 * 2);   // == W1t for chunk_fold
  short* t_e1r = (short*)alloc((size_t)16384 * 2);
  short* t_n2l = (short*)alloc((size_t)16384 * 2);
  short* t_n2r = (short*)alloc((size_t)16384 * 2);
  short* t_e2l = (short*)alloc((size_t)16384 * 2);
  short* t_e2r = (short*)alloc((size_t)16384 * 2);
  float* WcT   = (float*)alloc((size_t)2 * 256 * 4);
  float* pcv   = (float*)alloc((size_t)2 * 4);

  const int EB = (E + 255) / 256;
  const int NB = (N + 127) / 128;        // 157 (px GEMM)
  const int PB = (N + 63) / 64;          // 313 (mfma proj)
  const int Mhigh = E - N;               // 300000
  const int CFB = (Mhigh + 127) / 128;   // 2344

  hipMemsetAsync(deg, 0, (size_t)N * 4, stream);
  count_deg_kernel<<<EB, 256, 0, stream>>>(dst, deg, E);
  scan_kernel<<<1, 1024, 0, stream>>>(deg, rowptr, cursor, N);
  fill_csr_kernel<<<EB, 256, 0, stream>>>(src, dst, cursor, csr_src, csr_eid, E);
  prep_all_kernel<<<515, 256, 0, stream>>>(n1_wl, n1_wr, e1_wl, e1_wr,
                                           n2_wl, n2_wr, e2_wl, e2_wr,
                                           e2_b, crf_wp,
                                           t_n1l, t_n1r, t_e1l, t_e1r,
                                           t_n2l, t_n2r, t_e2l, t_e2r, WcT, pcv);

  // ---- node layer 1: GATv2(64 -> 4x64, concat) + elu ----
  mfma_proj_kernel<64><<<dim3(PB, 8), 128, 0, stream>>>(x, t_n1l, t_n1r, xl_bf, arena1, N, 4);
  gat_agg_v2<true, 256><<<N, 256, 0, stream>>>(xl_bf, arena1, n1_att, n1_b, rowptr, csr_src, arena2, 256);

  // ---- node layer 2: GATv2(256 -> 64) -> B3 ----
  mfma_proj_kernel<256><<<dim3(PB, 2), 128, 0, stream>>>(arena2, t_n2l, t_n2r, xl_bf, arena1, N, 1);
  gat_agg_v2<false, 64><<<N, 64, 0, stream>>>(xl_bf, arena1, n2_att, n2_b, rowptr, csr_src, B3, 64);

  // ---- edge layer 1, rows < N ----
  mfma_proj_kernel<64><<<dim3(PB, 8), 128, 0, stream>>>(edge_type, t_e1l, t_e1r, xl_bf, arena1, N, 4);
  gat_agg_v2<true, 256><<<N, 256, 0, stream>>>(xl_bf, arena1, e1_att, e1_b, rowptr, csr_src, arena2, 256);

  // ---- edge layer 2, rows < N -> erlow ----
  mfma_proj_kernel<256><<<dim3(PB, 2), 128, 0, stream>>>(arena2, t_e2l, t_e2r, xl_bf, arena1, N, 1);
  gat_agg_v2<false, 64><<<N, 64, 0, stream>>>(xl_bf, arena1, e2_att, e2_b, rowptr, csr_src, erlow, 64);

  // ---- CRF per-edge p pairs ----
  edge_dot_kernel<<<(N + 255) / 256, 256, 0, stream>>>(erlow, crf_wp, pbuf, N);
  chunk_fold_kernel<<<CFB, 256, 0, stream>>>(edge_type + (size_t)N * 64, t_e1l,
                                             e1_b, WcT, pcv, pbuf + 2 * (size_t)N, Mhigh);

  // ---- heads ----
  gemm64_kernel<64, 3><<<dim3(NB, 2), 256, 0, stream>>>(B3, px_w1, 128, px_b1, ph, 128, N);
  head_kernel<<<(N + 255) / 256, 256, 0, stream>>>(B3, ph, rowptr, csr_eid, pbuf,
                                                   crf_wu, crf_bu, px_w2, px_b2, out, N);
}

// Round 11
// 521.146 us; speedup vs baseline: 1.3392x; 1.0470x over previous
//
#include <hip/hip_runtime.h>
#include <cstddef>
#include <cstdint>

#define N_NODES 20000
#define N_EDGES 320000

typedef __attribute__((ext_vector_type(8))) short bf8_t;   // 8 x bf16 (MFMA frag)
typedef __attribute__((ext_vector_type(4))) float f4_t;    // MFMA acc / float4
typedef unsigned short bfu;                                 // bf16 storage
typedef __attribute__((ext_vector_type(4))) unsigned short us4_t;
typedef __attribute__((ext_vector_type(8))) unsigned short us8_t;

__device__ __forceinline__ short f2bf(float f) {
  unsigned u = __float_as_uint(f);
  u += 0x7fff + ((u >> 16) & 1);   // round-to-nearest-even
  return (short)(u >> 16);
}
__device__ __forceinline__ float bf2f(bfu u) {
  return __uint_as_float(((unsigned)u) << 16);
}

// ======================= CSR build =======================
__global__ void count_deg_kernel(const int* __restrict__ dst, int* __restrict__ deg, int e_cnt) {
  int e = blockIdx.x * blockDim.x + threadIdx.x;
  if (e < e_cnt) atomicAdd(&deg[dst[e]], 1);
}

__global__ void scan_kernel(const int* __restrict__ deg, int* __restrict__ rowptr,
                            int* __restrict__ cursor, int n) {
  __shared__ int sdata[1024];
  __shared__ int s_carry;
  int tid = threadIdx.x;
  if (tid == 0) s_carry = 0;
  __syncthreads();
  for (int base = 0; base < n; base += 1024) {
    int idx = base + tid;
    int v = (idx < n) ? deg[idx] : 0;
    sdata[tid] = v;
    __syncthreads();
    for (int off = 1; off < 1024; off <<= 1) {
      int t = (tid >= off) ? sdata[tid - off] : 0;
      __syncthreads();
      sdata[tid] += t;
      __syncthreads();
    }
    int excl = sdata[tid] - v;
    if (idx < n) { int val = s_carry + excl; rowptr[idx] = val; cursor[idx] = val; }
    __syncthreads();
    if (tid == 0) s_carry += sdata[1023];
    __syncthreads();
  }
  if (tid == 0) rowptr[n] = s_carry;
}

__global__ void fill_csr_kernel(const int* __restrict__ src, const int* __restrict__ dst,
                                int* __restrict__ cursor, int* __restrict__ csr_src,
                                int* __restrict__ csr_eid, int e_cnt) {
  int e = blockIdx.x * blockDim.x + threadIdx.x;
  if (e < e_cnt) {
    int pos = atomicAdd(&cursor[dst[e]], 1);
    csr_src[pos] = src[e];
    csr_eid[pos] = e;
  }
}

// ======================= weight prep: all projections -> bf16 transposed =======================
__global__ void prep_all_kernel(
    const float* __restrict__ n1l, const float* __restrict__ n1r,
    const float* __restrict__ e1l, const float* __restrict__ e1r,
    const float* __restrict__ n2l, const float* __restrict__ n2r,
    const float* __restrict__ e2l, const float* __restrict__ e2r,
    const float* __restrict__ b2, const float* __restrict__ wp,
    short* __restrict__ t_n1l, short* __restrict__ t_n1r,
    short* __restrict__ t_e1l, short* __restrict__ t_e1r,
    short* __restrict__ t_n2l, short* __restrict__ t_n2r,
    short* __restrict__ t_e2l, short* __restrict__ t_e2r,
    float* __restrict__ wct, float* __restrict__ pc)
{
  int i = blockIdx.x * blockDim.x + threadIdx.x;
  int seg = i >> 14;
  int j = i & 16383;
  if (seg < 4) {
    const float* srcs[4] = {n1l, n1r, e1l, e1r};
    short* dsts[4] = {t_n1l, t_n1r, t_e1l, t_e1r};
    int n = j >> 6, k = j & 63;
    dsts[seg][n * 64 + k] = f2bf(srcs[seg][k * 256 + n]);
  } else if (seg < 8) {
    const float* srcs[4] = {n2l, n2r, e2l, e2r};
    short* dsts[4] = {t_n2l, t_n2r, t_e2l, t_e2r};
    int n = j >> 8, k = j & 255;
    dsts[seg - 4][n * 256 + k] = f2bf(srcs[seg - 4][k * 64 + n]);
  } else if (seg == 8) {
    if (j < 512) {
      int jj = j & 1;
      int k  = j >> 1;
      float s = 0.f;
      for (int c = 0; c < 64; ++c) s = fmaf(e2l[k * 64 + c], wp[c * 2 + jj], s);
      wct[jj * 256 + k] = s;
    } else if (j < 514) {
      int jj = j - 512;
      float s = 0.f;
      for (int c = 0; c < 64; ++c) s = fmaf(b2[c], wp[c * 2 + jj], s);
      pc[jj] = s;
    }
  }
}

// ======================= MFMA projection kernel =======================
template<int K>
__global__ __launch_bounds__(128) void mfma_proj_kernel(
    const float* __restrict__ A,
    const short* __restrict__ Wtl, const short* __restrict__ Wtr,
    bfu* __restrict__ xl, float* __restrict__ xr,
    int M, int nslices)
{
  constexpr int KC = K / 32;
  int tid = threadIdx.x;
  int w = tid >> 6, lane = tid & 63, quad = lane >> 4, l15 = lane & 15;
  int row_base = (int)blockIdx.x * 64 + w * 32;
  int y = (int)blockIdx.y;
  bool is_l = y < nslices;
  const short* Wt = is_l ? Wtl : Wtr;
  int cb = (is_l ? y : y - nslices) * 64;
  int STR = nslices * 64;

  bf8_t a[2][KC];
  #pragma unroll
  for (int rt = 0; rt < 2; ++rt) {
    int r = row_base + rt * 16 + l15;
    int rc = r < M ? r : M - 1;
    const float* ap = A + (size_t)rc * K + quad * 8;
    #pragma unroll
    for (int kc = 0; kc < KC; ++kc) {
      float4 v0 = *(const float4*)(ap + kc * 32);
      float4 v1 = *(const float4*)(ap + kc * 32 + 4);
      bf8_t f;
      f[0] = f2bf(v0.x); f[1] = f2bf(v0.y); f[2] = f2bf(v0.z); f[3] = f2bf(v0.w);
      f[4] = f2bf(v1.x); f[5] = f2bf(v1.y); f[6] = f2bf(v1.z); f[7] = f2bf(v1.w);
      a[rt][kc] = f;
    }
  }

  #pragma unroll
  for (int nt = 0; nt < 4; ++nt) {
    f4_t acc0 = {0.f, 0.f, 0.f, 0.f};
    f4_t acc1 = {0.f, 0.f, 0.f, 0.f};
    const short* wb = Wt + (size_t)(cb + nt * 16 + l15) * K + quad * 8;
    #pragma unroll
    for (int kc = 0; kc < KC; ++kc) {
      bf8_t wf = *(const bf8_t*)(wb + kc * 32);
      acc0 = __builtin_amdgcn_mfma_f32_16x16x32_bf16(wf, a[0][kc], acc0, 0, 0, 0);
      acc1 = __builtin_amdgcn_mfma_f32_16x16x32_bf16(wf, a[1][kc], acc1, 0, 0, 0);
    }
    #pragma unroll
    for (int rt = 0; rt < 2; ++rt) {
      f4_t acc = rt == 0 ? acc0 : acc1;
      int row = row_base + rt * 16 + l15;
      if (row >= M) continue;
      int col = cb + nt * 16 + quad * 4;
      if (is_l) {
        us4_t pk;
        pk[0] = (bfu)f2bf(acc[0]); pk[1] = (bfu)f2bf(acc[1]);
        pk[2] = (bfu)f2bf(acc[2]); pk[3] = (bfu)f2bf(acc[3]);
        *(us4_t*)&xl[(size_t)row * STR + col] = pk;
      } else {
        *(float4*)&xr[(size_t)row * STR + col] = make_float4(acc[0], acc[1], acc[2], acc[3]);
      }
    }
  }
}

// ======================= fp32 GEMM (proxy head only) =======================
template<int KIN>
__device__ __forceinline__ void gemm_body(
    const float* __restrict__ A, const float* __restrict__ W, int wld, int cb,
    int block_m, int M, float (&acc)[8][4],
    float (*As)[128 + 4], float (*Ws)[64 + 4])
{
  int tid = threadIdx.x;
  int tx = tid & 15;
  int ty = tid >> 4;
  #pragma unroll
  for (int i = 0; i < 8; ++i)
    #pragma unroll
    for (int j = 0; j < 4; ++j) acc[i][j] = 0.f;

  for (int k0 = 0; k0 < KIN; k0 += 16) {
    #pragma unroll
    for (int rep = 0; rep < 2; ++rep) {
      int ar = (tid >> 2) + rep * 64;
      int ak = (tid & 3) * 4;
      int gr = block_m + ar;
      float4 v = make_float4(0.f, 0.f, 0.f, 0.f);
      if (gr < M) v = *(const float4*)&A[(size_t)gr * KIN + k0 + ak];
      As[ak + 0][ar] = v.x; As[ak + 1][ar] = v.y;
      As[ak + 2][ar] = v.z; As[ak + 3][ar] = v.w;
    }
    {
      int wr = tid >> 4;
      int wc = (tid & 15) * 4;
      float4 v = *(const float4*)&W[(size_t)(k0 + wr) * wld + cb + wc];
      Ws[wr][wc + 0] = v.x; Ws[wr][wc + 1] = v.y;
      Ws[wr][wc + 2] = v.z; Ws[wr][wc + 3] = v.w;
    }
    __syncthreads();
    #pragma unroll
    for (int k = 0; k < 16; ++k) {
      float a[8], w[4];
      #pragma unroll
      for (int i = 0; i < 8; ++i) a[i] = As[k][ty * 8 + i];
      #pragma unroll
      for (int j = 0; j < 4; ++j) w[j] = Ws[k][tx * 4 + j];
      #pragma unroll
      for (int i = 0; i < 8; ++i)
        #pragma unroll
        for (int j = 0; j < 4; ++j) acc[i][j] = fmaf(a[i], w[j], acc[i][j]);
    }
    __syncthreads();
  }
}

template<int KIN, int MODE>
__global__ __launch_bounds__(256) void gemm64_kernel(
    const float* __restrict__ A, const float* __restrict__ W, int wld,
    const float* __restrict__ bias, float* __restrict__ out, int old, int M)
{
  __shared__ float As[16][128 + 4];
  __shared__ float Ws[16][64 + 4];
  float acc[8][4];
  int block_m = (int)blockIdx.x * 128;
  int cb = (int)blockIdx.y * 64;
  gemm_body<KIN>(A, W, wld, cb, block_m, M, acc, As, Ws);

  int tid = threadIdx.x;
  int tx = tid & 15, ty = tid >> 4;
  int gc = cb + tx * 4;
  #pragma unroll
  for (int i = 0; i < 8; ++i) {
    int gr = block_m + ty * 8 + i;
    if (gr >= M) continue;
    size_t idx = (size_t)gr * old + gc;
    float t0 = acc[i][0], t1 = acc[i][1], t2 = acc[i][2], t3 = acc[i][3];
    if (MODE == 3) {
      t0 = fmaxf(t0 + bias[gc + 0], 0.f);
      t1 = fmaxf(t1 + bias[gc + 1], 0.f);
      t2 = fmaxf(t2 + bias[gc + 2], 0.f);
      t3 = fmaxf(t3 + bias[gc + 3], 0.f);
    }
    *(float4*)&out[idx] = make_float4(t0, t1, t2, t3);
  }
}

// ======================= GATv2 aggregation v2 =======================
template<bool ELU, int STR>
__global__ __launch_bounds__(STR == 256 ? 256 : 64) void gat_agg_v2(
    const bfu* __restrict__ xl, const float* __restrict__ xr,
    const float* __restrict__ att, const float* __restrict__ bias,
    const int* __restrict__ rowptr, const int* __restrict__ csr_src,
    float* __restrict__ out, int old)
{
  int d = blockIdx.x;
  int tid = threadIdx.x;
  int h = tid >> 6;
  int lane = tid & 63;
  int egrp = lane >> 3;
  int cch  = lane & 7;
  int row0 = rowptr[d];
  int deg = rowptr[d + 1] - row0;
  int cbase = h * 64 + cch * 8;

  float xrv[8], attv[8];
  {
    const float* xrp = xr + (size_t)d * STR + cbase;
    const float* atp = att + cbase;
    float4 a0 = *(const float4*)(xrp);
    float4 a1 = *(const float4*)(xrp + 4);
    xrv[0] = a0.x; xrv[1] = a0.y; xrv[2] = a0.z; xrv[3] = a0.w;
    xrv[4] = a1.x; xrv[5] = a1.y; xrv[6] = a1.z; xrv[7] = a1.w;
    float4 b0 = *(const float4*)(atp);
    float4 b1 = *(const float4*)(atp + 4);
    attv[0] = b0.x; attv[1] = b0.y; attv[2] = b0.z; attv[3] = b0.w;
    attv[4] = b1.x; attv[5] = b1.y; attv[6] = b1.z; attv[7] = b1.w;
  }

  float m, zloc;
  float acc8[8];
  {
    us8_t xu = *(const us8_t*)&xl[(size_t)d * STR + cbase];
    float part = 0.f;
    #pragma unroll
    for (int i = 0; i < 8; ++i) {
      float xs = bf2f(xu[i]);
      float t = xs + xrv[i];
      t = t > 0.f ? t : 0.2f * t;
      part = fmaf(t, attv[i], part);
      acc8[i] = (egrp == 0) ? xs : 0.f;
    }
    part += __shfl_xor(part, 1, 64);
    part += __shfl_xor(part, 2, 64);
    part += __shfl_xor(part, 4, 64);
    m = part;
    zloc = (egrp == 0) ? 1.f : 0.f;
  }

  for (int j = 0; j < deg; j += 8) {
    int idx = j + egrp;
    bool valid = idx < deg;
    int s = valid ? csr_src[row0 + idx] : d;
    us8_t xu = *(const us8_t*)&xl[(size_t)s * STR + cbase];
    float xf[8];
    float part = 0.f;
    #pragma unroll
    for (int i = 0; i < 8; ++i) {
      xf[i] = bf2f(xu[i]);
      float t = xf[i] + xrv[i];
      t = t > 0.f ? t : 0.2f * t;
      part = fmaf(t, attv[i], part);
    }
    part += __shfl_xor(part, 1, 64);
    part += __shfl_xor(part, 2, 64);
    part += __shfl_xor(part, 4, 64);
    float logit = valid ? part : -1e30f;
    float gmax = logit;
    gmax = fmaxf(gmax, __shfl_xor(gmax, 8, 64));
    gmax = fmaxf(gmax, __shfl_xor(gmax, 16, 64));
    gmax = fmaxf(gmax, __shfl_xor(gmax, 32, 64));
    float mn = fmaxf(m, gmax);
    float sc = __expf(m - mn);
    float w  = __expf(logit - mn);
    zloc = zloc * sc + w;
    #pragma unroll
    for (int i = 0; i < 8; ++i) acc8[i] = fmaf(w, xf[i], acc8[i] * sc);
    m = mn;
  }

  #pragma unroll
  for (int off = 8; off < 64; off <<= 1) {
    zloc += __shfl_xor(zloc, off, 64);
    #pragma unroll
    for (int i = 0; i < 8; ++i) acc8[i] += __shfl_xor(acc8[i], off, 64);
  }

  if (egrp == 0) {
    float invz = 1.f / zloc;
    float o[8];
    #pragma unroll
    for (int i = 0; i < 8; ++i) {
      float val = acc8[i] * invz + bias[cbase + i];
      if (ELU) val = val > 0.f ? val : __expf(val) - 1.f;
      o[i] = val;
    }
    float* op = out + (size_t)d * old + cbase;
    *(float4*)(op)     = make_float4(o[0], o[1], o[2], o[3]);
    *(float4*)(op + 4) = make_float4(o[4], o[5], o[6], o[7]);
  }
}

// ======================= folded chunk kernel v2 (edge rows >= N) =======================
// 64 rows per wave (RT=4), 256 rows/block: 2x ILP per MFMA step, 2x W-load
// amortization vs v1. No LDS, no barriers, coalesced pbuf writes.
__global__ __launch_bounds__(256) void chunk_fold_kernel(
    const float* __restrict__ A,      // edge_type + N*64
    const short* __restrict__ W1t,    // [256][64] bf16 (n,k) == W1^T
    const float* __restrict__ b1,     // [256]
    const float* __restrict__ WcT,    // [2][256] fp32
    const float* __restrict__ pc,     // [2]
    float* __restrict__ pbufN,        // pbuf + 2*N_NODES
    int Mtot)
{
  int tid = threadIdx.x;
  int w = tid >> 6;
  int lane = tid & 63;
  int quad = lane >> 4;
  int l15 = lane & 15;
  int row_base = (int)blockIdx.x * 256 + w * 64;

  // row frags (B-op): lane l15 = row (+16*rt), k = ks*32 + quad*8 + j
  bf8_t a1[4][2];
  #pragma unroll
  for (int rt = 0; rt < 4; ++rt) {
    int r = row_base + rt * 16 + l15;
    int rc = r < Mtot ? r : Mtot - 1;
    const float* ap = A + (size_t)rc * 64 + quad * 8;
    #pragma unroll
    for (int ks = 0; ks < 2; ++ks) {
      float4 v0 = *(const float4*)(ap + ks * 32);
      float4 v1 = *(const float4*)(ap + ks * 32 + 4);
      bf8_t f;
      f[0] = f2bf(v0.x); f[1] = f2bf(v0.y); f[2] = f2bf(v0.z); f[3] = f2bf(v0.w);
      f[4] = f2bf(v1.x); f[5] = f2bf(v1.y); f[6] = f2bf(v1.z); f[7] = f2bf(v1.w);
      a1[rt][ks] = f;
    }
  }

  float p0[4] = {0.f, 0.f, 0.f, 0.f};
  float p1[4] = {0.f, 0.f, 0.f, 0.f};

  #pragma unroll
  for (int cc = 0; cc < 4; ++cc) {
    #pragma unroll
    for (int nt = 0; nt < 4; ++nt) {
      const short* wb = W1t + (cc * 64 + nt * 16 + l15) * 64 + quad * 8;
      bf8_t w0 = *(const bf8_t*)(wb);
      bf8_t w1 = *(const bf8_t*)(wb + 32);
      f4_t g[4];
      #pragma unroll
      for (int rt = 0; rt < 4; ++rt) {
        f4_t z = {0.f, 0.f, 0.f, 0.f};
        z = __builtin_amdgcn_mfma_f32_16x16x32_bf16(w0, a1[rt][0], z, 0, 0, 0);
        z = __builtin_amdgcn_mfma_f32_16x16x32_bf16(w1, a1[rt][1], z, 0, 0, 0);
        g[rt] = z;
      }
      // lane reg r = G[row = rt*16 + l15][col = cc*64 + nt*16 + quad*4 + r]
      int cbase = cc * 64 + nt * 16 + quad * 4;
      f4_t b4  = *(const f4_t*)&b1[cbase];
      f4_t wc0 = *(const f4_t*)&WcT[cbase];
      f4_t wc1 = *(const f4_t*)&WcT[256 + cbase];
      #pragma unroll
      for (int rt = 0; rt < 4; ++rt) {
        #pragma unroll
        for (int r = 0; r < 4; ++r) {
          float v = g[rt][r] + b4[r];
          v = v > 0.f ? v : __expf(v) - 1.f;
          p0[rt] = fmaf(v, wc0[r], p0[rt]);
          p1[rt] = fmaf(v, wc1[r], p1[rt]);
        }
      }
    }
  }

  // reduce over quad (lane bits 4,5): full col-sum lands on every lane
  #pragma unroll
  for (int off = 16; off < 64; off <<= 1) {
    #pragma unroll
    for (int rt = 0; rt < 4; ++rt) {
      p0[rt] += __shfl_xor(p0[rt], off, 64);
      p1[rt] += __shfl_xor(p1[rt], off, 64);
    }
  }
  if (quad == 0) {
    float c0 = pc[0], c1 = pc[1];
    #pragma unroll
    for (int rt = 0; rt < 4; ++rt) {
      int row = row_base + rt * 16 + l15;
      if (row < Mtot)
        *(float2*)&pbufN[2 * row] = make_float2(p0[rt] + c0, p1[rt] + c1);
    }
  }
}

// ======================= per-edge p for edge ids < N =======================
__global__ void edge_dot_kernel(const float* __restrict__ edge_repr, const float* __restrict__ wp,
                                float* __restrict__ pbuf, int e_cnt) {
  __shared__ float swp[128];
  if (threadIdx.x < 128) swp[threadIdx.x] = wp[threadIdx.x];
  __syncthreads();
  int e = blockIdx.x * blockDim.x + threadIdx.x;
  if (e >= e_cnt) return;
  const float* er = edge_repr + (size_t)e * 64;
  float a0 = 0.f, a1 = 0.f;
  #pragma unroll
  for (int k = 0; k < 64; ++k) {
    float v = er[k];
    a0 = fmaf(v, swp[2 * k + 0], a0);
    a1 = fmaf(v, swp[2 * k + 1], a1);
  }
  *(float2*)&pbuf[2 * e] = make_float2(a0, a1);
}

// ======================= Heads =======================
__global__ void head_kernel(const float* __restrict__ node_repr, const float* __restrict__ ph,
                            const int* __restrict__ rowptr, const int* __restrict__ csr_eid,
                            const float* __restrict__ pbuf, const float* __restrict__ wu,
                            const float* __restrict__ bu, const float* __restrict__ w2,
                            const float* __restrict__ b2, float* __restrict__ out, int n) {
  __shared__ float swu[128];
  __shared__ float sw2[256];
  int tid = threadIdx.x;
  if (tid < 128) swu[tid] = wu[tid];
  sw2[tid] = w2[tid];
  __syncthreads();
  int i = blockIdx.x * blockDim.x + tid;
  if (i >= n) return;
  float m0 = 0.f, m1 = 0.f;
  int r0 = rowptr[i], r1 = rowptr[i + 1];
  int jj = r0;
  for (; jj + 4 <= r1; jj += 4) {
    int e0 = csr_eid[jj + 0], e1 = csr_eid[jj + 1];
    int e2 = csr_eid[jj + 2], e3 = csr_eid[jj + 3];
    float2 q0 = *(const float2*)&pbuf[2 * e0];
    float2 q1 = *(const float2*)&pbuf[2 * e1];
    float2 q2 = *(const float2*)&pbuf[2 * e2];
    float2 q3 = *(const float2*)&pbuf[2 * e3];
    m0 += (q0.x + q1.x) + (q2.x + q3.x);
    m1 += (q0.y + q1.y) + (q2.y + q3.y);
  }
  for (; jj < r1; ++jj) {
    int e = csr_eid[jj];
    float2 q = *(const float2*)&pbuf[2 * e];
    m0 += q.x; m1 += q.y;
  }
  const float* nr = node_repr + (size_t)i * 64;
  float u0 = bu[0], u1 = bu[1];
  #pragma unroll
  for (int k = 0; k < 64; ++k) {
    float v = nr[k];
    u0 = fmaf(v, swu[2 * k + 0], u0);
    u1 = fmaf(v, swu[2 * k + 1], u1);
  }
  float v0 = u0 + m0;
  float v1 = u1 + m1;
  float mx = fmaxf(v0, v1);
  float lse = mx + logf(__expf(v0 - mx) + __expf(v1 - mx));
  out[2 * i + 0] = v0 - lse;
  out[2 * i + 1] = v1 - lse;
  const float* p = ph + (size_t)i * 128;
  float p0 = b2[0], p1 = b2[1];
  #pragma unroll
  for (int k = 0; k < 128; ++k) {
    float v = p[k];
    p0 = fmaf(v, sw2[2 * k + 0], p0);
    p1 = fmaf(v, sw2[2 * k + 1], p1);
  }
  out[2 * n + 2 * i + 0] = p0;
  out[2 * n + 2 * i + 1] = p1;
}

// ======================= launch =======================
extern "C" void kernel_launch(void* const* d_in, const int* in_sizes, int n_in,
                              void* d_out, int out_size, void* d_ws, size_t ws_size,
                              hipStream_t stream) {
  const int N = N_NODES, E = N_EDGES;
  const float* x         = (const float*)d_in[0];
  const float* edge_type = (const float*)d_in[1];
  const int*   ei        = (const int*)d_in[2];
  const float* n1_wl  = (const float*)d_in[3];
  const float* n1_wr  = (const float*)d_in[4];
  const float* n1_att = (const float*)d_in[5];
  const float* n1_b   = (const float*)d_in[6];
  const float* n2_wl  = (const float*)d_in[7];
  const float* n2_wr  = (const float*)d_in[8];
  const float* n2_att = (const float*)d_in[9];
  const float* n2_b   = (const float*)d_in[10];
  const float* e1_wl  = (const float*)d_in[11];
  const float* e1_wr  = (const float*)d_in[12];
  const float* e1_att = (const float*)d_in[13];
  const float* e1_b   = (const float*)d_in[14];
  const float* e2_wl  = (const float*)d_in[15];
  const float* e2_wr  = (const float*)d_in[16];
  const float* e2_att = (const float*)d_in[17];
  const float* e2_b   = (const float*)d_in[18];
  const float* crf_wu = (const float*)d_in[19];
  const float* crf_bu = (const float*)d_in[20];
  const float* crf_wp = (const float*)d_in[21];
  const float* px_w1  = (const float*)d_in[22];
  const float* px_b1  = (const float*)d_in[23];
  const float* px_w2  = (const float*)d_in[24];
  const float* px_b2  = (const float*)d_in[25];
  float* out = (float*)d_out;
  const int* src = ei;
  const int* dst = ei + E;
  (void)in_sizes; (void)n_in; (void)out_size; (void)ws_size;

  // ---- workspace layout ----
  char* ws = (char*)d_ws;
  size_t off = 0;
  auto alloc = [&](size_t bytes) -> void* {
    void* p = ws + off;
    off += (bytes + 255) & ~(size_t)255;
    return p;
  };
  char* arena0 = (char*)alloc((size_t)N * 256 * 4);  // xl bf16 [N,256] / ph fp32 [N,128]
  float* arena1 = (float*)alloc((size_t)N * 256 * 4); // xr fp32
  float* arena2 = (float*)alloc((size_t)N * 256 * 4); // h / g_low fp32
  bfu* xl_bf   = (bfu*)arena0;
  float* ph    = (float*)arena0;
  float* B3    = (float*)alloc((size_t)N * 64 * 4);    // node_repr
  float* erlow = (float*)alloc((size_t)N * 64 * 4);    // edge_repr rows < N
  float* pbuf  = (float*)alloc((size_t)E * 2 * 4);     // per-edge CRF p-pairs
  int* deg     = (int*)alloc((size_t)N * 4);
  int* rowptr  = (int*)alloc((size_t)(N + 1) * 4);
  int* cursor  = (int*)alloc((size_t)N * 4);
  int* csr_src = (int*)alloc((size_t)E * 4);
  int* csr_eid = (int*)alloc((size_t)E * 4);
  short* t_n1l = (short*)alloc((size_t)16384 * 2);
  short* t_n1r = (short*)alloc((size_t)16384 * 2);
  short* t_e1l = (short*)alloc((size_t)16384 * 2);   // == W1t for chunk_fold
  short* t_e1r = (short*)alloc((size_t)16384 * 2);
  short* t_n2l = (short*)alloc((size_t)16384 * 2);
  short* t_n2r = (short*)alloc((size_t)16384 * 2);
  short* t_e2l = (short*)alloc((size_t)16384 * 2);
  short* t_e2r = (short*)alloc((size_t)16384 * 2);
  float* WcT   = (float*)alloc((size_t)2 * 256 * 4);
  float* pcv   = (float*)alloc((size_t)2 * 4);

  const int EB = (E + 255) / 256;
  const int NB = (N + 127) / 128;        // 157 (px GEMM)
  const int PB = (N + 63) / 64;          // 313 (mfma proj)
  const int Mhigh = E - N;               // 300000
  const int CFB = (Mhigh + 255) / 256;   // 1172 (chunk_fold v2: 256 rows/block)

  hipMemsetAsync(deg, 0, (size_t)N * 4, stream);
  count_deg_kernel<<<EB, 256, 0, stream>>>(dst, deg, E);
  scan_kernel<<<1, 1024, 0, stream>>>(deg, rowptr, cursor, N);
  fill_csr_kernel<<<EB, 256, 0, stream>>>(src, dst, cursor, csr_src, csr_eid, E);
  prep_all_kernel<<<515, 256, 0, stream>>>(n1_wl, n1_wr, e1_wl, e1_wr,
                                           n2_wl, n2_wr, e2_wl, e2_wr,
                                           e2_b, crf_wp,
                                           t_n1l, t_n1r, t_e1l, t_e1r,
                                           t_n2l, t_n2r, t_e2l, t_e2r, WcT, pcv);

  // ---- node layer 1: GATv2(64 -> 4x64, concat) + elu ----
  mfma_proj_kernel<64><<<dim3(PB, 8), 128, 0, stream>>>(x, t_n1l, t_n1r, xl_bf, arena1, N, 4);
  gat_agg_v2<true, 256><<<N, 256, 0, stream>>>(xl_bf, arena1, n1_att, n1_b, rowptr, csr_src, arena2, 256);

  // ---- node layer 2: GATv2(256 -> 64) -> B3 ----
  mfma_proj_kernel<256><<<dim3(PB, 2), 128, 0, stream>>>(arena2, t_n2l, t_n2r, xl_bf, arena1, N, 1);
  gat_agg_v2<false, 64><<<N, 64, 0, stream>>>(xl_bf, arena1, n2_att, n2_b, rowptr, csr_src, B3, 64);

  // ---- edge layer 1, rows < N ----
  mfma_proj_kernel<64><<<dim3(PB, 8), 128, 0, stream>>>(edge_type, t_e1l, t_e1r, xl_bf, arena1, N, 4);
  gat_agg_v2<true, 256><<<N, 256, 0, stream>>>(xl_bf, arena1, e1_att, e1_b, rowptr, csr_src, arena2, 256);

  // ---- edge layer 2, rows < N -> erlow ----
  mfma_proj_kernel<256><<<dim3(PB, 2), 128, 0, stream>>>(arena2, t_e2l, t_e2r, xl_bf, arena1, N, 1);
  gat_agg_v2<false, 64><<<N, 64, 0, stream>>>(xl_bf, arena1, e2_att, e2_b, rowptr, csr_src, erlow, 64);

  // ---- CRF per-edge p pairs ----
  edge_dot_kernel<<<(N + 255) / 256, 256, 0, stream>>>(erlow, crf_wp, pbuf, N);
  chunk_fold_kernel<<<CFB, 256, 0, stream>>>(edge_type + (size_t)N * 64, t_e1l,
                                             e1_b, WcT, pcv, pbuf + 2 * (size_t)N, Mhigh);

  // ---- heads ----
  gemm64_kernel<64, 3><<<dim3(NB, 2), 256, 0, stream>>>(B3, px_w1, 128, px_b1, ph, 128, N);
  head_kernel<<<(N + 255) / 256, 256, 0, stream>>>(B3, ph, rowptr, csr_eid, pbuf,
                                                   crf_wu, crf_bu, px_w2, px_b2, out, N);
}

// Round 12
// 504.888 us; speedup vs baseline: 1.3824x; 1.0322x over previous
//
#include <hip/hip_runtime.h>
#include <cstddef>
#include <cstdint>

#define N_NODES 20000
#define N_EDGES 320000

typedef __attribute__((ext_vector_type(8))) short bf8_t;   // 8 x bf16 (MFMA frag)
typedef __attribute__((ext_vector_type(4))) float f4_t;    // MFMA acc / float4
typedef __attribute__((ext_vector_type(2))) float f2_t;    // packed fp32 pair
typedef unsigned short bfu;                                 // bf16 storage
typedef __attribute__((ext_vector_type(4))) unsigned short us4_t;
typedef __attribute__((ext_vector_type(8))) unsigned short us8_t;

__device__ __forceinline__ short f2bf(float f) {
  unsigned u = __float_as_uint(f);
  u += 0x7fff + ((u >> 16) & 1);   // round-to-nearest-even
  return (short)(u >> 16);
}
__device__ __forceinline__ float bf2f(bfu u) {
  return __uint_as_float(((unsigned)u) << 16);
}
// leaky_relu(t) = max(t,0) + 0.2*min(t,0)  (packed-friendly, value-identical)
__device__ __forceinline__ f2_t leaky2(f2_t t) {
  f2_t zero = {0.f, 0.f};
  f2_t mx = __builtin_elementwise_max(t, zero);
  f2_t mn = __builtin_elementwise_min(t, zero);
  return mn * 0.2f + mx;
}
// unpack 8 bf16 (4 dwords) into 4 packed f32 pairs
__device__ __forceinline__ void bf8_to_f2x4(us8_t xu, f2_t o[4]) {
  union { us8_t v; unsigned u[4]; } c; c.v = xu;
  #pragma unroll
  for (int j = 0; j < 4; ++j) {
    unsigned d = c.u[j];
    f2_t t;
    t.x = __uint_as_float(d << 16);
    t.y = __uint_as_float(d & 0xffff0000u);
    o[j] = t;
  }
}

// ======================= CSR build =======================
__global__ void count_deg_kernel(const int* __restrict__ dst, int* __restrict__ deg, int e_cnt) {
  int e = blockIdx.x * blockDim.x + threadIdx.x;
  if (e < e_cnt) atomicAdd(&deg[dst[e]], 1);
}

__global__ void scan_kernel(const int* __restrict__ deg, int* __restrict__ rowptr,
                            int* __restrict__ cursor, int n) {
  __shared__ int sdata[1024];
  __shared__ int s_carry;
  int tid = threadIdx.x;
  if (tid == 0) s_carry = 0;
  __syncthreads();
  for (int base = 0; base < n; base += 1024) {
    int idx = base + tid;
    int v = (idx < n) ? deg[idx] : 0;
    sdata[tid] = v;
    __syncthreads();
    for (int off = 1; off < 1024; off <<= 1) {
      int t = (tid >= off) ? sdata[tid - off] : 0;
      __syncthreads();
      sdata[tid] += t;
      __syncthreads();
    }
    int excl = sdata[tid] - v;
    if (idx < n) { int val = s_carry + excl; rowptr[idx] = val; cursor[idx] = val; }
    __syncthreads();
    if (tid == 0) s_carry += sdata[1023];
    __syncthreads();
  }
  if (tid == 0) rowptr[n] = s_carry;
}

__global__ void fill_csr_kernel(const int* __restrict__ src, const int* __restrict__ dst,
                                int* __restrict__ cursor, int* __restrict__ csr_src,
                                int* __restrict__ csr_eid, int e_cnt) {
  int e = blockIdx.x * blockDim.x + threadIdx.x;
  if (e < e_cnt) {
    int pos = atomicAdd(&cursor[dst[e]], 1);
    csr_src[pos] = src[e];
    csr_eid[pos] = e;
  }
}

// ======================= weight prep: all projections -> bf16 transposed =======================
__global__ void prep_all_kernel(
    const float* __restrict__ n1l, const float* __restrict__ n1r,
    const float* __restrict__ e1l, const float* __restrict__ e1r,
    const float* __restrict__ n2l, const float* __restrict__ n2r,
    const float* __restrict__ e2l, const float* __restrict__ e2r,
    const float* __restrict__ b2, const float* __restrict__ wp,
    short* __restrict__ t_n1l, short* __restrict__ t_n1r,
    short* __restrict__ t_e1l, short* __restrict__ t_e1r,
    short* __restrict__ t_n2l, short* __restrict__ t_n2r,
    short* __restrict__ t_e2l, short* __restrict__ t_e2r,
    float* __restrict__ wct, float* __restrict__ pc)
{
  int i = blockIdx.x * blockDim.x + threadIdx.x;
  int seg = i >> 14;
  int j = i & 16383;
  if (seg < 4) {
    const float* srcs[4] = {n1l, n1r, e1l, e1r};
    short* dsts[4] = {t_n1l, t_n1r, t_e1l, t_e1r};
    int n = j >> 6, k = j & 63;
    dsts[seg][n * 64 + k] = f2bf(srcs[seg][k * 256 + n]);
  } else if (seg < 8) {
    const float* srcs[4] = {n2l, n2r, e2l, e2r};
    short* dsts[4] = {t_n2l, t_n2r, t_e2l, t_e2r};
    int n = j >> 8, k = j & 255;
    dsts[seg - 4][n * 256 + k] = f2bf(srcs[seg - 4][k * 64 + n]);
  } else if (seg == 8) {
    if (j < 512) {
      int jj = j & 1;
      int k  = j >> 1;
      float s = 0.f;
      for (int c = 0; c < 64; ++c) s = fmaf(e2l[k * 64 + c], wp[c * 2 + jj], s);
      wct[jj * 256 + k] = s;
    } else if (j < 514) {
      int jj = j - 512;
      float s = 0.f;
      for (int c = 0; c < 64; ++c) s = fmaf(b2[c], wp[c * 2 + jj], s);
      pc[jj] = s;
    }
  }
}

// ======================= MFMA projection kernel (dual-chain) =======================
// blockIdx.z picks chain (A0/weights0 -> xl0/xr0 vs A1/...).
template<int K>
__global__ __launch_bounds__(128) void mfma_proj2_kernel(
    const float* __restrict__ A0,
    const short* __restrict__ Wtl0, const short* __restrict__ Wtr0,
    bfu* __restrict__ xl0, float* __restrict__ xr0,
    const float* __restrict__ A1,
    const short* __restrict__ Wtl1, const short* __restrict__ Wtr1,
    bfu* __restrict__ xl1, float* __restrict__ xr1,
    int M, int nslices)
{
  constexpr int KC = K / 32;
  int tid = threadIdx.x;
  int w = tid >> 6, lane = tid & 63, quad = lane >> 4, l15 = lane & 15;
  int row_base = (int)blockIdx.x * 64 + w * 32;
  int y = (int)blockIdx.y;
  int z = (int)blockIdx.z;
  const float* A = z ? A1 : A0;
  bool is_l = y < nslices;
  const short* Wt = z ? (is_l ? Wtl1 : Wtr1) : (is_l ? Wtl0 : Wtr0);
  bfu* xl = z ? xl1 : xl0;
  float* xr = z ? xr1 : xr0;
  int cb = (is_l ? y : y - nslices) * 64;
  int STR = nslices * 64;

  bf8_t a[2][KC];
  #pragma unroll
  for (int rt = 0; rt < 2; ++rt) {
    int r = row_base + rt * 16 + l15;
    int rc = r < M ? r : M - 1;
    const float* ap = A + (size_t)rc * K + quad * 8;
    #pragma unroll
    for (int kc = 0; kc < KC; ++kc) {
      float4 v0 = *(const float4*)(ap + kc * 32);
      float4 v1 = *(const float4*)(ap + kc * 32 + 4);
      bf8_t f;
      f[0] = f2bf(v0.x); f[1] = f2bf(v0.y); f[2] = f2bf(v0.z); f[3] = f2bf(v0.w);
      f[4] = f2bf(v1.x); f[5] = f2bf(v1.y); f[6] = f2bf(v1.z); f[7] = f2bf(v1.w);
      a[rt][kc] = f;
    }
  }

  #pragma unroll
  for (int nt = 0; nt < 4; ++nt) {
    f4_t acc0 = {0.f, 0.f, 0.f, 0.f};
    f4_t acc1 = {0.f, 0.f, 0.f, 0.f};
    const short* wb = Wt + (size_t)(cb + nt * 16 + l15) * K + quad * 8;
    #pragma unroll
    for (int kc = 0; kc < KC; ++kc) {
      bf8_t wf = *(const bf8_t*)(wb + kc * 32);
      acc0 = __builtin_amdgcn_mfma_f32_16x16x32_bf16(wf, a[0][kc], acc0, 0, 0, 0);
      acc1 = __builtin_amdgcn_mfma_f32_16x16x32_bf16(wf, a[1][kc], acc1, 0, 0, 0);
    }
    #pragma unroll
    for (int rt = 0; rt < 2; ++rt) {
      f4_t acc = rt == 0 ? acc0 : acc1;
      int row = row_base + rt * 16 + l15;
      if (row >= M) continue;
      int col = cb + nt * 16 + quad * 4;
      if (is_l) {
        us4_t pk;
        pk[0] = (bfu)f2bf(acc[0]); pk[1] = (bfu)f2bf(acc[1]);
        pk[2] = (bfu)f2bf(acc[2]); pk[3] = (bfu)f2bf(acc[3]);
        *(us4_t*)&xl[(size_t)row * STR + col] = pk;
      } else {
        *(float4*)&xr[(size_t)row * STR + col] = make_float4(acc[0], acc[1], acc[2], acc[3]);
      }
    }
  }
}

// ======================= fp32 GEMM (proxy head only) =======================
template<int KIN>
__device__ __forceinline__ void gemm_body(
    const float* __restrict__ A, const float* __restrict__ W, int wld, int cb,
    int block_m, int M, float (&acc)[8][4],
    float (*As)[128 + 4], float (*Ws)[64 + 4])
{
  int tid = threadIdx.x;
  int tx = tid & 15;
  int ty = tid >> 4;
  #pragma unroll
  for (int i = 0; i < 8; ++i)
    #pragma unroll
    for (int j = 0; j < 4; ++j) acc[i][j] = 0.f;

  for (int k0 = 0; k0 < KIN; k0 += 16) {
    #pragma unroll
    for (int rep = 0; rep < 2; ++rep) {
      int ar = (tid >> 2) + rep * 64;
      int ak = (tid & 3) * 4;
      int gr = block_m + ar;
      float4 v = make_float4(0.f, 0.f, 0.f, 0.f);
      if (gr < M) v = *(const float4*)&A[(size_t)gr * KIN + k0 + ak];
      As[ak + 0][ar] = v.x; As[ak + 1][ar] = v.y;
      As[ak + 2][ar] = v.z; As[ak + 3][ar] = v.w;
    }
    {
      int wr = tid >> 4;
      int wc = (tid & 15) * 4;
      float4 v = *(const float4*)&W[(size_t)(k0 + wr) * wld + cb + wc];
      Ws[wr][wc + 0] = v.x; Ws[wr][wc + 1] = v.y;
      Ws[wr][wc + 2] = v.z; Ws[wr][wc + 3] = v.w;
    }
    __syncthreads();
    #pragma unroll
    for (int k = 0; k < 16; ++k) {
      float a[8], w[4];
      #pragma unroll
      for (int i = 0; i < 8; ++i) a[i] = As[k][ty * 8 + i];
      #pragma unroll
      for (int j = 0; j < 4; ++j) w[j] = Ws[k][tx * 4 + j];
      #pragma unroll
      for (int i = 0; i < 8; ++i)
        #pragma unroll
        for (int j = 0; j < 4; ++j) acc[i][j] = fmaf(a[i], w[j], acc[i][j]);
    }
    __syncthreads();
  }
}

template<int KIN, int MODE>
__global__ __launch_bounds__(256) void gemm64_kernel(
    const float* __restrict__ A, const float* __restrict__ W, int wld,
    const float* __restrict__ bias, float* __restrict__ out, int old, int M)
{
  __shared__ float As[16][128 + 4];
  __shared__ float Ws[16][64 + 4];
  float acc[8][4];
  int block_m = (int)blockIdx.x * 128;
  int cb = (int)blockIdx.y * 64;
  gemm_body<KIN>(A, W, wld, cb, block_m, M, acc, As, Ws);

  int tid = threadIdx.x;
  int tx = tid & 15, ty = tid >> 4;
  int gc = cb + tx * 4;
  #pragma unroll
  for (int i = 0; i < 8; ++i) {
    int gr = block_m + ty * 8 + i;
    if (gr >= M) continue;
    size_t idx = (size_t)gr * old + gc;
    float t0 = acc[i][0], t1 = acc[i][1], t2 = acc[i][2], t3 = acc[i][3];
    if (MODE == 3) {
      t0 = fmaxf(t0 + bias[gc + 0], 0.f);
      t1 = fmaxf(t1 + bias[gc + 1], 0.f);
      t2 = fmaxf(t2 + bias[gc + 2], 0.f);
      t3 = fmaxf(t3 + bias[gc + 3], 0.f);
    }
    *(float4*)&out[idx] = make_float4(t0, t1, t2, t3);
  }
}

// ======================= GATv2 aggregation v3 (packed fp32, dual-chain fused) ==========
// Edge x channel-chunk tiling: wave h = head h; lane = egrp*8 + cch.
// Channel math on f2_t -> v_pk_{add,max,min,fma}_f32. blocks [0,N) = chain 0,
// [N,2N) = chain 1.
template<bool ELU, int STR>
__global__ __launch_bounds__(STR == 256 ? 256 : 64) void gat_agg_v3(
    const bfu* __restrict__ xl0, const float* __restrict__ xr0,
    const float* __restrict__ att0, const float* __restrict__ bias0,
    float* __restrict__ out0, int old0,
    const bfu* __restrict__ xl1, const float* __restrict__ xr1,
    const float* __restrict__ att1, const float* __restrict__ bias1,
    float* __restrict__ out1, int old1,
    const int* __restrict__ rowptr, const int* __restrict__ csr_src)
{
  int d = blockIdx.x;
  bool c1 = d >= N_NODES;
  if (c1) d -= N_NODES;
  const bfu* xl = c1 ? xl1 : xl0;
  const float* xr = c1 ? xr1 : xr0;
  const float* att = c1 ? att1 : att0;
  const float* bias = c1 ? bias1 : bias0;
  float* out = c1 ? out1 : out0;
  int old = c1 ? old1 : old0;

  int tid = threadIdx.x;
  int h = tid >> 6;
  int lane = tid & 63;
  int egrp = lane >> 3;
  int cch  = lane & 7;
  int row0 = rowptr[d];
  int deg = rowptr[d + 1] - row0;
  int cbase = h * 64 + cch * 8;

  f2_t xr2[4], att2[4];
  {
    const float* xrp = xr + (size_t)d * STR + cbase;
    const float* atp = att + cbase;
    float4 a0 = *(const float4*)(xrp);
    float4 a1 = *(const float4*)(xrp + 4);
    xr2[0] = f2_t{a0.x, a0.y}; xr2[1] = f2_t{a0.z, a0.w};
    xr2[2] = f2_t{a1.x, a1.y}; xr2[3] = f2_t{a1.z, a1.w};
    float4 b0 = *(const float4*)(atp);
    float4 b1 = *(const float4*)(atp + 4);
    att2[0] = f2_t{b0.x, b0.y}; att2[1] = f2_t{b0.z, b0.w};
    att2[2] = f2_t{b1.x, b1.y}; att2[3] = f2_t{b1.z, b1.w};
  }

  float m, zloc;
  f2_t acc4[4];
  {
    us8_t xu = *(const us8_t*)&xl[(size_t)d * STR + cbase];
    f2_t xs[4];
    bf8_to_f2x4(xu, xs);
    f2_t p2 = {0.f, 0.f};
    #pragma unroll
    for (int j = 0; j < 4; ++j) {
      f2_t l = leaky2(xs[j] + xr2[j]);
      p2 = p2 + l * att2[j];
      f2_t zz = {0.f, 0.f};
      acc4[j] = (egrp == 0) ? xs[j] : zz;
    }
    float part = p2.x + p2.y;
    part += __shfl_xor(part, 1, 64);
    part += __shfl_xor(part, 2, 64);
    part += __shfl_xor(part, 4, 64);
    m = part;
    zloc = (egrp == 0) ? 1.f : 0.f;
  }

  for (int j = 0; j < deg; j += 8) {
    int idx = j + egrp;
    bool valid = idx < deg;
    int s = valid ? csr_src[row0 + idx] : d;
    us8_t xu = *(const us8_t*)&xl[(size_t)s * STR + cbase];
    f2_t xf[4];
    bf8_to_f2x4(xu, xf);
    f2_t p2 = {0.f, 0.f};
    #pragma unroll
    for (int i = 0; i < 4; ++i) {
      f2_t l = leaky2(xf[i] + xr2[i]);
      p2 = p2 + l * att2[i];
    }
    float part = p2.x + p2.y;
    part += __shfl_xor(part, 1, 64);
    part += __shfl_xor(part, 2, 64);
    part += __shfl_xor(part, 4, 64);
    float logit = valid ? part : -1e30f;
    float gmax = logit;
    gmax = fmaxf(gmax, __shfl_xor(gmax, 8, 64));
    gmax = fmaxf(gmax, __shfl_xor(gmax, 16, 64));
    gmax = fmaxf(gmax, __shfl_xor(gmax, 32, 64));
    float mn = fmaxf(m, gmax);
    float sc = __expf(m - mn);
    float w  = __expf(logit - mn);
    zloc = zloc * sc + w;
    f2_t sc2 = {sc, sc};
    f2_t w2 = {w, w};
    #pragma unroll
    for (int i = 0; i < 4; ++i) acc4[i] = acc4[i] * sc2 + xf[i] * w2;
    m = mn;
  }

  float a8[8];
  #pragma unroll
  for (int i = 0; i < 4; ++i) { a8[2 * i] = acc4[i].x; a8[2 * i + 1] = acc4[i].y; }
  #pragma unroll
  for (int off = 8; off < 64; off <<= 1) {
    zloc += __shfl_xor(zloc, off, 64);
    #pragma unroll
    for (int i = 0; i < 8; ++i) a8[i] += __shfl_xor(a8[i], off, 64);
  }

  if (egrp == 0) {
    float invz = 1.f / zloc;
    float o[8];
    #pragma unroll
    for (int i = 0; i < 8; ++i) {
      float val = a8[i] * invz + bias[cbase + i];
      if (ELU) val = val > 0.f ? val : __expf(val) - 1.f;
      o[i] = val;
    }
    float* op = out + (size_t)d * old + cbase;
    *(float4*)(op)     = make_float4(o[0], o[1], o[2], o[3]);
    *(float4*)(op + 4) = make_float4(o[4], o[5], o[6], o[7]);
  }
}

// ======================= folded chunk kernel v2 (edge rows >= N) =======================
__global__ __launch_bounds__(256) void chunk_fold_kernel(
    const float* __restrict__ A,      // edge_type + N*64
    const short* __restrict__ W1t,    // [256][64] bf16 (n,k) == W1^T
    const float* __restrict__ b1,     // [256]
    const float* __restrict__ WcT,    // [2][256] fp32
    const float* __restrict__ pc,     // [2]
    float* __restrict__ pbufN,        // pbuf + 2*N_NODES
    int Mtot)
{
  int tid = threadIdx.x;
  int w = tid >> 6;
  int lane = tid & 63;
  int quad = lane >> 4;
  int l15 = lane & 15;
  int row_base = (int)blockIdx.x * 256 + w * 64;

  bf8_t a1[4][2];
  #pragma unroll
  for (int rt = 0; rt < 4; ++rt) {
    int r = row_base + rt * 16 + l15;
    int rc = r < Mtot ? r : Mtot - 1;
    const float* ap = A + (size_t)rc * 64 + quad * 8;
    #pragma unroll
    for (int ks = 0; ks < 2; ++ks) {
      float4 v0 = *(const float4*)(ap + ks * 32);
      float4 v1 = *(const float4*)(ap + ks * 32 + 4);
      bf8_t f;
      f[0] = f2bf(v0.x); f[1] = f2bf(v0.y); f[2] = f2bf(v0.z); f[3] = f2bf(v0.w);
      f[4] = f2bf(v1.x); f[5] = f2bf(v1.y); f[6] = f2bf(v1.z); f[7] = f2bf(v1.w);
      a1[rt][ks] = f;
    }
  }

  float p0[4] = {0.f, 0.f, 0.f, 0.f};
  float p1[4] = {0.f, 0.f, 0.f, 0.f};

  #pragma unroll
  for (int cc = 0; cc < 4; ++cc) {
    #pragma unroll
    for (int nt = 0; nt < 4; ++nt) {
      const short* wb = W1t + (cc * 64 + nt * 16 + l15) * 64 + quad * 8;
      bf8_t w0 = *(const bf8_t*)(wb);
      bf8_t w1 = *(const bf8_t*)(wb + 32);
      f4_t g[4];
      #pragma unroll
      for (int rt = 0; rt < 4; ++rt) {
        f4_t z = {0.f, 0.f, 0.f, 0.f};
        z = __builtin_amdgcn_mfma_f32_16x16x32_bf16(w0, a1[rt][0], z, 0, 0, 0);
        z = __builtin_amdgcn_mfma_f32_16x16x32_bf16(w1, a1[rt][1], z, 0, 0, 0);
        g[rt] = z;
      }
      int cbase = cc * 64 + nt * 16 + quad * 4;
      f4_t b4  = *(const f4_t*)&b1[cbase];
      f4_t wc0 = *(const f4_t*)&WcT[cbase];
      f4_t wc1 = *(const f4_t*)&WcT[256 + cbase];
      #pragma unroll
      for (int rt = 0; rt < 4; ++rt) {
        #pragma unroll
        for (int r = 0; r < 4; ++r) {
          float v = g[rt][r] + b4[r];
          v = v > 0.f ? v : __expf(v) - 1.f;
          p0[rt] = fmaf(v, wc0[r], p0[rt]);
          p1[rt] = fmaf(v, wc1[r], p1[rt]);
        }
      }
    }
  }

  #pragma unroll
  for (int off = 16; off < 64; off <<= 1) {
    #pragma unroll
    for (int rt = 0; rt < 4; ++rt) {
      p0[rt] += __shfl_xor(p0[rt], off, 64);
      p1[rt] += __shfl_xor(p1[rt], off, 64);
    }
  }
  if (quad == 0) {
    float c0 = pc[0], c1 = pc[1];
    #pragma unroll
    for (int rt = 0; rt < 4; ++rt) {
      int row = row_base + rt * 16 + l15;
      if (row < Mtot)
        *(float2*)&pbufN[2 * row] = make_float2(p0[rt] + c0, p1[rt] + c1);
    }
  }
}

// ======================= per-edge p for edge ids < N =======================
__global__ void edge_dot_kernel(const float* __restrict__ edge_repr, const float* __restrict__ wp,
                                float* __restrict__ pbuf, int e_cnt) {
  __shared__ float swp[128];
  if (threadIdx.x < 128) swp[threadIdx.x] = wp[threadIdx.x];
  __syncthreads();
  int e = blockIdx.x * blockDim.x + threadIdx.x;
  if (e >= e_cnt) return;
  const float* er = edge_repr + (size_t)e * 64;
  float a0 = 0.f, a1 = 0.f;
  #pragma unroll
  for (int k = 0; k < 64; ++k) {
    float v = er[k];
    a0 = fmaf(v, swp[2 * k + 0], a0);
    a1 = fmaf(v, swp[2 * k + 1], a1);
  }
  *(float2*)&pbuf[2 * e] = make_float2(a0, a1);
}

// ======================= Heads =======================
__global__ void head_kernel(const float* __restrict__ node_repr, const float* __restrict__ ph,
                            const int* __restrict__ rowptr, const int* __restrict__ csr_eid,
                            const float* __restrict__ pbuf, const float* __restrict__ wu,
                            const float* __restrict__ bu, const float* __restrict__ w2,
                            const float* __restrict__ b2, float* __restrict__ out, int n) {
  __shared__ float swu[128];
  __shared__ float sw2[256];
  int tid = threadIdx.x;
  if (tid < 128) swu[tid] = wu[tid];
  sw2[tid] = w2[tid];
  __syncthreads();
  int i = blockIdx.x * blockDim.x + tid;
  if (i >= n) return;
  float m0 = 0.f, m1 = 0.f;
  int r0 = rowptr[i], r1 = rowptr[i + 1];
  int jj = r0;
  for (; jj + 4 <= r1; jj += 4) {
    int e0 = csr_eid[jj + 0], e1 = csr_eid[jj + 1];
    int e2 = csr_eid[jj + 2], e3 = csr_eid[jj + 3];
    float2 q0 = *(const float2*)&pbuf[2 * e0];
    float2 q1 = *(const float2*)&pbuf[2 * e1];
    float2 q2 = *(const float2*)&pbuf[2 * e2];
    float2 q3 = *(const float2*)&pbuf[2 * e3];
    m0 += (q0.x + q1.x) + (q2.x + q3.x);
    m1 += (q0.y + q1.y) + (q2.y + q3.y);
  }
  for (; jj < r1; ++jj) {
    int e = csr_eid[jj];
    float2 q = *(const float2*)&pbuf[2 * e];
    m0 += q.x; m1 += q.y;
  }
  const float* nr = node_repr + (size_t)i * 64;
  float u0 = bu[0], u1 = bu[1];
  #pragma unroll
  for (int k = 0; k < 64; ++k) {
    float v = nr[k];
    u0 = fmaf(v, swu[2 * k + 0], u0);
    u1 = fmaf(v, swu[2 * k + 1], u1);
  }
  float v0 = u0 + m0;
  float v1 = u1 + m1;
  float mx = fmaxf(v0, v1);
  float lse = mx + logf(__expf(v0 - mx) + __expf(v1 - mx));
  out[2 * i + 0] = v0 - lse;
  out[2 * i + 1] = v1 - lse;
  const float* p = ph + (size_t)i * 128;
  float p0 = b2[0], p1 = b2[1];
  #pragma unroll
  for (int k = 0; k < 128; ++k) {
    float v = p[k];
    p0 = fmaf(v, sw2[2 * k + 0], p0);
    p1 = fmaf(v, sw2[2 * k + 1], p1);
  }
  out[2 * n + 2 * i + 0] = p0;
  out[2 * n + 2 * i + 1] = p1;
}

// ======================= launch =======================
extern "C" void kernel_launch(void* const* d_in, const int* in_sizes, int n_in,
                              void* d_out, int out_size, void* d_ws, size_t ws_size,
                              hipStream_t stream) {
  const int N = N_NODES, E = N_EDGES;
  const float* x         = (const float*)d_in[0];
  const float* edge_type = (const float*)d_in[1];
  const int*   ei        = (const int*)d_in[2];
  const float* n1_wl  = (const float*)d_in[3];
  const float* n1_wr  = (const float*)d_in[4];
  const float* n1_att = (const float*)d_in[5];
  const float* n1_b   = (const float*)d_in[6];
  const float* n2_wl  = (const float*)d_in[7];
  const float* n2_wr  = (const float*)d_in[8];
  const float* n2_att = (const float*)d_in[9];
  const float* n2_b   = (const float*)d_in[10];
  const float* e1_wl  = (const float*)d_in[11];
  const float* e1_wr  = (const float*)d_in[12];
  const float* e1_att = (const float*)d_in[13];
  const float* e1_b   = (const float*)d_in[14];
  const float* e2_wl  = (const float*)d_in[15];
  const float* e2_wr  = (const float*)d_in[16];
  const float* e2_att = (const float*)d_in[17];
  const float* e2_b   = (const float*)d_in[18];
  const float* crf_wu = (const float*)d_in[19];
  const float* crf_bu = (const float*)d_in[20];
  const float* crf_wp = (const float*)d_in[21];
  const float* px_w1  = (const float*)d_in[22];
  const float* px_b1  = (const float*)d_in[23];
  const float* px_w2  = (const float*)d_in[24];
  const float* px_b2  = (const float*)d_in[25];
  float* out = (float*)d_out;
  const int* src = ei;
  const int* dst = ei + E;
  (void)in_sizes; (void)n_in; (void)out_size; (void)ws_size;

  // ---- workspace layout (~125 MB of ~327 MB) ----
  char* ws = (char*)d_ws;
  size_t off = 0;
  auto alloc = [&](size_t bytes) -> void* {
    void* p = ws + off;
    off += (bytes + 255) & ~(size_t)255;
    return p;
  };
  bfu*   xl_n  = (bfu*)alloc((size_t)N * 256 * 2);     // node l1 xl (bf16)
  float* xr_n  = (float*)alloc((size_t)N * 256 * 4);   // node l1 xr
  bfu*   xl_e  = (bfu*)alloc((size_t)N * 256 * 2);     // edge l1 xl
  float* xr_e  = (float*)alloc((size_t)N * 256 * 4);   // edge l1 xr
  float* h_n   = (float*)alloc((size_t)N * 256 * 4);   // node hidden
  float* g_e   = (float*)alloc((size_t)N * 256 * 4);   // edge hidden
  bfu*   xl2_n = (bfu*)alloc((size_t)N * 64 * 2);
  float* xr2_n = (float*)alloc((size_t)N * 64 * 4);
  bfu*   xl2_e = (bfu*)alloc((size_t)N * 64 * 2);
  float* xr2_e = (float*)alloc((size_t)N * 64 * 4);
  float* B3    = (float*)alloc((size_t)N * 64 * 4);    // node_repr
  float* erlow = (float*)alloc((size_t)N * 64 * 4);    // edge_repr rows < N
  float* pbuf  = (float*)alloc((size_t)E * 2 * 4);     // per-edge CRF p-pairs
  float* ph    = (float*)(void*)xl_n;                  // reuse (10.24 MB each)
  int* deg     = (int*)alloc((size_t)N * 4);
  int* rowptr  = (int*)alloc((size_t)(N + 1) * 4);
  int* cursor  = (int*)alloc((size_t)N * 4);
  int* csr_src = (int*)alloc((size_t)E * 4);
  int* csr_eid = (int*)alloc((size_t)E * 4);
  short* t_n1l = (short*)alloc((size_t)16384 * 2);
  short* t_n1r = (short*)alloc((size_t)16384 * 2);
  short* t_e1l = (short*)alloc((size_t)16384 * 2);
  short* t_e1r = (short*)alloc((size_t)16384 * 2);
  short* t_n2l = (short*)alloc((size_t)16384 * 2);
  short* t_n2r = (short*)alloc((size_t)16384 * 2);
  short* t_e2l = (short*)alloc((size_t)16384 * 2);
  short* t_e2r = (short*)alloc((size_t)16384 * 2);
  float* WcT   = (float*)alloc((size_t)2 * 256 * 4);
  float* pcv   = (float*)alloc((size_t)2 * 4);

  const int EB = (E + 255) / 256;
  const int NB = (N + 127) / 128;        // px GEMM
  const int PB = (N + 63) / 64;          // mfma proj
  const int Mhigh = E - N;               // 300000
  const int CFB = (Mhigh + 255) / 256;   // chunk_fold v2

  hipMemsetAsync(deg, 0, (size_t)N * 4, stream);
  count_deg_kernel<<<EB, 256, 0, stream>>>(dst, deg, E);
  scan_kernel<<<1, 1024, 0, stream>>>(deg, rowptr, cursor, N);
  fill_csr_kernel<<<EB, 256, 0, stream>>>(src, dst, cursor, csr_src, csr_eid, E);
  prep_all_kernel<<<515, 256, 0, stream>>>(n1_wl, n1_wr, e1_wl, e1_wr,
                                           n2_wl, n2_wr, e2_wl, e2_wr,
                                           e2_b, crf_wp,
                                           t_n1l, t_n1r, t_e1l, t_e1r,
                                           t_n2l, t_n2r, t_e2l, t_e2r, WcT, pcv);

  // ---- layer 1 projections, both chains (z = chain) ----
  mfma_proj2_kernel<64><<<dim3(PB, 8, 2), 128, 0, stream>>>(
      x, t_n1l, t_n1r, xl_n, xr_n,
      edge_type, t_e1l, t_e1r, xl_e, xr_e, N, 4);
  // ---- layer 1 aggregation, fused (2N blocks) ----
  gat_agg_v3<true, 256><<<2 * N, 256, 0, stream>>>(
      xl_n, xr_n, n1_att, n1_b, h_n, 256,
      xl_e, xr_e, e1_att, e1_b, g_e, 256, rowptr, csr_src);

  // ---- layer 2 projections, both chains ----
  mfma_proj2_kernel<256><<<dim3(PB, 2, 2), 128, 0, stream>>>(
      h_n, t_n2l, t_n2r, xl2_n, xr2_n,
      g_e, t_e2l, t_e2r, xl2_e, xr2_e, N, 1);
  // ---- layer 2 aggregation, fused -> B3 / erlow ----
  gat_agg_v3<false, 64><<<2 * N, 64, 0, stream>>>(
      xl2_n, xr2_n, n2_att, n2_b, B3, 64,
      xl2_e, xr2_e, e2_att, e2_b, erlow, 64, rowptr, csr_src);

  // ---- CRF per-edge p pairs ----
  edge_dot_kernel<<<(N + 255) / 256, 256, 0, stream>>>(erlow, crf_wp, pbuf, N);
  chunk_fold_kernel<<<CFB, 256, 0, stream>>>(edge_type + (size_t)N * 64, t_e1l,
                                             e1_b, WcT, pcv, pbuf + 2 * (size_t)N, Mhigh);

  // ---- heads ----
  gemm64_kernel<64, 3><<<dim3(NB, 2), 256, 0, stream>>>(B3, px_w1, 128, px_b1, ph, 128, N);
  head_kernel<<<(N + 255) / 256, 256, 0, stream>>>(B3, ph, rowptr, csr_eid, pbuf,
                                                   crf_wu, crf_bu, px_w2, px_b2, out, N);
}

// Round 13
// 465.576 us; speedup vs baseline: 1.4991x; 1.0844x over previous
//
#include <hip/hip_runtime.h>
#include <cstddef>
#include <cstdint>

#define N_NODES 20000
#define N_EDGES 320000

typedef __attribute__((ext_vector_type(8))) short bf8_t;   // 8 x bf16 (MFMA frag)
typedef __attribute__((ext_vector_type(4))) float f4_t;    // MFMA acc / float4
typedef __attribute__((ext_vector_type(2))) float f2_t;    // packed fp32 pair
typedef unsigned short bfu;                                 // bf16 storage
typedef __attribute__((ext_vector_type(4))) unsigned short us4_t;
typedef __attribute__((ext_vector_type(8))) unsigned short us8_t;

__device__ __forceinline__ short f2bf(float f) {
  unsigned u = __float_as_uint(f);
  u += 0x7fff + ((u >> 16) & 1);   // round-to-nearest-even
  return (short)(u >> 16);
}
// leaky_relu(t) = max(t,0) + 0.2*min(t,0)
__device__ __forceinline__ f2_t leaky2(f2_t t) {
  f2_t zero = {0.f, 0.f};
  f2_t mx = __builtin_elementwise_max(t, zero);
  f2_t mn = __builtin_elementwise_min(t, zero);
  return mn * 0.2f + mx;
}
__device__ __forceinline__ void bf8_to_f2x4(us8_t xu, f2_t o[4]) {
  union { us8_t v; unsigned u[4]; } c; c.v = xu;
  #pragma unroll
  for (int j = 0; j < 4; ++j) {
    unsigned d = c.u[j];
    f2_t t;
    t.x = __uint_as_float(d << 16);
    t.y = __uint_as_float(d & 0xffff0000u);
    o[j] = t;
  }
}

// ======================= CSR build =======================
__global__ void count_deg_kernel(const int* __restrict__ dst, int* __restrict__ deg, int e_cnt) {
  int e = blockIdx.x * blockDim.x + threadIdx.x;
  if (e < e_cnt) atomicAdd(&deg[dst[e]], 1);
}

// one-pass: per-thread 20-elem serial prefix + single 1024 block scan
__global__ __launch_bounds__(1024) void scan_kernel(
    const int* __restrict__ deg, int* __restrict__ rowptr,
    int* __restrict__ cursor, int n) {
  __shared__ int sdata[1024];
  const int CH = (n + 1023) / 1024;   // 20 for n=20000
  int tid = threadIdx.x;
  int base = tid * CH;
  int loc[20];
  int s = 0;
  for (int j = 0; j < CH; ++j) {
    int idx = base + j;
    int v = (idx < n) ? deg[idx] : 0;
    loc[j] = s;
    s += v;
  }
  sdata[tid] = s;
  __syncthreads();
  for (int off = 1; off < 1024; off <<= 1) {
    int t = (tid >= off) ? sdata[tid - off] : 0;
    __syncthreads();
    sdata[tid] += t;
    __syncthreads();
  }
  int excl = sdata[tid] - s;
  for (int j = 0; j < CH; ++j) {
    int idx = base + j;
    if (idx < n) { int val = excl + loc[j]; rowptr[idx] = val; cursor[idx] = val; }
  }
  if (tid == 0) rowptr[n] = sdata[1023];
}

__global__ void fill_csr_kernel(const int* __restrict__ src, const int* __restrict__ dst,
                                int* __restrict__ cursor, int* __restrict__ csr_src,
                                int* __restrict__ csr_eid, int e_cnt) {
  int e = blockIdx.x * blockDim.x + threadIdx.x;
  if (e < e_cnt) {
    int pos = atomicAdd(&cursor[dst[e]], 1);
    csr_src[pos] = src[e];
    csr_eid[pos] = e;
  }
}

// ======================= weight prep =======================
__global__ void prep_all_kernel(
    const float* __restrict__ n1l, const float* __restrict__ n1r,
    const float* __restrict__ e1l, const float* __restrict__ e1r,
    const float* __restrict__ n2l, const float* __restrict__ n2r,
    const float* __restrict__ e2l, const float* __restrict__ e2r,
    const float* __restrict__ b2, const float* __restrict__ wp,
    short* __restrict__ t_n1l, short* __restrict__ t_n1r,
    short* __restrict__ t_e1l, short* __restrict__ t_e1r,
    short* __restrict__ t_n2l, short* __restrict__ t_n2r,
    short* __restrict__ t_e2l, short* __restrict__ t_e2r,
    float* __restrict__ wct, float* __restrict__ pc)
{
  int i = blockIdx.x * blockDim.x + threadIdx.x;
  int seg = i >> 14;
  int j = i & 16383;
  if (seg < 4) {
    const float* srcs[4] = {n1l, n1r, e1l, e1r};
    short* dsts[4] = {t_n1l, t_n1r, t_e1l, t_e1r};
    int n = j >> 6, k = j & 63;
    dsts[seg][n * 64 + k] = f2bf(srcs[seg][k * 256 + n]);
  } else if (seg < 8) {
    const float* srcs[4] = {n2l, n2r, e2l, e2r};
    short* dsts[4] = {t_n2l, t_n2r, t_e2l, t_e2r};
    int n = j >> 8, k = j & 255;
    dsts[seg - 4][n * 256 + k] = f2bf(srcs[seg - 4][k * 64 + n]);
  } else if (seg == 8) {
    if (j < 512) {
      int jj = j & 1;
      int k  = j >> 1;
      float s = 0.f;
      for (int c = 0; c < 64; ++c) s = fmaf(e2l[k * 64 + c], wp[c * 2 + jj], s);
      wct[jj * 256 + k] = s;
    } else if (j < 514) {
      int jj = j - 512;
      float s = 0.f;
      for (int c = 0; c < 64; ++c) s = fmaf(b2[c], wp[c * 2 + jj], s);
      pc[jj] = s;
    }
  }
}

// ======================= MFMA projection kernel (dual-chain) =======================
template<int K>
__global__ __launch_bounds__(128) void mfma_proj2_kernel(
    const float* __restrict__ A0,
    const short* __restrict__ Wtl0, const short* __restrict__ Wtr0,
    bfu* __restrict__ xl0, float* __restrict__ xr0,
    const float* __restrict__ A1,
    const short* __restrict__ Wtl1, const short* __restrict__ Wtr1,
    bfu* __restrict__ xl1, float* __restrict__ xr1,
    int M, int nslices)
{
  constexpr int KC = K / 32;
  int tid = threadIdx.x;
  int w = tid >> 6, lane = tid & 63, quad = lane >> 4, l15 = lane & 15;
  int row_base = (int)blockIdx.x * 64 + w * 32;
  int y = (int)blockIdx.y;
  int z = (int)blockIdx.z;
  const float* A = z ? A1 : A0;
  bool is_l = y < nslices;
  const short* Wt = z ? (is_l ? Wtl1 : Wtr1) : (is_l ? Wtl0 : Wtr0);
  bfu* xl = z ? xl1 : xl0;
  float* xr = z ? xr1 : xr0;
  int cb = (is_l ? y : y - nslices) * 64;
  int STR = nslices * 64;

  bf8_t a[2][KC];
  #pragma unroll
  for (int rt = 0; rt < 2; ++rt) {
    int r = row_base + rt * 16 + l15;
    int rc = r < M ? r : M - 1;
    const float* ap = A + (size_t)rc * K + quad * 8;
    #pragma unroll
    for (int kc = 0; kc < KC; ++kc) {
      float4 v0 = *(const float4*)(ap + kc * 32);
      float4 v1 = *(const float4*)(ap + kc * 32 + 4);
      bf8_t f;
      f[0] = f2bf(v0.x); f[1] = f2bf(v0.y); f[2] = f2bf(v0.z); f[3] = f2bf(v0.w);
      f[4] = f2bf(v1.x); f[5] = f2bf(v1.y); f[6] = f2bf(v1.z); f[7] = f2bf(v1.w);
      a[rt][kc] = f;
    }
  }

  #pragma unroll
  for (int nt = 0; nt < 4; ++nt) {
    f4_t acc0 = {0.f, 0.f, 0.f, 0.f};
    f4_t acc1 = {0.f, 0.f, 0.f, 0.f};
    const short* wb = Wt + (size_t)(cb + nt * 16 + l15) * K + quad * 8;
    #pragma unroll
    for (int kc = 0; kc < KC; ++kc) {
      bf8_t wf = *(const bf8_t*)(wb + kc * 32);
      acc0 = __builtin_amdgcn_mfma_f32_16x16x32_bf16(wf, a[0][kc], acc0, 0, 0, 0);
      acc1 = __builtin_amdgcn_mfma_f32_16x16x32_bf16(wf, a[1][kc], acc1, 0, 0, 0);
    }
    #pragma unroll
    for (int rt = 0; rt < 2; ++rt) {
      f4_t acc = rt == 0 ? acc0 : acc1;
      int row = row_base + rt * 16 + l15;
      if (row >= M) continue;
      int col = cb + nt * 16 + quad * 4;
      if (is_l) {
        us4_t pk;
        pk[0] = (bfu)f2bf(acc[0]); pk[1] = (bfu)f2bf(acc[1]);
        pk[2] = (bfu)f2bf(acc[2]); pk[3] = (bfu)f2bf(acc[3]);
        *(us4_t*)&xl[(size_t)row * STR + col] = pk;
      } else {
        *(float4*)&xr[(size_t)row * STR + col] = make_float4(acc[0], acc[1], acc[2], acc[3]);
      }
    }
  }
}

// ======================= fp32 GEMM (proxy head only) =======================
template<int KIN>
__device__ __forceinline__ void gemm_body(
    const float* __restrict__ A, const float* __restrict__ W, int wld, int cb,
    int block_m, int M, float (&acc)[8][4],
    float (*As)[128 + 4], float (*Ws)[64 + 4])
{
  int tid = threadIdx.x;
  int tx = tid & 15;
  int ty = tid >> 4;
  #pragma unroll
  for (int i = 0; i < 8; ++i)
    #pragma unroll
    for (int j = 0; j < 4; ++j) acc[i][j] = 0.f;

  for (int k0 = 0; k0 < KIN; k0 += 16) {
    #pragma unroll
    for (int rep = 0; rep < 2; ++rep) {
      int ar = (tid >> 2) + rep * 64;
      int ak = (tid & 3) * 4;
      int gr = block_m + ar;
      float4 v = make_float4(0.f, 0.f, 0.f, 0.f);
      if (gr < M) v = *(const float4*)&A[(size_t)gr * KIN + k0 + ak];
      As[ak + 0][ar] = v.x; As[ak + 1][ar] = v.y;
      As[ak + 2][ar] = v.z; As[ak + 3][ar] = v.w;
    }
    {
      int wr = tid >> 4;
      int wc = (tid & 15) * 4;
      float4 v = *(const float4*)&W[(size_t)(k0 + wr) * wld + cb + wc];
      Ws[wr][wc + 0] = v.x; Ws[wr][wc + 1] = v.y;
      Ws[wr][wc + 2] = v.z; Ws[wr][wc + 3] = v.w;
    }
    __syncthreads();
    #pragma unroll
    for (int k = 0; k < 16; ++k) {
      float a[8], w[4];
      #pragma unroll
      for (int i = 0; i < 8; ++i) a[i] = As[k][ty * 8 + i];
      #pragma unroll
      for (int j = 0; j < 4; ++j) w[j] = Ws[k][tx * 4 + j];
      #pragma unroll
      for (int i = 0; i < 8; ++i)
        #pragma unroll
        for (int j = 0; j < 4; ++j) acc[i][j] = fmaf(a[i], w[j], acc[i][j]);
    }
    __syncthreads();
  }
}

template<int KIN, int MODE>
__global__ __launch_bounds__(256) void gemm64_kernel(
    const float* __restrict__ A, const float* __restrict__ W, int wld,
    const float* __restrict__ bias, float* __restrict__ out, int old, int M)
{
  __shared__ float As[16][128 + 4];
  __shared__ float Ws[16][64 + 4];
  float acc[8][4];
  int block_m = (int)blockIdx.x * 128;
  int cb = (int)blockIdx.y * 64;
  gemm_body<KIN>(A, W, wld, cb, block_m, M, acc, As, Ws);

  int tid = threadIdx.x;
  int tx = tid & 15, ty = tid >> 4;
  int gc = cb + tx * 4;
  #pragma unroll
  for (int i = 0; i < 8; ++i) {
    int gr = block_m + ty * 8 + i;
    if (gr >= M) continue;
    size_t idx = (size_t)gr * old + gc;
    float t0 = acc[i][0], t1 = acc[i][1], t2 = acc[i][2], t3 = acc[i][3];
    if (MODE == 3) {
      t0 = fmaxf(t0 + bias[gc + 0], 0.f);
      t1 = fmaxf(t1 + bias[gc + 1], 0.f);
      t2 = fmaxf(t2 + bias[gc + 2], 0.f);
      t3 = fmaxf(t3 + bias[gc + 3], 0.f);
    }
    *(float4*)&out[idx] = make_float4(t0, t1, t2, t3);
  }
}

// ======================= GATv2 aggregation v4 =======================
// Direct-exp softmax (no max subtraction — logits ~O(10), exp safe in fp32;
// mathematically identical to the max-subtracted reference). Iterations are
// pure accumulation -> no serial chain, gathers pipeline freely.
// FUSEP: for chain-1 epilogue, compute p = (acc/z + bias)@wp and write pbuf
// instead of materializing the output row.
template<bool ELU, int STR, bool FUSEP>
__global__ __launch_bounds__(STR == 256 ? 256 : 64) void gat_agg_v4(
    const bfu* __restrict__ xl0, const float* __restrict__ xr0,
    const float* __restrict__ att0, const float* __restrict__ bias0,
    float* __restrict__ out0, int old0,
    const bfu* __restrict__ xl1, const float* __restrict__ xr1,
    const float* __restrict__ att1, const float* __restrict__ bias1,
    float* __restrict__ out1, int old1,
    const int* __restrict__ rowptr, const int* __restrict__ csr_src,
    const float* __restrict__ wp, float* __restrict__ pbuf)
{
  int d = blockIdx.x;
  bool c1 = d >= N_NODES;
  if (c1) d -= N_NODES;
  const bfu* xl = c1 ? xl1 : xl0;
  const float* xr = c1 ? xr1 : xr0;
  const float* att = c1 ? att1 : att0;
  const float* bias = c1 ? bias1 : bias0;

  int tid = threadIdx.x;
  int h = tid >> 6;
  int lane = tid & 63;
  int egrp = lane >> 3;
  int cch  = lane & 7;
  int row0 = rowptr[d];
  int deg = rowptr[d + 1] - row0;
  int cbase = h * 64 + cch * 8;

  f2_t xr2[4], att2[4];
  {
    const float* xrp = xr + (size_t)d * STR + cbase;
    const float* atp = att + cbase;
    float4 a0 = *(const float4*)(xrp);
    float4 a1 = *(const float4*)(xrp + 4);
    xr2[0] = f2_t{a0.x, a0.y}; xr2[1] = f2_t{a0.z, a0.w};
    xr2[2] = f2_t{a1.x, a1.y}; xr2[3] = f2_t{a1.z, a1.w};
    float4 b0 = *(const float4*)(atp);
    float4 b1 = *(const float4*)(atp + 4);
    att2[0] = f2_t{b0.x, b0.y}; att2[1] = f2_t{b0.z, b0.w};
    att2[2] = f2_t{b1.x, b1.y}; att2[3] = f2_t{b1.z, b1.w};
  }

  float zloc;
  f2_t acc4[4];
  {
    us8_t xu = *(const us8_t*)&xl[(size_t)d * STR + cbase];
    f2_t xs[4];
    bf8_to_f2x4(xu, xs);
    f2_t p2 = {0.f, 0.f};
    #pragma unroll
    for (int j = 0; j < 4; ++j) p2 = p2 + leaky2(xs[j] + xr2[j]) * att2[j];
    float part = p2.x + p2.y;
    part += __shfl_xor(part, 1, 64);
    part += __shfl_xor(part, 2, 64);
    part += __shfl_xor(part, 4, 64);
    float w = __expf(part);
    float ws = (egrp == 0) ? w : 0.f;
    zloc = ws;
    f2_t ws2 = {ws, ws};
    #pragma unroll
    for (int j = 0; j < 4; ++j) acc4[j] = xs[j] * ws2;
  }

  for (int j = 0; j < deg; j += 8) {
    int idx = j + egrp;
    bool valid = idx < deg;
    int s = valid ? csr_src[row0 + idx] : d;
    us8_t xu = *(const us8_t*)&xl[(size_t)s * STR + cbase];
    f2_t xf[4];
    bf8_to_f2x4(xu, xf);
    f2_t p2 = {0.f, 0.f};
    #pragma unroll
    for (int i = 0; i < 4; ++i) p2 = p2 + leaky2(xf[i] + xr2[i]) * att2[i];
    float part = p2.x + p2.y;
    part += __shfl_xor(part, 1, 64);
    part += __shfl_xor(part, 2, 64);
    part += __shfl_xor(part, 4, 64);
    float w = valid ? __expf(part) : 0.f;
    zloc += w;
    f2_t w2 = {w, w};
    #pragma unroll
    for (int i = 0; i < 4; ++i) acc4[i] = acc4[i] + xf[i] * w2;
  }

  float a8[8];
  #pragma unroll
  for (int i = 0; i < 4; ++i) { a8[2 * i] = acc4[i].x; a8[2 * i + 1] = acc4[i].y; }
  #pragma unroll
  for (int off = 8; off < 64; off <<= 1) {
    zloc += __shfl_xor(zloc, off, 64);
    #pragma unroll
    for (int i = 0; i < 8; ++i) a8[i] += __shfl_xor(a8[i], off, 64);
  }

  float invz = 1.f / zloc;
  float o[8];
  #pragma unroll
  for (int i = 0; i < 8; ++i) {
    float val = a8[i] * invz + bias[cbase + i];
    if (ELU) val = val > 0.f ? val : __expf(val) - 1.f;
    o[i] = val;
  }

  if (FUSEP && c1) {
    // p = o . wp  (per-lane 8 channels, then reduce over cch)
    float p0 = 0.f, p1 = 0.f;
    #pragma unroll
    for (int i = 0; i < 8; ++i) {
      float2 wv = *(const float2*)&wp[(cbase + i) * 2];
      p0 = fmaf(o[i], wv.x, p0);
      p1 = fmaf(o[i], wv.y, p1);
    }
    p0 += __shfl_xor(p0, 1, 64); p1 += __shfl_xor(p1, 1, 64);
    p0 += __shfl_xor(p0, 2, 64); p1 += __shfl_xor(p1, 2, 64);
    p0 += __shfl_xor(p0, 4, 64); p1 += __shfl_xor(p1, 4, 64);
    if (lane == 0) *(float2*)&pbuf[2 * d] = make_float2(p0, p1);
  } else if (egrp == 0) {
    float* out = c1 ? out1 : out0;
    int old = c1 ? old1 : old0;
    float* op = out + (size_t)d * old + cbase;
    *(float4*)(op)     = make_float4(o[0], o[1], o[2], o[3]);
    *(float4*)(op + 4) = make_float4(o[4], o[5], o[6], o[7]);
  }
}

// ======================= folded chunk kernel v2 (edge rows >= N) =======================
__global__ __launch_bounds__(256) void chunk_fold_kernel(
    const float* __restrict__ A,
    const short* __restrict__ W1t,
    const float* __restrict__ b1,
    const float* __restrict__ WcT,
    const float* __restrict__ pc,
    float* __restrict__ pbufN,
    int Mtot)
{
  int tid = threadIdx.x;
  int w = tid >> 6;
  int lane = tid & 63;
  int quad = lane >> 4;
  int l15 = lane & 15;
  int row_base = (int)blockIdx.x * 256 + w * 64;

  bf8_t a1[4][2];
  #pragma unroll
  for (int rt = 0; rt < 4; ++rt) {
    int r = row_base + rt * 16 + l15;
    int rc = r < Mtot ? r : Mtot - 1;
    const float* ap = A + (size_t)rc * 64 + quad * 8;
    #pragma unroll
    for (int ks = 0; ks < 2; ++ks) {
      float4 v0 = *(const float4*)(ap + ks * 32);
      float4 v1 = *(const float4*)(ap + ks * 32 + 4);
      bf8_t f;
      f[0] = f2bf(v0.x); f[1] = f2bf(v0.y); f[2] = f2bf(v0.z); f[3] = f2bf(v0.w);
      f[4] = f2bf(v1.x); f[5] = f2bf(v1.y); f[6] = f2bf(v1.z); f[7] = f2bf(v1.w);
      a1[rt][ks] = f;
    }
  }

  float p0[4] = {0.f, 0.f, 0.f, 0.f};
  float p1[4] = {0.f, 0.f, 0.f, 0.f};

  #pragma unroll
  for (int cc = 0; cc < 4; ++cc) {
    #pragma unroll
    for (int nt = 0; nt < 4; ++nt) {
      const short* wb = W1t + (cc * 64 + nt * 16 + l15) * 64 + quad * 8;
      bf8_t w0 = *(const bf8_t*)(wb);
      bf8_t w1 = *(const bf8_t*)(wb + 32);
      f4_t g[4];
      #pragma unroll
      for (int rt = 0; rt < 4; ++rt) {
        f4_t z = {0.f, 0.f, 0.f, 0.f};
        z = __builtin_amdgcn_mfma_f32_16x16x32_bf16(w0, a1[rt][0], z, 0, 0, 0);
        z = __builtin_amdgcn_mfma_f32_16x16x32_bf16(w1, a1[rt][1], z, 0, 0, 0);
        g[rt] = z;
      }
      int cbase = cc * 64 + nt * 16 + quad * 4;
      f4_t b4  = *(const f4_t*)&b1[cbase];
      f4_t wc0 = *(const f4_t*)&WcT[cbase];
      f4_t wc1 = *(const f4_t*)&WcT[256 + cbase];
      #pragma unroll
      for (int rt = 0; rt < 4; ++rt) {
        #pragma unroll
        for (int r = 0; r < 4; ++r) {
          float v = g[rt][r] + b4[r];
          v = v > 0.f ? v : __expf(v) - 1.f;
          p0[rt] = fmaf(v, wc0[r], p0[rt]);
          p1[rt] = fmaf(v, wc1[r], p1[rt]);
        }
      }
    }
  }

  #pragma unroll
  for (int off = 16; off < 64; off <<= 1) {
    #pragma unroll
    for (int rt = 0; rt < 4; ++rt) {
      p0[rt] += __shfl_xor(p0[rt], off, 64);
      p1[rt] += __shfl_xor(p1[rt], off, 64);
    }
  }
  if (quad == 0) {
    float c0 = pc[0], c1 = pc[1];
    #pragma unroll
    for (int rt = 0; rt < 4; ++rt) {
      int row = row_base + rt * 16 + l15;
      if (row < Mtot)
        *(float2*)&pbufN[2 * row] = make_float2(p0[rt] + c0, p1[rt] + c1);
    }
  }
}

// ======================= Heads =======================
__global__ void head_kernel(const float* __restrict__ node_repr, const float* __restrict__ ph,
                            const int* __restrict__ rowptr, const int* __restrict__ csr_eid,
                            const float* __restrict__ pbuf, const float* __restrict__ wu,
                            const float* __restrict__ bu, const float* __restrict__ w2,
                            const float* __restrict__ b2, float* __restrict__ out, int n) {
  __shared__ float swu[128];
  __shared__ float sw2[256];
  int tid = threadIdx.x;
  if (tid < 128) swu[tid] = wu[tid];
  sw2[tid] = w2[tid];
  __syncthreads();
  int i = blockIdx.x * blockDim.x + tid;
  if (i >= n) return;
  float m0 = 0.f, m1 = 0.f;
  int r0 = rowptr[i], r1 = rowptr[i + 1];
  int jj = r0;
  for (; jj + 4 <= r1; jj += 4) {
    int e0 = csr_eid[jj + 0], e1 = csr_eid[jj + 1];
    int e2 = csr_eid[jj + 2], e3 = csr_eid[jj + 3];
    float2 q0 = *(const float2*)&pbuf[2 * e0];
    float2 q1 = *(const float2*)&pbuf[2 * e1];
    float2 q2 = *(const float2*)&pbuf[2 * e2];
    float2 q3 = *(const float2*)&pbuf[2 * e3];
    m0 += (q0.x + q1.x) + (q2.x + q3.x);
    m1 += (q0.y + q1.y) + (q2.y + q3.y);
  }
  for (; jj < r1; ++jj) {
    int e = csr_eid[jj];
    float2 q = *(const float2*)&pbuf[2 * e];
    m0 += q.x; m1 += q.y;
  }
  const float* nr = node_repr + (size_t)i * 64;
  float u0 = bu[0], u1 = bu[1];
  #pragma unroll
  for (int k = 0; k < 64; ++k) {
    float v = nr[k];
    u0 = fmaf(v, swu[2 * k + 0], u0);
    u1 = fmaf(v, swu[2 * k + 1], u1);
  }
  float v0 = u0 + m0;
  float v1 = u1 + m1;
  float mx = fmaxf(v0, v1);
  float lse = mx + logf(__expf(v0 - mx) + __expf(v1 - mx));
  out[2 * i + 0] = v0 - lse;
  out[2 * i + 1] = v1 - lse;
  const float* p = ph + (size_t)i * 128;
  float p0 = b2[0], p1 = b2[1];
  #pragma unroll
  for (int k = 0; k < 128; ++k) {
    float v = p[k];
    p0 = fmaf(v, sw2[2 * k + 0], p0);
    p1 = fmaf(v, sw2[2 * k + 1], p1);
  }
  out[2 * n + 2 * i + 0] = p0;
  out[2 * n + 2 * i + 1] = p1;
}

// ======================= launch =======================
extern "C" void kernel_launch(void* const* d_in, const int* in_sizes, int n_in,
                              void* d_out, int out_size, void* d_ws, size_t ws_size,
                              hipStream_t stream) {
  const int N = N_NODES, E = N_EDGES;
  const float* x         = (const float*)d_in[0];
  const float* edge_type = (const float*)d_in[1];
  const int*   ei        = (const int*)d_in[2];
  const float* n1_wl  = (const float*)d_in[3];
  const float* n1_wr  = (const float*)d_in[4];
  const float* n1_att = (const float*)d_in[5];
  const float* n1_b   = (const float*)d_in[6];
  const float* n2_wl  = (const float*)d_in[7];
  const float* n2_wr  = (const float*)d_in[8];
  const float* n2_att = (const float*)d_in[9];
  const float* n2_b   = (const float*)d_in[10];
  const float* e1_wl  = (const float*)d_in[11];
  const float* e1_wr  = (const float*)d_in[12];
  const float* e1_att = (const float*)d_in[13];
  const float* e1_b   = (const float*)d_in[14];
  const float* e2_wl  = (const float*)d_in[15];
  const float* e2_wr  = (const float*)d_in[16];
  const float* e2_att = (const float*)d_in[17];
  const float* e2_b   = (const float*)d_in[18];
  const float* crf_wu = (const float*)d_in[19];
  const float* crf_bu = (const float*)d_in[20];
  const float* crf_wp = (const float*)d_in[21];
  const float* px_w1  = (const float*)d_in[22];
  const float* px_b1  = (const float*)d_in[23];
  const float* px_w2  = (const float*)d_in[24];
  const float* px_b2  = (const float*)d_in[25];
  float* out = (float*)d_out;
  const int* src = ei;
  const int* dst = ei + E;
  (void)in_sizes; (void)n_in; (void)out_size; (void)ws_size;

  // ---- workspace layout ----
  char* ws = (char*)d_ws;
  size_t off = 0;
  auto alloc = [&](size_t bytes) -> void* {
    void* p = ws + off;
    off += (bytes + 255) & ~(size_t)255;
    return p;
  };
  bfu*   xl_n  = (bfu*)alloc((size_t)N * 256 * 2);
  float* xr_n  = (float*)alloc((size_t)N * 256 * 4);
  bfu*   xl_e  = (bfu*)alloc((size_t)N * 256 * 2);
  float* xr_e  = (float*)alloc((size_t)N * 256 * 4);
  float* h_n   = (float*)alloc((size_t)N * 256 * 4);
  float* g_e   = (float*)alloc((size_t)N * 256 * 4);
  bfu*   xl2_n = (bfu*)alloc((size_t)N * 64 * 2);
  float* xr2_n = (float*)alloc((size_t)N * 64 * 4);
  bfu*   xl2_e = (bfu*)alloc((size_t)N * 64 * 2);
  float* xr2_e = (float*)alloc((size_t)N * 64 * 4);
  float* B3    = (float*)alloc((size_t)N * 64 * 4);
  float* pbuf  = (float*)alloc((size_t)E * 2 * 4);
  float* ph    = (float*)(void*)xl_n;
  int* deg     = (int*)alloc((size_t)N * 4);
  int* rowptr  = (int*)alloc((size_t)(N + 1) * 4);
  int* cursor  = (int*)alloc((size_t)N * 4);
  int* csr_src = (int*)alloc((size_t)E * 4);
  int* csr_eid = (int*)alloc((size_t)E * 4);
  short* t_n1l = (short*)alloc((size_t)16384 * 2);
  short* t_n1r = (short*)alloc((size_t)16384 * 2);
  short* t_e1l = (short*)alloc((size_t)16384 * 2);
  short* t_e1r = (short*)alloc((size_t)16384 * 2);
  short* t_n2l = (short*)alloc((size_t)16384 * 2);
  short* t_n2r = (short*)alloc((size_t)16384 * 2);
  short* t_e2l = (short*)alloc((size_t)16384 * 2);
  short* t_e2r = (short*)alloc((size_t)16384 * 2);
  float* WcT   = (float*)alloc((size_t)2 * 256 * 4);
  float* pcv   = (float*)alloc((size_t)2 * 4);

  const int EB = (E + 255) / 256;
  const int NB = (N + 127) / 128;
  const int PB = (N + 63) / 64;
  const int Mhigh = E - N;
  const int CFB = (Mhigh + 255) / 256;

  hipMemsetAsync(deg, 0, (size_t)N * 4, stream);
  count_deg_kernel<<<EB, 256, 0, stream>>>(dst, deg, E);
  scan_kernel<<<1, 1024, 0, stream>>>(deg, rowptr, cursor, N);
  fill_csr_kernel<<<EB, 256, 0, stream>>>(src, dst, cursor, csr_src, csr_eid, E);
  prep_all_kernel<<<515, 256, 0, stream>>>(n1_wl, n1_wr, e1_wl, e1_wr,
                                           n2_wl, n2_wr, e2_wl, e2_wr,
                                           e2_b, crf_wp,
                                           t_n1l, t_n1r, t_e1l, t_e1r,
                                           t_n2l, t_n2r, t_e2l, t_e2r, WcT, pcv);

  // ---- layer 1: projections (both chains) + fused aggregation ----
  mfma_proj2_kernel<64><<<dim3(PB, 8, 2), 128, 0, stream>>>(
      x, t_n1l, t_n1r, xl_n, xr_n,
      edge_type, t_e1l, t_e1r, xl_e, xr_e, N, 4);
  gat_agg_v4<true, 256, false><<<2 * N, 256, 0, stream>>>(
      xl_n, xr_n, n1_att, n1_b, h_n, 256,
      xl_e, xr_e, e1_att, e1_b, g_e, 256, rowptr, csr_src, nullptr, nullptr);

  // ---- layer 2: projections + fused aggregation (chain1 -> pbuf directly) ----
  mfma_proj2_kernel<256><<<dim3(PB, 2, 2), 128, 0, stream>>>(
      h_n, t_n2l, t_n2r, xl2_n, xr2_n,
      g_e, t_e2l, t_e2r, xl2_e, xr2_e, N, 1);
  gat_agg_v4<false, 64, true><<<2 * N, 64, 0, stream>>>(
      xl2_n, xr2_n, n2_att, n2_b, B3, 64,
      xl2_e, xr2_e, e2_att, e2_b, nullptr, 64, rowptr, csr_src, crf_wp, pbuf);

  // ---- CRF p for self-loop-only edge rows ----
  chunk_fold_kernel<<<CFB, 256, 0, stream>>>(edge_type + (size_t)N * 64, t_e1l,
                                             e1_b, WcT, pcv, pbuf + 2 * (size_t)N, Mhigh);

  // ---- heads ----
  gemm64_kernel<64, 3><<<dim3(NB, 2), 256, 0, stream>>>(B3, px_w1, 128, px_b1, ph, 128, N);
  head_kernel<<<(N + 255) / 256, 256, 0, stream>>>(B3, ph, rowptr, csr_eid, pbuf,
                                                   crf_wu, crf_bu, px_w2, px_b2, out, N);
}

// Round 14
// 459.916 us; speedup vs baseline: 1.5175x; 1.0123x over previous
//
#include <hip/hip_runtime.h>
#include <cstddef>
#include <cstdint>

#define N_NODES 20000
#define N_EDGES 320000

typedef __attribute__((ext_vector_type(8))) short bf8_t;   // 8 x bf16 (MFMA frag)
typedef __attribute__((ext_vector_type(4))) float f4_t;    // MFMA acc / float4
typedef __attribute__((ext_vector_type(2))) float f2_t;    // packed fp32 pair
typedef unsigned short bfu;                                 // bf16 storage
typedef __attribute__((ext_vector_type(4))) unsigned short us4_t;
typedef __attribute__((ext_vector_type(8))) unsigned short us8_t;

__device__ __forceinline__ short f2bf(float f) {
  unsigned u = __float_as_uint(f);
  u += 0x7fff + ((u >> 16) & 1);   // round-to-nearest-even
  return (short)(u >> 16);
}
// leaky_relu(t) = max(t,0) + 0.2*min(t,0)
__device__ __forceinline__ f2_t leaky2(f2_t t) {
  f2_t zero = {0.f, 0.f};
  f2_t mx = __builtin_elementwise_max(t, zero);
  f2_t mn = __builtin_elementwise_min(t, zero);
  return mn * 0.2f + mx;
}
__device__ __forceinline__ void bf8_to_f2x4(us8_t xu, f2_t o[4]) {
  union { us8_t v; unsigned u[4]; } c; c.v = xu;
  #pragma unroll
  for (int j = 0; j < 4; ++j) {
    unsigned d = c.u[j];
    f2_t t;
    t.x = __uint_as_float(d << 16);
    t.y = __uint_as_float(d & 0xffff0000u);
    o[j] = t;
  }
}

// ======================= CSR build =======================
__global__ void count_deg_kernel(const int* __restrict__ dst, int* __restrict__ deg, int e_cnt) {
  int e = blockIdx.x * blockDim.x + threadIdx.x;
  if (e < e_cnt) atomicAdd(&deg[dst[e]], 1);
}

__global__ __launch_bounds__(1024) void scan_kernel(
    const int* __restrict__ deg, int* __restrict__ rowptr,
    int* __restrict__ cursor, int n) {
  __shared__ int sdata[1024];
  const int CH = (n + 1023) / 1024;   // 20 for n=20000
  int tid = threadIdx.x;
  int base = tid * CH;
  int loc[20];
  int s = 0;
  for (int j = 0; j < CH; ++j) {
    int idx = base + j;
    int v = (idx < n) ? deg[idx] : 0;
    loc[j] = s;
    s += v;
  }
  sdata[tid] = s;
  __syncthreads();
  for (int off = 1; off < 1024; off <<= 1) {
    int t = (tid >= off) ? sdata[tid - off] : 0;
    __syncthreads();
    sdata[tid] += t;
    __syncthreads();
  }
  int excl = sdata[tid] - s;
  for (int j = 0; j < CH; ++j) {
    int idx = base + j;
    if (idx < n) { int val = excl + loc[j]; rowptr[idx] = val; cursor[idx] = val; }
  }
  if (tid == 0) rowptr[n] = sdata[1023];
}

__global__ void fill_csr_kernel(const int* __restrict__ src, const int* __restrict__ dst,
                                int* __restrict__ cursor, int* __restrict__ csr_src,
                                int* __restrict__ csr_eid, int e_cnt) {
  int e = blockIdx.x * blockDim.x + threadIdx.x;
  if (e < e_cnt) {
    int pos = atomicAdd(&cursor[dst[e]], 1);
    csr_src[pos] = src[e];
    csr_eid[pos] = e;
  }
}

// ======================= weight prep =======================
__global__ void prep_all_kernel(
    const float* __restrict__ n1l, const float* __restrict__ n1r,
    const float* __restrict__ e1l, const float* __restrict__ e1r,
    const float* __restrict__ n2l, const float* __restrict__ n2r,
    const float* __restrict__ e2l, const float* __restrict__ e2r,
    const float* __restrict__ b2, const float* __restrict__ wp,
    short* __restrict__ t_n1l, short* __restrict__ t_n1r,
    short* __restrict__ t_e1l, short* __restrict__ t_e1r,
    short* __restrict__ t_n2l, short* __restrict__ t_n2r,
    short* __restrict__ t_e2l, short* __restrict__ t_e2r,
    float* __restrict__ wct, float* __restrict__ pc)
{
  int i = blockIdx.x * blockDim.x + threadIdx.x;
  int seg = i >> 14;
  int j = i & 16383;
  if (seg < 4) {
    const float* srcs[4] = {n1l, n1r, e1l, e1r};
    short* dsts[4] = {t_n1l, t_n1r, t_e1l, t_e1r};
    int n = j >> 6, k = j & 63;
    dsts[seg][n * 64 + k] = f2bf(srcs[seg][k * 256 + n]);
  } else if (seg < 8) {
    const float* srcs[4] = {n2l, n2r, e2l, e2r};
    short* dsts[4] = {t_n2l, t_n2r, t_e2l, t_e2r};
    int n = j >> 8, k = j & 255;
    dsts[seg - 4][n * 256 + k] = f2bf(srcs[seg - 4][k * 64 + n]);
  } else if (seg == 8) {
    if (j < 512) {
      int jj = j & 1;
      int k  = j >> 1;
      float s = 0.f;
      for (int c = 0; c < 64; ++c) s = fmaf(e2l[k * 64 + c], wp[c * 2 + jj], s);
      wct[jj * 256 + k] = s;
    } else if (j < 514) {
      int jj = j - 512;
      float s = 0.f;
      for (int c = 0; c < 64; ++c) s = fmaf(b2[c], wp[c * 2 + jj], s);
      pc[jj] = s;
    }
  }
}

// ======================= MFMA projection kernel (dual-chain) =======================
template<int K>
__global__ __launch_bounds__(128) void mfma_proj2_kernel(
    const float* __restrict__ A0,
    const short* __restrict__ Wtl0, const short* __restrict__ Wtr0,
    bfu* __restrict__ xl0, float* __restrict__ xr0,
    const float* __restrict__ A1,
    const short* __restrict__ Wtl1, const short* __restrict__ Wtr1,
    bfu* __restrict__ xl1, float* __restrict__ xr1,
    int M, int nslices)
{
  constexpr int KC = K / 32;
  int tid = threadIdx.x;
  int w = tid >> 6, lane = tid & 63, quad = lane >> 4, l15 = lane & 15;
  int row_base = (int)blockIdx.x * 64 + w * 32;
  int y = (int)blockIdx.y;
  int z = (int)blockIdx.z;
  const float* A = z ? A1 : A0;
  bool is_l = y < nslices;
  const short* Wt = z ? (is_l ? Wtl1 : Wtr1) : (is_l ? Wtl0 : Wtr0);
  bfu* xl = z ? xl1 : xl0;
  float* xr = z ? xr1 : xr0;
  int cb = (is_l ? y : y - nslices) * 64;
  int STR = nslices * 64;

  bf8_t a[2][KC];
  #pragma unroll
  for (int rt = 0; rt < 2; ++rt) {
    int r = row_base + rt * 16 + l15;
    int rc = r < M ? r : M - 1;
    const float* ap = A + (size_t)rc * K + quad * 8;
    #pragma unroll
    for (int kc = 0; kc < KC; ++kc) {
      float4 v0 = *(const float4*)(ap + kc * 32);
      float4 v1 = *(const float4*)(ap + kc * 32 + 4);
      bf8_t f;
      f[0] = f2bf(v0.x); f[1] = f2bf(v0.y); f[2] = f2bf(v0.z); f[3] = f2bf(v0.w);
      f[4] = f2bf(v1.x); f[5] = f2bf(v1.y); f[6] = f2bf(v1.z); f[7] = f2bf(v1.w);
      a[rt][kc] = f;
    }
  }

  #pragma unroll
  for (int nt = 0; nt < 4; ++nt) {
    f4_t acc0 = {0.f, 0.f, 0.f, 0.f};
    f4_t acc1 = {0.f, 0.f, 0.f, 0.f};
    const short* wb = Wt + (size_t)(cb + nt * 16 + l15) * K + quad * 8;
    #pragma unroll
    for (int kc = 0; kc < KC; ++kc) {
      bf8_t wf = *(const bf8_t*)(wb + kc * 32);
      acc0 = __builtin_amdgcn_mfma_f32_16x16x32_bf16(wf, a[0][kc], acc0, 0, 0, 0);
      acc1 = __builtin_amdgcn_mfma_f32_16x16x32_bf16(wf, a[1][kc], acc1, 0, 0, 0);
    }
    #pragma unroll
    for (int rt = 0; rt < 2; ++rt) {
      f4_t acc = rt == 0 ? acc0 : acc1;
      int row = row_base + rt * 16 + l15;
      if (row >= M) continue;
      int col = cb + nt * 16 + quad * 4;
      if (is_l) {
        us4_t pk;
        pk[0] = (bfu)f2bf(acc[0]); pk[1] = (bfu)f2bf(acc[1]);
        pk[2] = (bfu)f2bf(acc[2]); pk[3] = (bfu)f2bf(acc[3]);
        *(us4_t*)&xl[(size_t)row * STR + col] = pk;
      } else {
        *(float4*)&xr[(size_t)row * STR + col] = make_float4(acc[0], acc[1], acc[2], acc[3]);
      }
    }
  }
}

// ======================= fp32 GEMM (proxy head only) =======================
template<int KIN>
__device__ __forceinline__ void gemm_body(
    const float* __restrict__ A, const float* __restrict__ W, int wld, int cb,
    int block_m, int M, float (&acc)[8][4],
    float (*As)[128 + 4], float (*Ws)[64 + 4])
{
  int tid = threadIdx.x;
  int tx = tid & 15;
  int ty = tid >> 4;
  #pragma unroll
  for (int i = 0; i < 8; ++i)
    #pragma unroll
    for (int j = 0; j < 4; ++j) acc[i][j] = 0.f;

  for (int k0 = 0; k0 < KIN; k0 += 16) {
    #pragma unroll
    for (int rep = 0; rep < 2; ++rep) {
      int ar = (tid >> 2) + rep * 64;
      int ak = (tid & 3) * 4;
      int gr = block_m + ar;
      float4 v = make_float4(0.f, 0.f, 0.f, 0.f);
      if (gr < M) v = *(const float4*)&A[(size_t)gr * KIN + k0 + ak];
      As[ak + 0][ar] = v.x; As[ak + 1][ar] = v.y;
      As[ak + 2][ar] = v.z; As[ak + 3][ar] = v.w;
    }
    {
      int wr = tid >> 4;
      int wc = (tid & 15) * 4;
      float4 v = *(const float4*)&W[(size_t)(k0 + wr) * wld + cb + wc];
      Ws[wr][wc + 0] = v.x; Ws[wr][wc + 1] = v.y;
      Ws[wr][wc + 2] = v.z; Ws[wr][wc + 3] = v.w;
    }
    __syncthreads();
    #pragma unroll
    for (int k = 0; k < 16; ++k) {
      float a[8], w[4];
      #pragma unroll
      for (int i = 0; i < 8; ++i) a[i] = As[k][ty * 8 + i];
      #pragma unroll
      for (int j = 0; j < 4; ++j) w[j] = Ws[k][tx * 4 + j];
      #pragma unroll
      for (int i = 0; i < 8; ++i)
        #pragma unroll
        for (int j = 0; j < 4; ++j) acc[i][j] = fmaf(a[i], w[j], acc[i][j]);
    }
    __syncthreads();
  }
}

template<int KIN, int MODE>
__global__ __launch_bounds__(256) void gemm64_kernel(
    const float* __restrict__ A, const float* __restrict__ W, int wld,
    const float* __restrict__ bias, float* __restrict__ out, int old, int M)
{
  __shared__ float As[16][128 + 4];
  __shared__ float Ws[16][64 + 4];
  float acc[8][4];
  int block_m = (int)blockIdx.x * 128;
  int cb = (int)blockIdx.y * 64;
  gemm_body<KIN>(A, W, wld, cb, block_m, M, acc, As, Ws);

  int tid = threadIdx.x;
  int tx = tid & 15, ty = tid >> 4;
  int gc = cb + tx * 4;
  #pragma unroll
  for (int i = 0; i < 8; ++i) {
    int gr = block_m + ty * 8 + i;
    if (gr >= M) continue;
    size_t idx = (size_t)gr * old + gc;
    float t0 = acc[i][0], t1 = acc[i][1], t2 = acc[i][2], t3 = acc[i][3];
    if (MODE == 3) {
      t0 = fmaxf(t0 + bias[gc + 0], 0.f);
      t1 = fmaxf(t1 + bias[gc + 1], 0.f);
      t2 = fmaxf(t2 + bias[gc + 2], 0.f);
      t3 = fmaxf(t3 + bias[gc + 3], 0.f);
    }
    *(float4*)&out[idx] = make_float4(t0, t1, t2, t3);
  }
}

// ======================= GATv2 aggregation v5 =======================
// Direct-exp softmax, edge x channel-chunk tiling, 3-stage software pipeline
// (prefetch idx k+2, row k+1 while computing k), head-major block mapping for
// per-XCD L2 locality. Block = 256 thr: wave w handles dst d_base+w; all 4
// waves of a block work on the SAME head (one head slice hot per phase).
template<int STR, bool ELU, bool FUSEP>
__global__ __launch_bounds__(256) void gat_agg_v5(
    const bfu* __restrict__ xl0, const float* __restrict__ xr0,
    const float* __restrict__ att0, const float* __restrict__ bias0,
    float* __restrict__ out0,
    const bfu* __restrict__ xl1, const float* __restrict__ xr1,
    const float* __restrict__ att1, const float* __restrict__ bias1,
    float* __restrict__ out1,
    const int* __restrict__ rowptr, const int* __restrict__ csr_src,
    const float* __restrict__ wp, float* __restrict__ pbuf)
{
  constexpr int HEADS = STR / 64;          // 4 or 1
  constexpr int GRP = N_NODES / 4;         // 5000 blocks per (chain, head)
  int tid = threadIdx.x;
  int w = tid >> 6;
  int lane = tid & 63;
  int egrp = lane >> 3;
  int cch  = lane & 7;

  int bid = (int)blockIdx.x;
  int per_chain = HEADS * GRP;
  int chain = bid >= per_chain ? 1 : 0;
  int r = bid - chain * per_chain;
  int head = r / GRP;
  int d = (r - head * GRP) * 4 + w;

  const bfu* xl = chain ? xl1 : xl0;
  const float* xr = chain ? xr1 : xr0;
  const float* att = chain ? att1 : att0;
  const float* bias = chain ? bias1 : bias0;

  int row0 = rowptr[d];
  int deg = rowptr[d + 1] - row0;
  int cbase = head * 64 + cch * 8;

  f2_t xr2[4], att2[4];
  {
    const float* xrp = xr + (size_t)d * STR + cbase;
    const float* atp = att + cbase;
    float4 a0 = *(const float4*)(xrp);
    float4 a1 = *(const float4*)(xrp + 4);
    xr2[0] = f2_t{a0.x, a0.y}; xr2[1] = f2_t{a0.z, a0.w};
    xr2[2] = f2_t{a1.x, a1.y}; xr2[3] = f2_t{a1.z, a1.w};
    float4 b0 = *(const float4*)(atp);
    float4 b1 = *(const float4*)(atp + 4);
    att2[0] = f2_t{b0.x, b0.y}; att2[1] = f2_t{b0.z, b0.w};
    att2[2] = f2_t{b1.x, b1.y}; att2[3] = f2_t{b1.z, b1.w};
  }

  // clamped, branchless CSR index fetch for chunk k (invalid -> self d)
  auto ld_idx = [&](int k) -> int {
    int idx = k * 8 + egrp;
    int cl = idx < deg ? idx : (deg > 0 ? deg - 1 : 0);
    int pos = deg > 0 ? row0 + cl : 0;
    int sv = csr_src[pos];
    return idx < deg ? sv : d;
  };

  float zloc;
  f2_t acc4[4];
  {
    us8_t xu = *(const us8_t*)&xl[(size_t)d * STR + cbase];
    f2_t xs[4];
    bf8_to_f2x4(xu, xs);
    f2_t p2 = {0.f, 0.f};
    #pragma unroll
    for (int j = 0; j < 4; ++j) p2 = p2 + leaky2(xs[j] + xr2[j]) * att2[j];
    float part = p2.x + p2.y;
    part += __shfl_xor(part, 1, 64);
    part += __shfl_xor(part, 2, 64);
    part += __shfl_xor(part, 4, 64);
    float wgt = __expf(part);
    float ws = (egrp == 0) ? wgt : 0.f;
    zloc = ws;
    f2_t ws2 = {ws, ws};
    #pragma unroll
    for (int j = 0; j < 4; ++j) acc4[j] = xs[j] * ws2;
  }

  int C = (deg + 7) >> 3;
  int s_cur = ld_idx(0);
  us8_t xu_cur = *(const us8_t*)&xl[(size_t)s_cur * STR + cbase];
  int s_nxt = ld_idx(1);
  for (int k = 0; k < C; ++k) {
    // stage: row gather for k+1, idx fetch for k+2 (issued before compute)
    us8_t xu_nxt = *(const us8_t*)&xl[(size_t)s_nxt * STR + cbase];
    int s_n2 = ld_idx(k + 2);
    // compute chunk k
    bool valid = (k * 8 + egrp) < deg;
    f2_t xf[4];
    bf8_to_f2x4(xu_cur, xf);
    f2_t p2 = {0.f, 0.f};
    #pragma unroll
    for (int i = 0; i < 4; ++i) p2 = p2 + leaky2(xf[i] + xr2[i]) * att2[i];
    float part = p2.x + p2.y;
    part += __shfl_xor(part, 1, 64);
    part += __shfl_xor(part, 2, 64);
    part += __shfl_xor(part, 4, 64);
    float wgt = valid ? __expf(part) : 0.f;
    zloc += wgt;
    f2_t w2 = {wgt, wgt};
    #pragma unroll
    for (int i = 0; i < 4; ++i) acc4[i] = acc4[i] + xf[i] * w2;
    xu_cur = xu_nxt;
    s_nxt = s_n2;
  }

  float a8[8];
  #pragma unroll
  for (int i = 0; i < 4; ++i) { a8[2 * i] = acc4[i].x; a8[2 * i + 1] = acc4[i].y; }
  #pragma unroll
  for (int off = 8; off < 64; off <<= 1) {
    zloc += __shfl_xor(zloc, off, 64);
    #pragma unroll
    for (int i = 0; i < 8; ++i) a8[i] += __shfl_xor(a8[i], off, 64);
  }

  float invz = 1.f / zloc;
  float o[8];
  #pragma unroll
  for (int i = 0; i < 8; ++i) {
    float val = a8[i] * invz + bias[cbase + i];
    if (ELU) val = val > 0.f ? val : __expf(val) - 1.f;
    o[i] = val;
  }

  if (FUSEP && chain) {
    float p0 = 0.f, p1 = 0.f;
    #pragma unroll
    for (int i = 0; i < 8; ++i) {
      float2 wv = *(const float2*)&wp[(cbase + i) * 2];
      p0 = fmaf(o[i], wv.x, p0);
      p1 = fmaf(o[i], wv.y, p1);
    }
    p0 += __shfl_xor(p0, 1, 64); p1 += __shfl_xor(p1, 1, 64);
    p0 += __shfl_xor(p0, 2, 64); p1 += __shfl_xor(p1, 2, 64);
    p0 += __shfl_xor(p0, 4, 64); p1 += __shfl_xor(p1, 4, 64);
    if (lane == 0) *(float2*)&pbuf[2 * d] = make_float2(p0, p1);
  } else if (egrp == 0) {
    float* out = chain ? out1 : out0;
    float* op = out + (size_t)d * STR + cbase;
    *(float4*)(op)     = make_float4(o[0], o[1], o[2], o[3]);
    *(float4*)(op + 4) = make_float4(o[4], o[5], o[6], o[7]);
  }
}

// ======================= folded chunk kernel v2 (edge rows >= N) =======================
__global__ __launch_bounds__(256) void chunk_fold_kernel(
    const float* __restrict__ A,
    const short* __restrict__ W1t,
    const float* __restrict__ b1,
    const float* __restrict__ WcT,
    const float* __restrict__ pc,
    float* __restrict__ pbufN,
    int Mtot)
{
  int tid = threadIdx.x;
  int w = tid >> 6;
  int lane = tid & 63;
  int quad = lane >> 4;
  int l15 = lane & 15;
  int row_base = (int)blockIdx.x * 256 + w * 64;

  bf8_t a1[4][2];
  #pragma unroll
  for (int rt = 0; rt < 4; ++rt) {
    int r = row_base + rt * 16 + l15;
    int rc = r < Mtot ? r : Mtot - 1;
    const float* ap = A + (size_t)rc * 64 + quad * 8;
    #pragma unroll
    for (int ks = 0; ks < 2; ++ks) {
      float4 v0 = *(const float4*)(ap + ks * 32);
      float4 v1 = *(const float4*)(ap + ks * 32 + 4);
      bf8_t f;
      f[0] = f2bf(v0.x); f[1] = f2bf(v0.y); f[2] = f2bf(v0.z); f[3] = f2bf(v0.w);
      f[4] = f2bf(v1.x); f[5] = f2bf(v1.y); f[6] = f2bf(v1.z); f[7] = f2bf(v1.w);
      a1[rt][ks] = f;
    }
  }

  float p0[4] = {0.f, 0.f, 0.f, 0.f};
  float p1[4] = {0.f, 0.f, 0.f, 0.f};

  #pragma unroll
  for (int cc = 0; cc < 4; ++cc) {
    #pragma unroll
    for (int nt = 0; nt < 4; ++nt) {
      const short* wb = W1t + (cc * 64 + nt * 16 + l15) * 64 + quad * 8;
      bf8_t w0 = *(const bf8_t*)(wb);
      bf8_t w1 = *(const bf8_t*)(wb + 32);
      f4_t g[4];
      #pragma unroll
      for (int rt = 0; rt < 4; ++rt) {
        f4_t z = {0.f, 0.f, 0.f, 0.f};
        z = __builtin_amdgcn_mfma_f32_16x16x32_bf16(w0, a1[rt][0], z, 0, 0, 0);
        z = __builtin_amdgcn_mfma_f32_16x16x32_bf16(w1, a1[rt][1], z, 0, 0, 0);
        g[rt] = z;
      }
      int cbase = cc * 64 + nt * 16 + quad * 4;
      f4_t b4  = *(const f4_t*)&b1[cbase];
      f4_t wc0 = *(const f4_t*)&WcT[cbase];
      f4_t wc1 = *(const f4_t*)&WcT[256 + cbase];
      #pragma unroll
      for (int rt = 0; rt < 4; ++rt) {
        #pragma unroll
        for (int r = 0; r < 4; ++r) {
          float v = g[rt][r] + b4[r];
          v = v > 0.f ? v : __expf(v) - 1.f;
          p0[rt] = fmaf(v, wc0[r], p0[rt]);
          p1[rt] = fmaf(v, wc1[r], p1[rt]);
        }
      }
    }
  }

  #pragma unroll
  for (int off = 16; off < 64; off <<= 1) {
    #pragma unroll
    for (int rt = 0; rt < 4; ++rt) {
      p0[rt] += __shfl_xor(p0[rt], off, 64);
      p1[rt] += __shfl_xor(p1[rt], off, 64);
    }
  }
  if (quad == 0) {
    float c0 = pc[0], c1 = pc[1];
    #pragma unroll
    for (int rt = 0; rt < 4; ++rt) {
      int row = row_base + rt * 16 + l15;
      if (row < Mtot)
        *(float2*)&pbufN[2 * row] = make_float2(p0[rt] + c0, p1[rt] + c1);
    }
  }
}

// ======================= Heads =======================
__global__ void head_kernel(const float* __restrict__ node_repr, const float* __restrict__ ph,
                            const int* __restrict__ rowptr, const int* __restrict__ csr_eid,
                            const float* __restrict__ pbuf, const float* __restrict__ wu,
                            const float* __restrict__ bu, const float* __restrict__ w2,
                            const float* __restrict__ b2, float* __restrict__ out, int n) {
  __shared__ float swu[128];
  __shared__ float sw2[256];
  int tid = threadIdx.x;
  if (tid < 128) swu[tid] = wu[tid];
  sw2[tid] = w2[tid];
  __syncthreads();
  int i = blockIdx.x * blockDim.x + tid;
  if (i >= n) return;
  float m0 = 0.f, m1 = 0.f;
  int r0 = rowptr[i], r1 = rowptr[i + 1];
  int jj = r0;
  for (; jj + 4 <= r1; jj += 4) {
    int e0 = csr_eid[jj + 0], e1 = csr_eid[jj + 1];
    int e2 = csr_eid[jj + 2], e3 = csr_eid[jj + 3];
    float2 q0 = *(const float2*)&pbuf[2 * e0];
    float2 q1 = *(const float2*)&pbuf[2 * e1];
    float2 q2 = *(const float2*)&pbuf[2 * e2];
    float2 q3 = *(const float2*)&pbuf[2 * e3];
    m0 += (q0.x + q1.x) + (q2.x + q3.x);
    m1 += (q0.y + q1.y) + (q2.y + q3.y);
  }
  for (; jj < r1; ++jj) {
    int e = csr_eid[jj];
    float2 q = *(const float2*)&pbuf[2 * e];
    m0 += q.x; m1 += q.y;
  }
  const float* nr = node_repr + (size_t)i * 64;
  float u0 = bu[0], u1 = bu[1];
  #pragma unroll
  for (int k = 0; k < 64; ++k) {
    float v = nr[k];
    u0 = fmaf(v, swu[2 * k + 0], u0);
    u1 = fmaf(v, swu[2 * k + 1], u1);
  }
  float v0 = u0 + m0;
  float v1 = u1 + m1;
  float mx = fmaxf(v0, v1);
  float lse = mx + logf(__expf(v0 - mx) + __expf(v1 - mx));
  out[2 * i + 0] = v0 - lse;
  out[2 * i + 1] = v1 - lse;
  const float* p = ph + (size_t)i * 128;
  float p0 = b2[0], p1 = b2[1];
  #pragma unroll
  for (int k = 0; k < 128; ++k) {
    float v = p[k];
    p0 = fmaf(v, sw2[2 * k + 0], p0);
    p1 = fmaf(v, sw2[2 * k + 1], p1);
  }
  out[2 * n + 2 * i + 0] = p0;
  out[2 * n + 2 * i + 1] = p1;
}

// ======================= launch =======================
extern "C" void kernel_launch(void* const* d_in, const int* in_sizes, int n_in,
                              void* d_out, int out_size, void* d_ws, size_t ws_size,
                              hipStream_t stream) {
  const int N = N_NODES, E = N_EDGES;
  const float* x         = (const float*)d_in[0];
  const float* edge_type = (const float*)d_in[1];
  const int*   ei        = (const int*)d_in[2];
  const float* n1_wl  = (const float*)d_in[3];
  const float* n1_wr  = (const float*)d_in[4];
  const float* n1_att = (const float*)d_in[5];
  const float* n1_b   = (const float*)d_in[6];
  const float* n2_wl  = (const float*)d_in[7];
  const float* n2_wr  = (const float*)d_in[8];
  const float* n2_att = (const float*)d_in[9];
  const float* n2_b   = (const float*)d_in[10];
  const float* e1_wl  = (const float*)d_in[11];
  const float* e1_wr  = (const float*)d_in[12];
  const float* e1_att = (const float*)d_in[13];
  const float* e1_b   = (const float*)d_in[14];
  const float* e2_wl  = (const float*)d_in[15];
  const float* e2_wr  = (const float*)d_in[16];
  const float* e2_att = (const float*)d_in[17];
  const float* e2_b   = (const float*)d_in[18];
  const float* crf_wu = (const float*)d_in[19];
  const float* crf_bu = (const float*)d_in[20];
  const float* crf_wp = (const float*)d_in[21];
  const float* px_w1  = (const float*)d_in[22];
  const float* px_b1  = (const float*)d_in[23];
  const float* px_w2  = (const float*)d_in[24];
  const float* px_b2  = (const float*)d_in[25];
  float* out = (float*)d_out;
  const int* src = ei;
  const int* dst = ei + E;
  (void)in_sizes; (void)n_in; (void)out_size; (void)ws_size;

  // ---- workspace layout ----
  char* ws = (char*)d_ws;
  size_t off = 0;
  auto alloc = [&](size_t bytes) -> void* {
    void* p = ws + off;
    off += (bytes + 255) & ~(size_t)255;
    return p;
  };
  bfu*   xl_n  = (bfu*)alloc((size_t)N * 256 * 2);
  float* xr_n  = (float*)alloc((size_t)N * 256 * 4);
  bfu*   xl_e  = (bfu*)alloc((size_t)N * 256 * 2);
  float* xr_e  = (float*)alloc((size_t)N * 256 * 4);
  float* h_n   = (float*)alloc((size_t)N * 256 * 4);
  float* g_e   = (float*)alloc((size_t)N * 256 * 4);
  bfu*   xl2_n = (bfu*)alloc((size_t)N * 64 * 2);
  float* xr2_n = (float*)alloc((size_t)N * 64 * 4);
  bfu*   xl2_e = (bfu*)alloc((size_t)N * 64 * 2);
  float* xr2_e = (float*)alloc((size_t)N * 64 * 4);
  float* B3    = (float*)alloc((size_t)N * 64 * 4);
  float* pbuf  = (float*)alloc((size_t)E * 2 * 4);
  float* ph    = (float*)(void*)xl_n;
  int* deg     = (int*)alloc((size_t)N * 4);
  int* rowptr  = (int*)alloc((size_t)(N + 1) * 4);
  int* cursor  = (int*)alloc((size_t)N * 4);
  int* csr_src = (int*)alloc((size_t)E * 4);
  int* csr_eid = (int*)alloc((size_t)E * 4);
  short* t_n1l = (short*)alloc((size_t)16384 * 2);
  short* t_n1r = (short*)alloc((size_t)16384 * 2);
  short* t_e1l = (short*)alloc((size_t)16384 * 2);
  short* t_e1r = (short*)alloc((size_t)16384 * 2);
  short* t_n2l = (short*)alloc((size_t)16384 * 2);
  short* t_n2r = (short*)alloc((size_t)16384 * 2);
  short* t_e2l = (short*)alloc((size_t)16384 * 2);
  short* t_e2r = (short*)alloc((size_t)16384 * 2);
  float* WcT   = (float*)alloc((size_t)2 * 256 * 4);
  float* pcv   = (float*)alloc((size_t)2 * 4);

  const int EB = (E + 255) / 256;
  const int NB = (N + 127) / 128;
  const int PB = (N + 63) / 64;
  const int Mhigh = E - N;
  const int CFB = (Mhigh + 255) / 256;
  const int GRP = N / 4;                 // 5000

  hipMemsetAsync(deg, 0, (size_t)N * 4, stream);
  count_deg_kernel<<<EB, 256, 0, stream>>>(dst, deg, E);
  scan_kernel<<<1, 1024, 0, stream>>>(deg, rowptr, cursor, N);
  fill_csr_kernel<<<EB, 256, 0, stream>>>(src, dst, cursor, csr_src, csr_eid, E);
  prep_all_kernel<<<515, 256, 0, stream>>>(n1_wl, n1_wr, e1_wl, e1_wr,
                                           n2_wl, n2_wr, e2_wl, e2_wr,
                                           e2_b, crf_wp,
                                           t_n1l, t_n1r, t_e1l, t_e1r,
                                           t_n2l, t_n2r, t_e2l, t_e2r, WcT, pcv);

  // ---- layer 1: projections (both chains) + fused aggregation (head-major) ----
  mfma_proj2_kernel<64><<<dim3(PB, 8, 2), 128, 0, stream>>>(
      x, t_n1l, t_n1r, xl_n, xr_n,
      edge_type, t_e1l, t_e1r, xl_e, xr_e, N, 4);
  gat_agg_v5<256, true, false><<<2 * 4 * GRP, 256, 0, stream>>>(
      xl_n, xr_n, n1_att, n1_b, h_n,
      xl_e, xr_e, e1_att, e1_b, g_e, rowptr, csr_src, nullptr, nullptr);

  // ---- layer 2: projections + fused aggregation (chain1 -> pbuf directly) ----
  mfma_proj2_kernel<256><<<dim3(PB, 2, 2), 128, 0, stream>>>(
      h_n, t_n2l, t_n2r, xl2_n, xr2_n,
      g_e, t_e2l, t_e2r, xl2_e, xr2_e, N, 1);
  gat_agg_v5<64, false, true><<<2 * GRP, 256, 0, stream>>>(
      xl2_n, xr2_n, n2_att, n2_b, B3,
      xl2_e, xr2_e, e2_att, e2_b, nullptr, rowptr, csr_src, crf_wp, pbuf);

  // ---- CRF p for self-loop-only edge rows ----
  chunk_fold_kernel<<<CFB, 256, 0, stream>>>(edge_type + (size_t)N * 64, t_e1l,
                                             e1_b, WcT, pcv, pbuf + 2 * (size_t)N, Mhigh);

  // ---- heads ----
  gemm64_kernel<64, 3><<<dim3(NB, 2), 256, 0, stream>>>(B3, px_w1, 128, px_b1, ph, 128, N);
  head_kernel<<<(N + 255) / 256, 256, 0, stream>>>(B3, ph, rowptr, csr_eid, pbuf,
                                                   crf_wu, crf_bu, px_w2, px_b2, out, N);
}

// Round 15
// 456.573 us; speedup vs baseline: 1.5286x; 1.0073x over previous
//
#include <hip/hip_runtime.h>
#include <cstddef>
#include <cstdint>

#define N_NODES 20000
#define N_EDGES 320000

typedef __attribute__((ext_vector_type(8))) short bf8_t;   // 8 x bf16 (MFMA frag)
typedef __attribute__((ext_vector_type(4))) float f4_t;    // MFMA acc / float4
typedef __attribute__((ext_vector_type(2))) float f2_t;
typedef unsigned short bfu;
typedef _Float16 half_t;
typedef __attribute__((ext_vector_type(2))) _Float16 h2_t;
typedef __attribute__((ext_vector_type(4))) _Float16 h4_t;
typedef __attribute__((ext_vector_type(8))) _Float16 h8_t;

__device__ __forceinline__ short f2bf(float f) {
  unsigned u = __float_as_uint(f);
  u += 0x7fff + ((u >> 16) & 1);   // round-to-nearest-even
  return (short)(u >> 16);
}
// leaky on packed f16: max(t,0) + 0.2*min(t,0)
__device__ __forceinline__ h2_t leaky_h2(h2_t t) {
  h2_t zero = {(_Float16)0.f, (_Float16)0.f};
  h2_t mx = __builtin_elementwise_max(t, zero);
  h2_t mn = __builtin_elementwise_min(t, zero);
  h2_t c  = {(_Float16)0.2f, (_Float16)0.2f};
  return mn * c + mx;
}
__device__ __forceinline__ float dot2h(h2_t a, h2_t b, float c) {
#if __has_builtin(__builtin_amdgcn_fdot2)
  return __builtin_amdgcn_fdot2(a, b, c, false);
#else
  return c + (float)a.x * (float)b.x + (float)a.y * (float)b.y;
#endif
}

// ======================= CSR build =======================
__global__ void count_deg_kernel(const int* __restrict__ dst, int* __restrict__ deg, int e_cnt) {
  int e = blockIdx.x * blockDim.x + threadIdx.x;
  if (e < e_cnt) atomicAdd(&deg[dst[e]], 1);
}

__global__ __launch_bounds__(1024) void scan_kernel(
    const int* __restrict__ deg, int* __restrict__ rowptr,
    int* __restrict__ cursor, int n) {
  __shared__ int sdata[1024];
  const int CH = (n + 1023) / 1024;
  int tid = threadIdx.x;
  int base = tid * CH;
  int loc[20];
  int s = 0;
  for (int j = 0; j < CH; ++j) {
    int idx = base + j;
    int v = (idx < n) ? deg[idx] : 0;
    loc[j] = s;
    s += v;
  }
  sdata[tid] = s;
  __syncthreads();
  for (int off = 1; off < 1024; off <<= 1) {
    int t = (tid >= off) ? sdata[tid - off] : 0;
    __syncthreads();
    sdata[tid] += t;
    __syncthreads();
  }
  int excl = sdata[tid] - s;
  for (int j = 0; j < CH; ++j) {
    int idx = base + j;
    if (idx < n) { int val = excl + loc[j]; rowptr[idx] = val; cursor[idx] = val; }
  }
  if (tid == 0) rowptr[n] = sdata[1023];
}

__global__ void fill_csr_kernel(const int* __restrict__ src, const int* __restrict__ dst,
                                int* __restrict__ cursor, int* __restrict__ csr_src,
                                int* __restrict__ csr_eid, int e_cnt) {
  int e = blockIdx.x * blockDim.x + threadIdx.x;
  if (e < e_cnt) {
    int pos = atomicAdd(&cursor[dst[e]], 1);
    csr_src[pos] = src[e];
    csr_eid[pos] = e;
  }
}

// ======================= weight prep =======================
__global__ void prep_all_kernel(
    const float* __restrict__ n1l, const float* __restrict__ n1r,
    const float* __restrict__ e1l, const float* __restrict__ e1r,
    const float* __restrict__ n2l, const float* __restrict__ n2r,
    const float* __restrict__ e2l, const float* __restrict__ e2r,
    const float* __restrict__ b2, const float* __restrict__ wp,
    short* __restrict__ t_n1l, short* __restrict__ t_n1r,
    short* __restrict__ t_e1l, short* __restrict__ t_e1r,
    short* __restrict__ t_n2l, short* __restrict__ t_n2r,
    short* __restrict__ t_e2l, short* __restrict__ t_e2r,
    float* __restrict__ wct, float* __restrict__ pc)
{
  int i = blockIdx.x * blockDim.x + threadIdx.x;
  int seg = i >> 14;
  int j = i & 16383;
  if (seg < 4) {
    const float* srcs[4] = {n1l, n1r, e1l, e1r};
    short* dsts[4] = {t_n1l, t_n1r, t_e1l, t_e1r};
    int n = j >> 6, k = j & 63;
    dsts[seg][n * 64 + k] = f2bf(srcs[seg][k * 256 + n]);
  } else if (seg < 8) {
    const float* srcs[4] = {n2l, n2r, e2l, e2r};
    short* dsts[4] = {t_n2l, t_n2r, t_e2l, t_e2r};
    int n = j >> 8, k = j & 255;
    dsts[seg - 4][n * 256 + k] = f2bf(srcs[seg - 4][k * 64 + n]);
  } else if (seg == 8) {
    if (j < 512) {
      int jj = j & 1;
      int k  = j >> 1;
      float s = 0.f;
      for (int c = 0; c < 64; ++c) s = fmaf(e2l[k * 64 + c], wp[c * 2 + jj], s);
      wct[jj * 256 + k] = s;
    } else if (j < 514) {
      int jj = j - 512;
      float s = 0.f;
      for (int c = 0; c < 64; ++c) s = fmaf(b2[c], wp[c * 2 + jj], s);
      pc[jj] = s;
    }
  }
}

// ======================= MFMA projection kernel (dual-chain, fp16 outputs) ==========
template<int K>
__global__ __launch_bounds__(128) void mfma_proj2_kernel(
    const float* __restrict__ A0,
    const short* __restrict__ Wtl0, const short* __restrict__ Wtr0,
    half_t* __restrict__ xl0, half_t* __restrict__ xr0,
    const float* __restrict__ A1,
    const short* __restrict__ Wtl1, const short* __restrict__ Wtr1,
    half_t* __restrict__ xl1, half_t* __restrict__ xr1,
    int M, int nslices)
{
  constexpr int KC = K / 32;
  int tid = threadIdx.x;
  int w = tid >> 6, lane = tid & 63, quad = lane >> 4, l15 = lane & 15;
  int row_base = (int)blockIdx.x * 64 + w * 32;
  int y = (int)blockIdx.y;
  int z = (int)blockIdx.z;
  const float* A = z ? A1 : A0;
  bool is_l = y < nslices;
  const short* Wt = z ? (is_l ? Wtl1 : Wtr1) : (is_l ? Wtl0 : Wtr0);
  half_t* dst = z ? (is_l ? xl1 : xr1) : (is_l ? xl0 : xr0);
  int cb = (is_l ? y : y - nslices) * 64;
  int STR = nslices * 64;

  bf8_t a[2][KC];
  #pragma unroll
  for (int rt = 0; rt < 2; ++rt) {
    int r = row_base + rt * 16 + l15;
    int rc = r < M ? r : M - 1;
    const float* ap = A + (size_t)rc * K + quad * 8;
    #pragma unroll
    for (int kc = 0; kc < KC; ++kc) {
      float4 v0 = *(const float4*)(ap + kc * 32);
      float4 v1 = *(const float4*)(ap + kc * 32 + 4);
      bf8_t f;
      f[0] = f2bf(v0.x); f[1] = f2bf(v0.y); f[2] = f2bf(v0.z); f[3] = f2bf(v0.w);
      f[4] = f2bf(v1.x); f[5] = f2bf(v1.y); f[6] = f2bf(v1.z); f[7] = f2bf(v1.w);
      a[rt][kc] = f;
    }
  }

  #pragma unroll
  for (int nt = 0; nt < 4; ++nt) {
    f4_t acc0 = {0.f, 0.f, 0.f, 0.f};
    f4_t acc1 = {0.f, 0.f, 0.f, 0.f};
    const short* wb = Wt + (size_t)(cb + nt * 16 + l15) * K + quad * 8;
    #pragma unroll
    for (int kc = 0; kc < KC; ++kc) {
      bf8_t wf = *(const bf8_t*)(wb + kc * 32);
      acc0 = __builtin_amdgcn_mfma_f32_16x16x32_bf16(wf, a[0][kc], acc0, 0, 0, 0);
      acc1 = __builtin_amdgcn_mfma_f32_16x16x32_bf16(wf, a[1][kc], acc1, 0, 0, 0);
    }
    #pragma unroll
    for (int rt = 0; rt < 2; ++rt) {
      f4_t acc = rt == 0 ? acc0 : acc1;
      int row = row_base + rt * 16 + l15;
      if (row >= M) continue;
      int col = cb + nt * 16 + quad * 4;
      h4_t pk;
      pk[0] = (_Float16)acc[0]; pk[1] = (_Float16)acc[1];
      pk[2] = (_Float16)acc[2]; pk[3] = (_Float16)acc[3];
      *(h4_t*)&dst[(size_t)row * STR + col] = pk;
    }
  }
}

// ======================= fp32 GEMM (proxy head only) =======================
template<int KIN>
__device__ __forceinline__ void gemm_body(
    const float* __restrict__ A, const float* __restrict__ W, int wld, int cb,
    int block_m, int M, float (&acc)[8][4],
    float (*As)[128 + 4], float (*Ws)[64 + 4])
{
  int tid = threadIdx.x;
  int tx = tid & 15;
  int ty = tid >> 4;
  #pragma unroll
  for (int i = 0; i < 8; ++i)
    #pragma unroll
    for (int j = 0; j < 4; ++j) acc[i][j] = 0.f;

  for (int k0 = 0; k0 < KIN; k0 += 16) {
    #pragma unroll
    for (int rep = 0; rep < 2; ++rep) {
      int ar = (tid >> 2) + rep * 64;
      int ak = (tid & 3) * 4;
      int gr = block_m + ar;
      float4 v = make_float4(0.f, 0.f, 0.f, 0.f);
      if (gr < M) v = *(const float4*)&A[(size_t)gr * KIN + k0 + ak];
      As[ak + 0][ar] = v.x; As[ak + 1][ar] = v.y;
      As[ak + 2][ar] = v.z; As[ak + 3][ar] = v.w;
    }
    {
      int wr = tid >> 4;
      int wc = (tid & 15) * 4;
      float4 v = *(const float4*)&W[(size_t)(k0 + wr) * wld + cb + wc];
      Ws[wr][wc + 0] = v.x; Ws[wr][wc + 1] = v.y;
      Ws[wr][wc + 2] = v.z; Ws[wr][wc + 3] = v.w;
    }
    __syncthreads();
    #pragma unroll
    for (int k = 0; k < 16; ++k) {
      float a[8], w[4];
      #pragma unroll
      for (int i = 0; i < 8; ++i) a[i] = As[k][ty * 8 + i];
      #pragma unroll
      for (int j = 0; j < 4; ++j) w[j] = Ws[k][tx * 4 + j];
      #pragma unroll
      for (int i = 0; i < 8; ++i)
        #pragma unroll
        for (int j = 0; j < 4; ++j) acc[i][j] = fmaf(a[i], w[j], acc[i][j]);
    }
    __syncthreads();
  }
}

template<int KIN, int MODE>
__global__ __launch_bounds__(256) void gemm64_kernel(
    const float* __restrict__ A, const float* __restrict__ W, int wld,
    const float* __restrict__ bias, float* __restrict__ out, int old, int M)
{
  __shared__ float As[16][128 + 4];
  __shared__ float Ws[16][64 + 4];
  float acc[8][4];
  int block_m = (int)blockIdx.x * 128;
  int cb = (int)blockIdx.y * 64;
  gemm_body<KIN>(A, W, wld, cb, block_m, M, acc, As, Ws);

  int tid = threadIdx.x;
  int tx = tid & 15, ty = tid >> 4;
  int gc = cb + tx * 4;
  #pragma unroll
  for (int i = 0; i < 8; ++i) {
    int gr = block_m + ty * 8 + i;
    if (gr >= M) continue;
    size_t idx = (size_t)gr * old + gc;
    float t0 = acc[i][0], t1 = acc[i][1], t2 = acc[i][2], t3 = acc[i][3];
    if (MODE == 3) {
      t0 = fmaxf(t0 + bias[gc + 0], 0.f);
      t1 = fmaxf(t1 + bias[gc + 1], 0.f);
      t2 = fmaxf(t2 + bias[gc + 2], 0.f);
      t3 = fmaxf(t3 + bias[gc + 3], 0.f);
    }
    *(float4*)&out[idx] = make_float4(t0, t1, t2, t3);
  }
}

// ======================= GATv2 aggregation v6 (fp16 math) =======================
// fp16 xl/xr, packed-f16 leaky, v_dot2_f32_f16 logit accumulation, fp32 value
// accumulation. 3-stage pipeline + head-major block map from v5.
template<int STR, bool ELU, bool FUSEP>
__global__ __launch_bounds__(256) void gat_agg_v6(
    const half_t* __restrict__ xl0, const half_t* __restrict__ xr0,
    const float* __restrict__ att0, const float* __restrict__ bias0,
    float* __restrict__ out0,
    const half_t* __restrict__ xl1, const half_t* __restrict__ xr1,
    const float* __restrict__ att1, const float* __restrict__ bias1,
    float* __restrict__ out1,
    const int* __restrict__ rowptr, const int* __restrict__ csr_src,
    const float* __restrict__ wp, float* __restrict__ pbuf)
{
  constexpr int HEADS = STR / 64;
  constexpr int GRP = N_NODES / 4;
  int tid = threadIdx.x;
  int w = tid >> 6;
  int lane = tid & 63;
  int egrp = lane >> 3;
  int cch  = lane & 7;

  int bid = (int)blockIdx.x;
  int per_chain = HEADS * GRP;
  int chain = bid >= per_chain ? 1 : 0;
  int r = bid - chain * per_chain;
  int head = r / GRP;
  int d = (r - head * GRP) * 4 + w;

  const half_t* xl = chain ? xl1 : xl0;
  const half_t* xr = chain ? xr1 : xr0;
  const float* att = chain ? att1 : att0;
  const float* bias = chain ? bias1 : bias0;

  int row0 = rowptr[d];
  int deg = rowptr[d + 1] - row0;
  int cbase = head * 64 + cch * 8;

  h2_t xr2[4], att2[4];
  {
    h8_t xv = *(const h8_t*)&xr[(unsigned)(d * STR + cbase)];
    xr2[0] = h2_t{xv[0], xv[1]}; xr2[1] = h2_t{xv[2], xv[3]};
    xr2[2] = h2_t{xv[4], xv[5]}; xr2[3] = h2_t{xv[6], xv[7]};
    const float* atp = att + cbase;
    float4 b0 = *(const float4*)(atp);
    float4 b1 = *(const float4*)(atp + 4);
    att2[0] = h2_t{(_Float16)b0.x, (_Float16)b0.y};
    att2[1] = h2_t{(_Float16)b0.z, (_Float16)b0.w};
    att2[2] = h2_t{(_Float16)b1.x, (_Float16)b1.y};
    att2[3] = h2_t{(_Float16)b1.z, (_Float16)b1.w};
  }

  auto ld_idx = [&](int k) -> int {
    int idx = k * 8 + egrp;
    int cl = idx < deg ? idx : (deg > 0 ? deg - 1 : 0);
    int pos = deg > 0 ? row0 + cl : 0;
    int sv = csr_src[pos];
    return idx < deg ? sv : d;
  };

  float zloc;
  f2_t acc4[4];
  {
    h8_t xu = *(const h8_t*)&xl[(unsigned)(d * STR + cbase)];
    h2_t xs[4];
    xs[0] = h2_t{xu[0], xu[1]}; xs[1] = h2_t{xu[2], xu[3]};
    xs[2] = h2_t{xu[4], xu[5]}; xs[3] = h2_t{xu[6], xu[7]};
    float part = 0.f;
    #pragma unroll
    for (int j = 0; j < 4; ++j) part = dot2h(leaky_h2(xs[j] + xr2[j]), att2[j], part);
    part += __shfl_xor(part, 1, 64);
    part += __shfl_xor(part, 2, 64);
    part += __shfl_xor(part, 4, 64);
    float wgt = __expf(part);
    float ws = (egrp == 0) ? wgt : 0.f;
    zloc = ws;
    #pragma unroll
    for (int j = 0; j < 4; ++j) {
      f2_t t;
      t.x = (float)xs[j].x * ws;
      t.y = (float)xs[j].y * ws;
      acc4[j] = t;
    }
  }

  int C = (deg + 7) >> 3;
  int s_cur = ld_idx(0);
  h8_t xu_cur = *(const h8_t*)&xl[(unsigned)(s_cur * STR + cbase)];
  int s_nxt = ld_idx(1);
  for (int k = 0; k < C; ++k) {
    h8_t xu_nxt = *(const h8_t*)&xl[(unsigned)(s_nxt * STR + cbase)];
    int s_n2 = ld_idx(k + 2);
    bool valid = (k * 8 + egrp) < deg;
    h2_t xf[4];
    xf[0] = h2_t{xu_cur[0], xu_cur[1]}; xf[1] = h2_t{xu_cur[2], xu_cur[3]};
    xf[2] = h2_t{xu_cur[4], xu_cur[5]}; xf[3] = h2_t{xu_cur[6], xu_cur[7]};
    float part = 0.f;
    #pragma unroll
    for (int i = 0; i < 4; ++i) part = dot2h(leaky_h2(xf[i] + xr2[i]), att2[i], part);
    part += __shfl_xor(part, 1, 64);
    part += __shfl_xor(part, 2, 64);
    part += __shfl_xor(part, 4, 64);
    float wgt = valid ? __expf(part) : 0.f;
    zloc += wgt;
    #pragma unroll
    for (int i = 0; i < 4; ++i) {
      acc4[i].x = fmaf((float)xf[i].x, wgt, acc4[i].x);
      acc4[i].y = fmaf((float)xf[i].y, wgt, acc4[i].y);
    }
    xu_cur = xu_nxt;
    s_nxt = s_n2;
  }

  float a8[8];
  #pragma unroll
  for (int i = 0; i < 4; ++i) { a8[2 * i] = acc4[i].x; a8[2 * i + 1] = acc4[i].y; }
  #pragma unroll
  for (int off = 8; off < 64; off <<= 1) {
    zloc += __shfl_xor(zloc, off, 64);
    #pragma unroll
    for (int i = 0; i < 8; ++i) a8[i] += __shfl_xor(a8[i], off, 64);
  }

  float invz = 1.f / zloc;
  float o[8];
  #pragma unroll
  for (int i = 0; i < 8; ++i) {
    float val = a8[i] * invz + bias[cbase + i];
    if (ELU) val = val > 0.f ? val : __expf(val) - 1.f;
    o[i] = val;
  }

  if (FUSEP && chain) {
    float p0 = 0.f, p1 = 0.f;
    #pragma unroll
    for (int i = 0; i < 8; ++i) {
      float2 wv = *(const float2*)&wp[(cbase + i) * 2];
      p0 = fmaf(o[i], wv.x, p0);
      p1 = fmaf(o[i], wv.y, p1);
    }
    p0 += __shfl_xor(p0, 1, 64); p1 += __shfl_xor(p1, 1, 64);
    p0 += __shfl_xor(p0, 2, 64); p1 += __shfl_xor(p1, 2, 64);
    p0 += __shfl_xor(p0, 4, 64); p1 += __shfl_xor(p1, 4, 64);
    if (lane == 0) *(float2*)&pbuf[2 * d] = make_float2(p0, p1);
  } else if (egrp == 0) {
    float* out = chain ? out1 : out0;
    float* op = out + (size_t)d * STR + cbase;
    *(float4*)(op)     = make_float4(o[0], o[1], o[2], o[3]);
    *(float4*)(op + 4) = make_float4(o[4], o[5], o[6], o[7]);
  }
}

// ======================= folded chunk kernel v3 (64-thr blocks) =======================
__global__ __launch_bounds__(64) void chunk_fold_kernel(
    const float* __restrict__ A,
    const short* __restrict__ W1t,
    const float* __restrict__ b1,
    const float* __restrict__ WcT,
    const float* __restrict__ pc,
    float* __restrict__ pbufN,
    int Mtot)
{
  int lane = threadIdx.x;
  int quad = lane >> 4;
  int l15 = lane & 15;
  int row_base = (int)blockIdx.x * 64;

  bf8_t a1[4][2];
  #pragma unroll
  for (int rt = 0; rt < 4; ++rt) {
    int r = row_base + rt * 16 + l15;
    int rc = r < Mtot ? r : Mtot - 1;
    const float* ap = A + (size_t)rc * 64 + quad * 8;
    #pragma unroll
    for (int ks = 0; ks < 2; ++ks) {
      float4 v0 = *(const float4*)(ap + ks * 32);
      float4 v1 = *(const float4*)(ap + ks * 32 + 4);
      bf8_t f;
      f[0] = f2bf(v0.x); f[1] = f2bf(v0.y); f[2] = f2bf(v0.z); f[3] = f2bf(v0.w);
      f[4] = f2bf(v1.x); f[5] = f2bf(v1.y); f[6] = f2bf(v1.z); f[7] = f2bf(v1.w);
      a1[rt][ks] = f;
    }
  }

  float p0[4] = {0.f, 0.f, 0.f, 0.f};
  float p1[4] = {0.f, 0.f, 0.f, 0.f};

  #pragma unroll
  for (int cc = 0; cc < 4; ++cc) {
    #pragma unroll
    for (int nt = 0; nt < 4; ++nt) {
      const short* wb = W1t + (cc * 64 + nt * 16 + l15) * 64 + quad * 8;
      bf8_t w0 = *(const bf8_t*)(wb);
      bf8_t w1 = *(const bf8_t*)(wb + 32);
      f4_t g[4];
      #pragma unroll
      for (int rt = 0; rt < 4; ++rt) {
        f4_t z = {0.f, 0.f, 0.f, 0.f};
        z = __builtin_amdgcn_mfma_f32_16x16x32_bf16(w0, a1[rt][0], z, 0, 0, 0);
        z = __builtin_amdgcn_mfma_f32_16x16x32_bf16(w1, a1[rt][1], z, 0, 0, 0);
        g[rt] = z;
      }
      int cbase = cc * 64 + nt * 16 + quad * 4;
      f4_t b4  = *(const f4_t*)&b1[cbase];
      f4_t wc0 = *(const f4_t*)&WcT[cbase];
      f4_t wc1 = *(const f4_t*)&WcT[256 + cbase];
      #pragma unroll
      for (int rt = 0; rt < 4; ++rt) {
        #pragma unroll
        for (int r = 0; r < 4; ++r) {
          float v = g[rt][r] + b4[r];
          v = v > 0.f ? v : __expf(v) - 1.f;
          p0[rt] = fmaf(v, wc0[r], p0[rt]);
          p1[rt] = fmaf(v, wc1[r], p1[rt]);
        }
      }
    }
  }

  #pragma unroll
  for (int off = 16; off < 64; off <<= 1) {
    #pragma unroll
    for (int rt = 0; rt < 4; ++rt) {
      p0[rt] += __shfl_xor(p0[rt], off, 64);
      p1[rt] += __shfl_xor(p1[rt], off, 64);
    }
  }
  if (quad == 0) {
    float c0 = pc[0], c1 = pc[1];
    #pragma unroll
    for (int rt = 0; rt < 4; ++rt) {
      int row = row_base + rt * 16 + l15;
      if (row < Mtot)
        *(float2*)&pbufN[2 * row] = make_float2(p0[rt] + c0, p1[rt] + c1);
    }
  }
}

// ======================= Heads =======================
__global__ void head_kernel(const float* __restrict__ node_repr, const float* __restrict__ ph,
                            const int* __restrict__ rowptr, const int* __restrict__ csr_eid,
                            const float* __restrict__ pbuf, const float* __restrict__ wu,
                            const float* __restrict__ bu, const float* __restrict__ w2,
                            const float* __restrict__ b2, float* __restrict__ out, int n) {
  __shared__ float swu[128];
  __shared__ float sw2[256];
  int tid = threadIdx.x;
  if (tid < 128) swu[tid] = wu[tid];
  sw2[tid] = w2[tid];
  __syncthreads();
  int i = blockIdx.x * blockDim.x + tid;
  if (i >= n) return;
  float m0 = 0.f, m1 = 0.f;
  int r0 = rowptr[i], r1 = rowptr[i + 1];
  int jj = r0;
  for (; jj + 4 <= r1; jj += 4) {
    int e0 = csr_eid[jj + 0], e1 = csr_eid[jj + 1];
    int e2 = csr_eid[jj + 2], e3 = csr_eid[jj + 3];
    float2 q0 = *(const float2*)&pbuf[2 * e0];
    float2 q1 = *(const float2*)&pbuf[2 * e1];
    float2 q2 = *(const float2*)&pbuf[2 * e2];
    float2 q3 = *(const float2*)&pbuf[2 * e3];
    m0 += (q0.x + q1.x) + (q2.x + q3.x);
    m1 += (q0.y + q1.y) + (q2.y + q3.y);
  }
  for (; jj < r1; ++jj) {
    int e = csr_eid[jj];
    float2 q = *(const float2*)&pbuf[2 * e];
    m0 += q.x; m1 += q.y;
  }
  const float* nr = node_repr + (size_t)i * 64;
  float u0 = bu[0], u1 = bu[1];
  #pragma unroll
  for (int k = 0; k < 64; ++k) {
    float v = nr[k];
    u0 = fmaf(v, swu[2 * k + 0], u0);
    u1 = fmaf(v, swu[2 * k + 1], u1);
  }
  float v0 = u0 + m0;
  float v1 = u1 + m1;
  float mx = fmaxf(v0, v1);
  float lse = mx + logf(__expf(v0 - mx) + __expf(v1 - mx));
  out[2 * i + 0] = v0 - lse;
  out[2 * i + 1] = v1 - lse;
  const float* p = ph + (size_t)i * 128;
  float p0 = b2[0], p1 = b2[1];
  #pragma unroll
  for (int k = 0; k < 128; ++k) {
    float v = p[k];
    p0 = fmaf(v, sw2[2 * k + 0], p0);
    p1 = fmaf(v, sw2[2 * k + 1], p1);
  }
  out[2 * n + 2 * i + 0] = p0;
  out[2 * n + 2 * i + 1] = p1;
}

// ======================= launch =======================
extern "C" void kernel_launch(void* const* d_in, const int* in_sizes, int n_in,
                              void* d_out, int out_size, void* d_ws, size_t ws_size,
                              hipStream_t stream) {
  const int N = N_NODES, E = N_EDGES;
  const float* x         = (const float*)d_in[0];
  const float* edge_type = (const float*)d_in[1];
  const int*   ei        = (const int*)d_in[2];
  const float* n1_wl  = (const float*)d_in[3];
  const float* n1_wr  = (const float*)d_in[4];
  const float* n1_att = (const float*)d_in[5];
  const float* n1_b   = (const float*)d_in[6];
  const float* n2_wl  = (const float*)d_in[7];
  const float* n2_wr  = (const float*)d_in[8];
  const float* n2_att = (const float*)d_in[9];
  const float* n2_b   = (const float*)d_in[10];
  const float* e1_wl  = (const float*)d_in[11];
  const float* e1_wr  = (const float*)d_in[12];
  const float* e1_att = (const float*)d_in[13];
  const float* e1_b   = (const float*)d_in[14];
  const float* e2_wl  = (const float*)d_in[15];
  const float* e2_wr  = (const float*)d_in[16];
  const float* e2_att = (const float*)d_in[17];
  const float* e2_b   = (const float*)d_in[18];
  const float* crf_wu = (const float*)d_in[19];
  const float* crf_bu = (const float*)d_in[20];
  const float* crf_wp = (const float*)d_in[21];
  const float* px_w1  = (const float*)d_in[22];
  const float* px_b1  = (const float*)d_in[23];
  const float* px_w2  = (const float*)d_in[24];
  const float* px_b2  = (const float*)d_in[25];
  float* out = (float*)d_out;
  const int* src = ei;
  const int* dst = ei + E;
  (void)in_sizes; (void)n_in; (void)out_size; (void)ws_size;

  // ---- workspace layout ----
  char* ws = (char*)d_ws;
  size_t off = 0;
  auto alloc = [&](size_t bytes) -> void* {
    void* p = ws + off;
    off += (bytes + 255) & ~(size_t)255;
    return p;
  };
  half_t* xl_n  = (half_t*)alloc((size_t)N * 256 * 2);
  half_t* xr_n  = (half_t*)alloc((size_t)N * 256 * 2);
  half_t* xl_e  = (half_t*)alloc((size_t)N * 256 * 2);
  half_t* xr_e  = (half_t*)alloc((size_t)N * 256 * 2);
  float* h_n   = (float*)alloc((size_t)N * 256 * 4);
  float* g_e   = (float*)alloc((size_t)N * 256 * 4);
  half_t* xl2_n = (half_t*)alloc((size_t)N * 64 * 2);
  half_t* xr2_n = (half_t*)alloc((size_t)N * 64 * 2);
  half_t* xl2_e = (half_t*)alloc((size_t)N * 64 * 2);
  half_t* xr2_e = (half_t*)alloc((size_t)N * 64 * 2);
  float* B3    = (float*)alloc((size_t)N * 64 * 4);
  float* pbuf  = (float*)alloc((size_t)E * 2 * 4);
  float* ph    = (float*)(void*)xl_n;   // reuse 10.24 MB
  int* deg     = (int*)alloc((size_t)N * 4);
  int* rowptr  = (int*)alloc((size_t)(N + 1) * 4);
  int* cursor  = (int*)alloc((size_t)N * 4);
  int* csr_src = (int*)alloc((size_t)E * 4);
  int* csr_eid = (int*)alloc((size_t)E * 4);
  short* t_n1l = (short*)alloc((size_t)16384 * 2);
  short* t_n1r = (short*)alloc((size_t)16384 * 2);
  short* t_e1l = (short*)alloc((size_t)16384 * 2);
  short* t_e1r = (short*)alloc((size_t)16384 * 2);
  short* t_n2l = (short*)alloc((size_t)16384 * 2);
  short* t_n2r = (short*)alloc((size_t)16384 * 2);
  short* t_e2l = (short*)alloc((size_t)16384 * 2);
  short* t_e2r = (short*)alloc((size_t)16384 * 2);
  float* WcT   = (float*)alloc((size_t)2 * 256 * 4);
  float* pcv   = (float*)alloc((size_t)2 * 4);

  const int EB = (E + 255) / 256;
  const int NB = (N + 127) / 128;
  const int PB = (N + 63) / 64;
  const int Mhigh = E - N;
  const int CFB = (Mhigh + 63) / 64;     // 64-row single-wave blocks
  const int GRP = N / 4;

  hipMemsetAsync(deg, 0, (size_t)N * 4, stream);
  count_deg_kernel<<<EB, 256, 0, stream>>>(dst, deg, E);
  scan_kernel<<<1, 1024, 0, stream>>>(deg, rowptr, cursor, N);
  fill_csr_kernel<<<EB, 256, 0, stream>>>(src, dst, cursor, csr_src, csr_eid, E);
  prep_all_kernel<<<515, 256, 0, stream>>>(n1_wl, n1_wr, e1_wl, e1_wr,
                                           n2_wl, n2_wr, e2_wl, e2_wr,
                                           e2_b, crf_wp,
                                           t_n1l, t_n1r, t_e1l, t_e1r,
                                           t_n2l, t_n2r, t_e2l, t_e2r, WcT, pcv);

  // ---- layer 1 ----
  mfma_proj2_kernel<64><<<dim3(PB, 8, 2), 128, 0, stream>>>(
      x, t_n1l, t_n1r, xl_n, xr_n,
      edge_type, t_e1l, t_e1r, xl_e, xr_e, N, 4);
  gat_agg_v6<256, true, false><<<2 * 4 * GRP, 256, 0, stream>>>(
      xl_n, xr_n, n1_att, n1_b, h_n,
      xl_e, xr_e, e1_att, e1_b, g_e, rowptr, csr_src, nullptr, nullptr);

  // ---- layer 2 ----
  mfma_proj2_kernel<256><<<dim3(PB, 2, 2), 128, 0, stream>>>(
      h_n, t_n2l, t_n2r, xl2_n, xr2_n,
      g_e, t_e2l, t_e2r, xl2_e, xr2_e, N, 1);
  gat_agg_v6<64, false, true><<<2 * GRP, 256, 0, stream>>>(
      xl2_n, xr2_n, n2_att, n2_b, B3,
      xl2_e, xr2_e, e2_att, e2_b, nullptr, rowptr, csr_src, crf_wp, pbuf);

  // ---- CRF p for self-loop-only edge rows ----
  chunk_fold_kernel<<<CFB, 64, 0, stream>>>(edge_type + (size_t)N * 64, t_e1l,
                                            e1_b, WcT, pcv, pbuf + 2 * (size_t)N, Mhigh);

  // ---- heads ----
  gemm64_kernel<64, 3><<<dim3(NB, 2), 256, 0, stream>>>(B3, px_w1, 128, px_b1, ph, 128, N);
  head_kernel<<<(N + 255) / 256, 256, 0, stream>>>(B3, ph, rowptr, csr_eid, pbuf,
                                                   crf_wu, crf_bu, px_w2, px_b2, out, N);
}